// Round 3
// baseline (1729.347 us; speedup 1.0000x reference)
//
#include <hip/hip_runtime.h>
#include <cstddef>

#define DEV __device__ __forceinline__

DEV float fexp2(float x) { return __builtin_amdgcn_exp2f(x); }
DEV float frcp(float x)  { return __builtin_amdgcn_rcpf(x); }
DEV float fsigm(float x) { return frcp(1.0f + fexp2(-1.44269504f * x)); }
DEV float ftanh_(float x){ return 1.0f - 2.0f * frcp(1.0f + fexp2(2.88539008f * x)); }

typedef _Float16 h2t __attribute__((ext_vector_type(2)));
typedef _Float16 v8h __attribute__((ext_vector_type(8)));
typedef float v4f __attribute__((ext_vector_type(4)));
union U32H2 { unsigned int u; h2t h; };
DEV h2t u2h(unsigned int u) { U32H2 x; x.u = u; return x.h; }

// ---------------------------------------------------------------------------
// f16 MFMA GEMM: C[M,N] = A[M,K] @ W[N,K]^T + bias; A,W f16 row-major.
// BM in {64,128}, BK=32, 256 threads (4 waves, 2x2), wave tile (BM/2)x(BN/2).
// ---------------------------------------------------------------------------
template <int BM, int BN, bool RELU, bool OUTF16>
__global__ __launch_bounds__(256) void hgemm_kernel(
    const _Float16* __restrict__ A, const _Float16* __restrict__ W,
    const float* __restrict__ bias1, const float* __restrict__ bias2,
    void* __restrict__ Cout, int M, int N, int K)
{
    constexpr int MT = BM / 32;
    constexpr int NT = BN / 32;
    constexpr int RA = BM / 64;
    constexpr int RB = BN / 64;
    __shared__ _Float16 As[BM * 32];
    __shared__ _Float16 Bs[BN * 32];

    const int tid = threadIdx.x;
    const int lane = tid & 63;
    const int lm = lane & 15, lq = lane >> 4;
    const int wrow = ((tid >> 6) & 1) * (BM / 2);
    const int wcol = (tid >> 7) * (BN / 2);
    const int m0 = blockIdx.x * BM, n0 = blockIdx.y * BN;
    const _Float16* Ab = A + (size_t)m0 * K;
    const _Float16* Wb = W + (size_t)n0 * K;

    v4f acc[MT][NT];
#pragma unroll
    for (int i = 0; i < MT; ++i)
#pragma unroll
        for (int j = 0; j < NT; ++j) acc[i][j] = (v4f){0.f, 0.f, 0.f, 0.f};

    const int rowS = tid >> 2, qS = tid & 3;

    uint4 ra[RA], rb[RB];
#pragma unroll
    for (int r = 0; r < RA; ++r)
        ra[r] = *(const uint4*)(Ab + (size_t)(rowS + 64 * r) * K + qS * 8);
#pragma unroll
    for (int r = 0; r < RB; ++r)
        rb[r] = *(const uint4*)(Wb + (size_t)(rowS + 64 * r) * K + qS * 8);

    for (int k0 = 0; k0 < K; k0 += 32) {
        __syncthreads();
#pragma unroll
        for (int r = 0; r < RA; ++r)
            *(uint4*)(As + (size_t)(tid + 256 * r) * 8) = ra[r];
#pragma unroll
        for (int r = 0; r < RB; ++r)
            *(uint4*)(Bs + (size_t)(tid + 256 * r) * 8) = rb[r];
        __syncthreads();
        int kn = k0 + 32;
        if (kn < K) {
#pragma unroll
            for (int r = 0; r < RA; ++r)
                ra[r] = *(const uint4*)(Ab + (size_t)(rowS + 64 * r) * K + kn + qS * 8);
#pragma unroll
            for (int r = 0; r < RB; ++r)
                rb[r] = *(const uint4*)(Wb + (size_t)(rowS + 64 * r) * K + kn + qS * 8);
        }
        v8h af[MT], bf[NT];
#pragma unroll
        for (int i = 0; i < MT; ++i)
            af[i] = *(const v8h*)(As + (size_t)(wrow + i * 16 + lm) * 32 + lq * 8);
#pragma unroll
        for (int j = 0; j < NT; ++j)
            bf[j] = *(const v8h*)(Bs + (size_t)(wcol + j * 16 + lm) * 32 + lq * 8);
#pragma unroll
        for (int i = 0; i < MT; ++i)
#pragma unroll
            for (int j = 0; j < NT; ++j)
                acc[i][j] = __builtin_amdgcn_mfma_f32_16x16x32_f16(
                    af[i], bf[j], acc[i][j], 0, 0, 0);
    }

#pragma unroll
    for (int j = 0; j < NT; ++j) {
        int col = n0 + wcol + j * 16 + lm;
        float bv = bias1[col];
        if (bias2) bv += bias2[col];
#pragma unroll
        for (int i = 0; i < MT; ++i) {
            int rbase = m0 + wrow + i * 16 + lq * 4;
#pragma unroll
            for (int rg = 0; rg < 4; ++rg) {
                float vv = acc[i][j][rg] + bv;
                if (RELU) vv = fmaxf(vv, 0.f);
                if (OUTF16)
                    ((_Float16*)Cout)[(size_t)(rbase + rg) * N + col] = (_Float16)vv;
                else
                    ((float*)Cout)[(size_t)(rbase + rg) * N + col] = vv;
            }
        }
    }
}

// ---------------------------------------------------------------------------
// GEMM (N=256 fixed) + bias + residual + LayerNorm fused.
// Out: X (f32, in-place residual target) and X16 (f16 copy).
// BM=64, BN=256, 256 threads (4 waves, 2x2), wave tile 32x128.
// ---------------------------------------------------------------------------
__global__ __launch_bounds__(256) void hgemm_ln_kernel(
    const _Float16* __restrict__ A, const _Float16* __restrict__ W,
    const float* __restrict__ bias, const float* __restrict__ gamma,
    const float* __restrict__ beta, float* __restrict__ X,
    _Float16* __restrict__ X16, int K)
{
    constexpr int BM = 64, BN = 256, MT = 2, NT = 8, RA = 1, RB = 4;
    __shared__ _Float16 As[BM * 32];
    __shared__ _Float16 Bs[BN * 32];
    __shared__ float redS[2][BM][2];

    const int tid = threadIdx.x;
    const int lane = tid & 63;
    const int lm = lane & 15, lq = lane >> 4;
    const int wrow = ((tid >> 6) & 1) * 32;
    const int wcol = (tid >> 7) * 128;
    const int half = tid >> 7;
    const int m0 = blockIdx.x * BM;
    const _Float16* Ab = A + (size_t)m0 * K;

    v4f acc[MT][NT];
#pragma unroll
    for (int i = 0; i < MT; ++i)
#pragma unroll
        for (int j = 0; j < NT; ++j) acc[i][j] = (v4f){0.f, 0.f, 0.f, 0.f};

    const int rowS = tid >> 2, qS = tid & 3;

    uint4 ra[RA], rb[RB];
#pragma unroll
    for (int r = 0; r < RA; ++r)
        ra[r] = *(const uint4*)(Ab + (size_t)(rowS + 64 * r) * K + qS * 8);
#pragma unroll
    for (int r = 0; r < RB; ++r)
        rb[r] = *(const uint4*)(W + (size_t)(rowS + 64 * r) * K + qS * 8);

    for (int k0 = 0; k0 < K; k0 += 32) {
        __syncthreads();
#pragma unroll
        for (int r = 0; r < RA; ++r)
            *(uint4*)(As + (size_t)(tid + 256 * r) * 8) = ra[r];
#pragma unroll
        for (int r = 0; r < RB; ++r)
            *(uint4*)(Bs + (size_t)(tid + 256 * r) * 8) = rb[r];
        __syncthreads();
        int kn = k0 + 32;
        if (kn < K) {
#pragma unroll
            for (int r = 0; r < RA; ++r)
                ra[r] = *(const uint4*)(Ab + (size_t)(rowS + 64 * r) * K + kn + qS * 8);
#pragma unroll
            for (int r = 0; r < RB; ++r)
                rb[r] = *(const uint4*)(W + (size_t)(rowS + 64 * r) * K + kn + qS * 8);
        }
        v8h af[MT], bf[NT];
#pragma unroll
        for (int i = 0; i < MT; ++i)
            af[i] = *(const v8h*)(As + (size_t)(wrow + i * 16 + lm) * 32 + lq * 8);
#pragma unroll
        for (int j = 0; j < NT; ++j)
            bf[j] = *(const v8h*)(Bs + (size_t)(wcol + j * 16 + lm) * 32 + lq * 8);
#pragma unroll
        for (int i = 0; i < MT; ++i)
#pragma unroll
            for (int j = 0; j < NT; ++j)
                acc[i][j] = __builtin_amdgcn_mfma_f32_16x16x32_f16(
                    af[i], bf[j], acc[i][j], 0, 0, 0);
    }

    // y = gemm + bias + residual; accumulate per-row sums
    float s[MT][4], s2[MT][4];
#pragma unroll
    for (int i = 0; i < MT; ++i)
#pragma unroll
        for (int rg = 0; rg < 4; ++rg) { s[i][rg] = 0.f; s2[i][rg] = 0.f; }
#pragma unroll
    for (int j = 0; j < NT; ++j) {
        int col = wcol + j * 16 + lm;
        float bv = bias[col];
#pragma unroll
        for (int i = 0; i < MT; ++i) {
            int rbase = m0 + wrow + i * 16 + lq * 4;
#pragma unroll
            for (int rg = 0; rg < 4; ++rg) {
                float y = acc[i][j][rg] + bv + X[(size_t)(rbase + rg) * 256 + col];
                acc[i][j][rg] = y;
                s[i][rg] += y;
                s2[i][rg] += y * y;
            }
        }
    }
    // reduce across the 16 lm lanes (same row), publish per-half partials
#pragma unroll
    for (int i = 0; i < MT; ++i)
#pragma unroll
        for (int rg = 0; rg < 4; ++rg) {
            float a = s[i][rg], b2 = s2[i][rg];
#pragma unroll
            for (int m = 1; m < 16; m <<= 1) {
                a += __shfl_xor(a, m);
                b2 += __shfl_xor(b2, m);
            }
            if (lm == 0) {
                int rloc = wrow + i * 16 + lq * 4 + rg;
                redS[half][rloc][0] = a;
                redS[half][rloc][1] = b2;
            }
        }
    __syncthreads();
#pragma unroll
    for (int i = 0; i < MT; ++i) {
#pragma unroll
        for (int rg = 0; rg < 4; ++rg) {
            int rloc = wrow + i * 16 + lq * 4 + rg;
            float st = redS[0][rloc][0] + redS[1][rloc][0];
            float s2t = redS[0][rloc][1] + redS[1][rloc][1];
            float mean = st * (1.f / 256.f);
            float var = s2t * (1.f / 256.f) - mean * mean;
            float inv = rsqrtf(var + 1e-5f);
            size_t rowb = (size_t)(m0 + rloc) * 256;
#pragma unroll
            for (int j = 0; j < NT; ++j) {
                int col = wcol + j * 16 + lm;
                float o = (acc[i][j][rg] - mean) * inv * gamma[col] + beta[col];
                X[rowb + col] = o;
                X16[rowb + col] = (_Float16)o;
            }
        }
    }
}

// ---------------------------------------------------------------------------
// Fused weight conversion (cvt_all + Whh MFMA-fragment blob + permuted bias).
// Wih dest rows are gate-interleaved: dest row j*4+g = src row g*256+j.
// Whh blob: B-fragments for mfma_f32_16x16x32_f16. Fragment (w,jt,kt):
//   word idx = (((w*8+jt)*8+kt)*64 + lane)*4 + wd
//   n = w*128 + jt*16 + (lane&15)   (logical gate index, = j*4+g)
//   k = kt*32 + (lane>>4)*8 + wd*2  (+0,+1 packed)
//   src row = (n&3)*256 + (n>>2)
// ---------------------------------------------------------------------------
__global__ __launch_bounds__(256) void cvt_fused_kernel(
    const float* __restrict__ s0, const float* __restrict__ s1,
    const float* __restrict__ s2, const float* __restrict__ s3,
    const float* __restrict__ s4, const float* __restrict__ s5,
    _Float16* __restrict__ dst,
    const float* __restrict__ Whh, unsigned int* __restrict__ WB,
    const float* __restrict__ bih, const float* __restrict__ bhh,
    float* __restrict__ PB)
{
    if (blockIdx.x < 7424) {
        int i = blockIdx.x * 256 + threadIdx.x;
        if (i >= 1900544) return;
        float val;
        if (i < 589824)       val = s0[i];
        else if (i < 786432)  val = s1[i - 589824];
        else if (i < 1179648) val = s2[i - 786432];
        else if (i < 1572864) val = s3[i - 1179648];
        else if (i < 1835008) {
            int idx = i - 1572864;
            int rp = idx >> 8, k = idx & 255;
            int j = rp >> 2, g = rp & 3;
            val = s4[(g * 256 + j) * 256 + k];
        }
        else                  val = s5[i - 1835008];
        dst[i] = (_Float16)val;
    } else {
        int idx = (blockIdx.x - 7424) * 256 + threadIdx.x;  // 0..131071
        if (idx < 1024) {
            int j = idx >> 2, g = idx & 3;
            PB[idx] = bih[g * 256 + j] + bhh[g * 256 + j];
        }
        int wd   = idx & 3;
        int lane = (idx >> 2) & 63;
        int kt   = (idx >> 8) & 7;
        int jt   = (idx >> 11) & 7;
        int w    = (idx >> 14) & 7;
        int n = w * 128 + jt * 16 + (lane & 15);
        int src_r = (n & 3) * 256 + (n >> 2);
        int k = kt * 32 + ((lane >> 4) << 3) + (wd << 1);
        _Float16 lo = (_Float16)Whh[src_r * 256 + k];
        _Float16 hi = (_Float16)Whh[src_r * 256 + k + 1];
        U32H2 x; x.h = h2t{lo, hi};
        WB[idx] = x.u;
    }
}

// ---------------------------------------------------------------------------
// Part encoder with bin-encoder fused (bb computed redundantly per block).
// ---------------------------------------------------------------------------
__global__ __launch_bounds__(128) void part_enc_kernel(
    const float* __restrict__ parts, const float* __restrict__ W1,
    const float* __restrict__ b1, const float* __restrict__ W2,
    const float* __restrict__ b2, const float* __restrict__ bin_info,
    const float* __restrict__ be_W1, const float* __restrict__ be_b1,
    const float* __restrict__ be_W2, const float* __restrict__ be_b2,
    const float* __restrict__ pos_emb, float* __restrict__ X,
    _Float16* __restrict__ X16)
{
    __shared__ float W2s[128][129];
    __shared__ float h1[128];
    __shared__ float pin[16];
    __shared__ float h1b[64];
    __shared__ float bb_s[64];
    int tid = threadIdx.x;
    int b = blockIdx.x >> 3, s0 = (blockIdx.x & 7) * 32;
    for (int l = 0; l < 128; ++l) W2s[l][tid] = W2[l * 128 + tid];
    // bin encoder (64-dim MLP, redundant per block, trivial)
    {
        float x0 = bin_info[b * 2], x1 = bin_info[b * 2 + 1];
        if (tid < 64)
            h1b[tid] = fmaxf(be_W1[tid * 2] * x0 + be_W1[tid * 2 + 1] * x1
                             + be_b1[tid], 0.f);
        __syncthreads();
        if (tid < 64) {
            float a = be_b2[tid];
#pragma unroll 4
            for (int e = 0; e < 64; ++e) a += be_W2[tid * 64 + e] * h1b[e];
            bb_s[tid] = a;
        }
        __syncthreads();
    }
    float w1r[16];
#pragma unroll
    for (int k = 0; k < 16; ++k) w1r[k] = W1[tid * 16 + k];
    float bias1v = b1[tid], bias2v = b2[tid];
    for (int si = 0; si < 32; ++si) {
        int s = s0 + si;
        size_t row = (size_t)b * 256 + s;
        if (tid < 16) pin[tid] = parts[row * 16 + tid];
        __syncthreads();
        float h = bias1v;
#pragma unroll
        for (int k = 0; k < 16; ++k) h += w1r[k] * pin[k];
        h1[tid] = fmaxf(h, 0.f);
        __syncthreads();
        float acc = bias2v;
#pragma unroll 4
        for (int e = 0; e < 128; ++e) acc += W2s[tid][e] * h1[e];
        X[row * 256 + tid] = acc;
        X16[row * 256 + tid] = (_Float16)acc;
        if (tid < 64) {
            float bbv = bb_s[tid];
            float pev = pos_emb[s * 64 + tid];
            X[row * 256 + 128 + tid] = bbv;
            X[row * 256 + 192 + tid] = pev;
            X16[row * 256 + 128 + tid] = (_Float16)bbv;
            X16[row * 256 + 192 + tid] = (_Float16)pev;
        }
        __syncthreads();
    }
}

// ---------------------------------------------------------------------------
// MFMA attention: one block per (b,h), 256 threads (4 waves).
// ---------------------------------------------------------------------------
__global__ __launch_bounds__(256) void attn_mfma_kernel(
    const _Float16* __restrict__ QKV, _Float16* __restrict__ O16)
{
    int bh = blockIdx.x;
    int b = bh >> 3, h = bh & 7;
    const int tid = threadIdx.x;
    const int w = tid >> 6;
    const int lane = tid & 63;
    const int lm = lane & 15, lq = lane >> 4;
    const float c_se = 0.17677669529663687f * 1.44269504f;

    __shared__ _Float16 Ks[4][256][8];
    __shared__ _Float16 Vt[32][264];
    __shared__ _Float16 Ps[4][16][264];

    const _Float16* qkvb = QKV + (size_t)(b * 256) * 768 + h * 32;
    {
        int s = tid;
        const _Float16* kr = qkvb + (size_t)s * 768 + 256;
#pragma unroll
        for (int c = 0; c < 4; ++c)
            *(uint4*)&Ks[c][s][0] = *(const uint4*)(kr + c * 8);
        const _Float16* vr = qkvb + (size_t)s * 768 + 512;
        _Float16 vtmp[32];
        *(uint4*)&vtmp[0]  = *(const uint4*)(vr);
        *(uint4*)&vtmp[8]  = *(const uint4*)(vr + 8);
        *(uint4*)&vtmp[16] = *(const uint4*)(vr + 16);
        *(uint4*)&vtmp[24] = *(const uint4*)(vr + 24);
#pragma unroll
        for (int d = 0; d < 32; ++d) Vt[d][s] = vtmp[d];
    }
    __syncthreads();

#pragma unroll 1
    for (int st = 0; st < 4; ++st) {
        int rt = w * 4 + st;
        v8h qf = *(const v8h*)(QKV + (size_t)(b * 256 + rt * 16 + lm) * 768
                               + h * 32 + lq * 8);
        v4f acc[16];
#pragma unroll
        for (int ct = 0; ct < 16; ++ct) {
            v8h kf = *(const v8h*)&Ks[lq][ct * 16 + lm][0];
            acc[ct] = __builtin_amdgcn_mfma_f32_16x16x32_f16(
                qf, kf, (v4f){0.f, 0.f, 0.f, 0.f}, 0, 0, 0);
        }
        float sminv[4];
#pragma unroll
        for (int r = 0; r < 4; ++r) {
            float m = acc[0][r];
#pragma unroll
            for (int ct = 1; ct < 16; ++ct) m = fmaxf(m, acc[ct][r]);
#pragma unroll
            for (int msk = 1; msk < 16; msk <<= 1)
                m = fmaxf(m, __shfl_xor(m, msk));
            float ssum = 0.f;
#pragma unroll
            for (int ct = 0; ct < 16; ++ct) {
                float e = fexp2((acc[ct][r] - m) * c_se);
                acc[ct][r] = e;
                ssum += e;
            }
#pragma unroll
            for (int msk = 1; msk < 16; msk <<= 1)
                ssum += __shfl_xor(ssum, msk);
            sminv[r] = frcp(ssum);
        }
#pragma unroll
        for (int ct = 0; ct < 16; ++ct)
#pragma unroll
            for (int r = 0; r < 4; ++r)
                Ps[w][lq * 4 + r][ct * 16 + lm] =
                    (_Float16)(acc[ct][r] * sminv[r]);
#pragma unroll
        for (int dt = 0; dt < 2; ++dt) {
            v4f o = (v4f){0.f, 0.f, 0.f, 0.f};
#pragma unroll
            for (int jc = 0; jc < 8; ++jc) {
                v8h pf = *(const v8h*)&Ps[w][lm][jc * 32 + lq * 8];
                v8h vf = *(const v8h*)&Vt[dt * 16 + lm][jc * 32 + lq * 8];
                o = __builtin_amdgcn_mfma_f32_16x16x32_f16(pf, vf, o, 0, 0, 0);
            }
#pragma unroll
            for (int r = 0; r < 4; ++r)
                O16[(size_t)(b * 256 + rt * 16 + lq * 4 + r) * 256
                    + h * 32 + dt * 16 + lm] = (_Float16)o[r];
        }
    }
}

// ---------------------------------------------------------------------------
__global__ __launch_bounds__(256) void gather_kernel(
    const float* __restrict__ X, const int* __restrict__ target,
    _Float16* __restrict__ Xg16)
{
    int row = blockIdx.x;
    int b = row >> 8, t = row & 255;
    int d = threadIdx.x;
    float val = 0.f;
    if (t > 0) {
        int src = target[b * 256 + t - 1];
        val = X[((size_t)b * 256 + src) * 256 + d];
    }
    Xg16[(size_t)row * 256 + d] = (_Float16)val;
}

// ---------------------------------------------------------------------------
// LSTM recurrence via MFMA: 1 block/batch, 512 threads (8 waves).
// Whole Whh lives register-resident as wave-stationary B-fragments
// (64 uint4/thread = 256 regs, unified VGPR+AGPR). A = h broadcast to all
// 16 rows (row-redundant, free). Per step/wave: 64 MFMA, n-range w*128..+128.
// g layout n = j*4+g matches g_in gate interleave -> tail reads one float4.
// ---------------------------------------------------------------------------
__global__ __launch_bounds__(512) void lstm_kernel(
    const _Float16* __restrict__ g_in, const uint4* __restrict__ WB4,
    _Float16* __restrict__ HALL16)
{
    const int b = blockIdx.x;
    const int tid = threadIdx.x;
    const int w = tid >> 6;
    const int lane = tid & 63;
    const int lq = lane >> 4;

    __shared__ float gf[1024];         // 4 KB gate staging
    __shared__ uint4 h2v[32];          // 512 B packed h (f16 pairs)
    unsigned int* h2_s = (unsigned int*)h2v;

    // stationary B-fragments: wf[jt][kt] (static indexing only)
    uint4 wf[8][8];
#pragma unroll
    for (int jt = 0; jt < 8; ++jt)
#pragma unroll
        for (int kt = 0; kt < 8; ++kt)
            wf[jt][kt] = WB4[((((w << 3) + jt) << 3) + kt) * 64 + lane];

    if (tid < 128) h2_s[tid] = 0u;

    const _Float16* ginb = g_in + (size_t)b * 256 * 1024;
    uint2 gi = make_uint2(0u, 0u);
    if (tid < 256) gi = *(const uint2*)(ginb + tid * 4);
    float c_state = 0.f;
    __syncthreads();

    for (int t = 0; t < 256; ++t) {
        // A-fragments: h[kt*32 + lq*8 .. +8] -> broadcast read per 16-lane group
        uint4 ha[8];
#pragma unroll
        for (int kt = 0; kt < 8; ++kt) ha[kt] = h2v[kt * 4 + lq];

        v4f acc[8];
#pragma unroll
        for (int jt = 0; jt < 8; ++jt) acc[jt] = (v4f){0.f, 0.f, 0.f, 0.f};
#pragma unroll
        for (int kt = 0; kt < 8; ++kt) {
            v8h av = *(v8h*)&ha[kt];
#pragma unroll
            for (int jt = 0; jt < 8; ++jt)
                acc[jt] = __builtin_amdgcn_mfma_f32_16x16x32_f16(
                    av, *(v8h*)&wf[jt][kt], acc[jt], 0, 0, 0);
        }
        // D: col = lane&15 (= n within tile), rows redundant -> lanes 0..15, reg 0
        if (lane < 16) {
#pragma unroll
            for (int jt = 0; jt < 8; ++jt)
                gf[(w << 7) + (jt << 4) + lane] = acc[jt][0];
        }
        __syncthreads();

        if (tid < 256) {
            int j = tid;
            float4 gv = *(const float4*)&gf[j << 2];
            h2t p0 = u2h(gi.x), p1 = u2h(gi.y);
            float ig = (float)p0.x + gv.x;
            float fg = (float)p0.y + gv.y;
            float gg = (float)p1.x + gv.z;
            float og = (float)p1.y + gv.w;
            c_state = fsigm(fg) * c_state + fsigm(ig) * ftanh_(gg);
            float h = fsigm(og) * ftanh_(c_state);
            HALL16[((size_t)(b * 256 + t)) * 256 + j] = (_Float16)h;
            U32H2 hxp; hxp.h = h2t{(_Float16)h, (_Float16)0.f};
            unsigned int hu = hxp.u & 0xffffu;
            unsigned int other = (unsigned int)__shfl_xor((int)hu, 1);
            if ((j & 1) == 0) h2_s[j >> 1] = hu | (other << 16);
            int tn = (t < 255) ? (t + 1) : 255;
            gi = *(const uint2*)(ginb + (size_t)tn * 1024 + j * 4);
        }
        __syncthreads();
    }
}

// ---------------------------------------------------------------------------
// Pointer logits: out[b,t,i] = vsum - 2 * sum_d v_d / (1 + exp2(s_d)),
// s = 2.88539*(hp+ep) (scale folded into LDS staging).
// ---------------------------------------------------------------------------
__global__ __launch_bounds__(256) void pointer_kernel(
    const float* __restrict__ HP, const float* __restrict__ EP,
    const float* __restrict__ v, float* __restrict__ out)
{
    int b = blockIdx.z, tt = blockIdx.y, it = blockIdx.x;
    __shared__ float hp_s[16][260];
    __shared__ float ep_s[16][260];
    __shared__ float v_s[256];
    __shared__ float red[4];
    int tid = threadIdx.x;
    const float cs = 2.88539008f;
    const float* hpb = HP + ((size_t)b * 256 + tt * 16) * 256;
    const float* epb = EP + ((size_t)b * 256 + it * 16) * 256;
#pragma unroll
    for (int l = 0; l < 4; ++l) {
        int idx = tid + l * 256;
        int r = idx >> 6, c4 = idx & 63;
        float4 hv = *(const float4*)(hpb + r * 256 + c4 * 4);
        hv.x *= cs; hv.y *= cs; hv.z *= cs; hv.w *= cs;
        *(float4*)&hp_s[r][c4 * 4] = hv;
        float4 ev = *(const float4*)(epb + r * 256 + c4 * 4);
        ev.x *= cs; ev.y *= cs; ev.z *= cs; ev.w *= cs;
        *(float4*)&ep_s[r][c4 * 4] = ev;
    }
    float vv = v[tid];
    v_s[tid] = vv;
    float vp = vv;
#pragma unroll
    for (int m = 1; m < 64; m <<= 1) vp += __shfl_xor(vp, m);
    if ((tid & 63) == 0) red[tid >> 6] = vp;
    __syncthreads();
    float vsum = red[0] + red[1] + red[2] + red[3];
    int tl = tid >> 4, il = tid & 15;
    float acc = 0.f;
#pragma unroll 4
    for (int d = 0; d < 256; ++d) {
        float sval = hp_s[tl][d] + ep_s[il][d];
        float r = frcp(1.0f + fexp2(sval));
        acc = fmaf(v_s[d], r, acc);
    }
    out[((size_t)b * 256 + tt * 16 + tl) * 256 + it * 16 + il] =
        vsum - 2.0f * acc;
}

// ---------------------------------------------------------------------------
extern "C" void kernel_launch(void* const* d_in, const int* in_sizes, int n_in,
                              void* d_out, int out_size, void* d_ws, size_t ws_size,
                              hipStream_t stream)
{
    const float* parts    = (const float*)d_in[0];
    const float* bin_info = (const float*)d_in[1];
    const int*   target   = (const int*)d_in[2];
    const float* pe_W1 = (const float*)d_in[3];
    const float* pe_b1 = (const float*)d_in[4];
    const float* pe_W2 = (const float*)d_in[5];
    const float* pe_b2 = (const float*)d_in[6];
    const float* be_W1 = (const float*)d_in[7];
    const float* be_b1 = (const float*)d_in[8];
    const float* be_W2 = (const float*)d_in[9];
    const float* be_b2 = (const float*)d_in[10];
    const float* pos_emb = (const float*)d_in[11];
    const float* tr_Wqkv = (const float*)d_in[12];
    const float* tr_bqkv = (const float*)d_in[13];
    const float* tr_Wo   = (const float*)d_in[14];
    const float* tr_bo   = (const float*)d_in[15];
    const float* tr_ln1_g = (const float*)d_in[16];
    const float* tr_ln1_b = (const float*)d_in[17];
    const float* tr_ff_W1 = (const float*)d_in[18];
    const float* tr_ff_b1 = (const float*)d_in[19];
    const float* tr_ff_W2 = (const float*)d_in[20];
    const float* tr_ff_b2 = (const float*)d_in[21];
    const float* tr_ln2_g = (const float*)d_in[22];
    const float* tr_ln2_b = (const float*)d_in[23];
    const float* lstm_Wih = (const float*)d_in[24];
    const float* lstm_Whh = (const float*)d_in[25];
    const float* lstm_bih = (const float*)d_in[26];
    const float* lstm_bhh = (const float*)d_in[27];
    const float* ptr_W = (const float*)d_in[28];
    const float* ptr_b = (const float*)d_in[29];
    const float* ptr_v = (const float*)d_in[30];

    // ---- workspace layout (floats) ----
    float* ws = (float*)d_ws;
    float* X     = ws;                        // 2,097,152
    float* S1    = X + 2097152;               // 8,388,608 (qkv/ff1/g_in f16)
    float* CF32  = S1 + 8388608;              // 2,097,152
    float* EPROJ = CF32 + 2097152;            // 2,097,152
    float* X16f  = EPROJ + 2097152;           // 1,048,576
    float* S2f   = X16f + 1048576;            // 1,048,576
    float* W16f  = S2f + 1048576;             // 1,048,576
    float* WBf   = W16f + 1048576;            // 131,072
    float* BBuf  = WBf + 131072;              // 2,048 (unused)
    float* PB    = BBuf + 2048;               // 1,024

    _Float16* X16    = (_Float16*)X16f;
    _Float16* Xg16   = X16;
    _Float16* S2h    = (_Float16*)S2f;
    _Float16* HALL16 = S2h;
    _Float16* S1h    = (_Float16*)S1;
    _Float16* W16    = (_Float16*)W16f;
    _Float16* Wqkv16 = W16;                   // 589,824
    _Float16* Wo16   = Wqkv16 + 589824;       // 196,608
    _Float16* Wff116 = Wo16 + 196608;         // 393,216
    _Float16* Wff216 = Wff116 + 393216;       // 393,216
    _Float16* Wih16  = Wff216 + 393216;       // 262,144 (gate-interleaved rows)
    _Float16* WpW16  = Wih16 + 262144;        // 65,536

    // ---- one-time weight conversions (single fused launch) ----
    cvt_fused_kernel<<<7936, 256, 0, stream>>>(
        tr_Wqkv, tr_Wo, tr_ff_W1, tr_ff_W2, lstm_Wih, ptr_W, W16,
        lstm_Whh, (unsigned int*)WBf, lstm_bih, lstm_bhh, PB);

    // ---- encoders (bin fused into part) ----
    part_enc_kernel<<<256, 128, 0, stream>>>(parts, pe_W1, pe_b1, pe_W2, pe_b2,
                                             bin_info, be_W1, be_b1, be_W2, be_b2,
                                             pos_emb, X, X16);

    // ---- transformer layers ----
    for (int l = 0; l < 3; ++l) {
        hgemm_kernel<64, 128, false, true><<<dim3(128, 6), 256, 0, stream>>>(
            X16, Wqkv16 + (size_t)l * 196608, tr_bqkv + l * 768, nullptr,
            S1h, 8192, 768, 256);
        attn_mfma_kernel<<<256, 256, 0, stream>>>(S1h, S2h);
        hgemm_ln_kernel<<<128, 256, 0, stream>>>(
            S2h, Wo16 + (size_t)l * 65536, tr_bo + l * 256,
            tr_ln1_g + l * 256, tr_ln1_b + l * 256, X, X16, 256);
        hgemm_kernel<64, 128, true, true><<<dim3(128, 4), 256, 0, stream>>>(
            X16, Wff116 + (size_t)l * 131072, tr_ff_b1 + l * 512, nullptr,
            S1h, 8192, 512, 256);
        hgemm_ln_kernel<<<128, 256, 0, stream>>>(
            S1h, Wff216 + (size_t)l * 131072, tr_ff_b2 + l * 256,
            tr_ln2_g + l * 256, tr_ln2_b + l * 256, X, X16, 512);
    }

    // ---- pointer decode ----
    hgemm_kernel<64, 64, false, false><<<dim3(128, 4), 256, 0, stream>>>(
        X16, WpW16, ptr_b, nullptr, EPROJ, 8192, 256, 256);
    gather_kernel<<<8192, 256, 0, stream>>>(X, target, Xg16);
    hgemm_kernel<64, 128, false, true><<<dim3(128, 8), 256, 0, stream>>>(
        Xg16, Wih16, PB, nullptr, S1h, 8192, 1024, 256);
    lstm_kernel<<<32, 512, 0, stream>>>(S1h, (const uint4*)WBf, HALL16);
    hgemm_kernel<64, 64, false, false><<<dim3(128, 4), 256, 0, stream>>>(
        HALL16, WpW16, ptr_b, nullptr, CF32, 8192, 256, 256);
    pointer_kernel<<<dim3(16, 16, 32), 256, 0, stream>>>(CF32, EPROJ, ptr_v,
                                                         (float*)d_out);
}

// Round 4
// 1635.840 us; speedup vs baseline: 1.0572x; 1.0572x over previous
//
#include <hip/hip_runtime.h>
#include <cstddef>

#define DEV __device__ __forceinline__

DEV float fexp2(float x) { return __builtin_amdgcn_exp2f(x); }
DEV float frcp(float x)  { return __builtin_amdgcn_rcpf(x); }
DEV float fsigm(float x) { return frcp(1.0f + fexp2(-1.44269504f * x)); }
DEV float ftanh_(float x){ return 1.0f - 2.0f * frcp(1.0f + fexp2(2.88539008f * x)); }

typedef _Float16 h2t __attribute__((ext_vector_type(2)));
typedef _Float16 v8h __attribute__((ext_vector_type(8)));
typedef float v4f __attribute__((ext_vector_type(4)));
union U32H2 { unsigned int u; h2t h; };
DEV h2t u2h(unsigned int u) { U32H2 x; x.u = u; return x.h; }

// ---------------------------------------------------------------------------
// f16 MFMA GEMM: C[M,N] = A[M,K] @ W[N,K]^T + bias; A,W f16 row-major.
// BM in {64,128}, BK=32, 256 threads (4 waves, 2x2), wave tile (BM/2)x(BN/2).
// ---------------------------------------------------------------------------
template <int BM, int BN, bool RELU, bool OUTF16>
__global__ __launch_bounds__(256) void hgemm_kernel(
    const _Float16* __restrict__ A, const _Float16* __restrict__ W,
    const float* __restrict__ bias1, const float* __restrict__ bias2,
    void* __restrict__ Cout, int M, int N, int K)
{
    constexpr int MT = BM / 32;
    constexpr int NT = BN / 32;
    constexpr int RA = BM / 64;
    constexpr int RB = BN / 64;
    __shared__ _Float16 As[BM * 32];
    __shared__ _Float16 Bs[BN * 32];

    const int tid = threadIdx.x;
    const int lane = tid & 63;
    const int lm = lane & 15, lq = lane >> 4;
    const int wrow = ((tid >> 6) & 1) * (BM / 2);
    const int wcol = (tid >> 7) * (BN / 2);
    const int m0 = blockIdx.x * BM, n0 = blockIdx.y * BN;
    const _Float16* Ab = A + (size_t)m0 * K;
    const _Float16* Wb = W + (size_t)n0 * K;

    v4f acc[MT][NT];
#pragma unroll
    for (int i = 0; i < MT; ++i)
#pragma unroll
        for (int j = 0; j < NT; ++j) acc[i][j] = (v4f){0.f, 0.f, 0.f, 0.f};

    const int rowS = tid >> 2, qS = tid & 3;

    uint4 ra[RA], rb[RB];
#pragma unroll
    for (int r = 0; r < RA; ++r)
        ra[r] = *(const uint4*)(Ab + (size_t)(rowS + 64 * r) * K + qS * 8);
#pragma unroll
    for (int r = 0; r < RB; ++r)
        rb[r] = *(const uint4*)(Wb + (size_t)(rowS + 64 * r) * K + qS * 8);

    for (int k0 = 0; k0 < K; k0 += 32) {
        __syncthreads();
#pragma unroll
        for (int r = 0; r < RA; ++r)
            *(uint4*)(As + (size_t)(tid + 256 * r) * 8) = ra[r];
#pragma unroll
        for (int r = 0; r < RB; ++r)
            *(uint4*)(Bs + (size_t)(tid + 256 * r) * 8) = rb[r];
        __syncthreads();
        int kn = k0 + 32;
        if (kn < K) {
#pragma unroll
            for (int r = 0; r < RA; ++r)
                ra[r] = *(const uint4*)(Ab + (size_t)(rowS + 64 * r) * K + kn + qS * 8);
#pragma unroll
            for (int r = 0; r < RB; ++r)
                rb[r] = *(const uint4*)(Wb + (size_t)(rowS + 64 * r) * K + kn + qS * 8);
        }
        v8h af[MT], bf[NT];
#pragma unroll
        for (int i = 0; i < MT; ++i)
            af[i] = *(const v8h*)(As + (size_t)(wrow + i * 16 + lm) * 32 + lq * 8);
#pragma unroll
        for (int j = 0; j < NT; ++j)
            bf[j] = *(const v8h*)(Bs + (size_t)(wcol + j * 16 + lm) * 32 + lq * 8);
#pragma unroll
        for (int i = 0; i < MT; ++i)
#pragma unroll
            for (int j = 0; j < NT; ++j)
                acc[i][j] = __builtin_amdgcn_mfma_f32_16x16x32_f16(
                    af[i], bf[j], acc[i][j], 0, 0, 0);
    }

#pragma unroll
    for (int j = 0; j < NT; ++j) {
        int col = n0 + wcol + j * 16 + lm;
        float bv = bias1[col];
        if (bias2) bv += bias2[col];
#pragma unroll
        for (int i = 0; i < MT; ++i) {
            int rbase = m0 + wrow + i * 16 + lq * 4;
#pragma unroll
            for (int rg = 0; rg < 4; ++rg) {
                float vv = acc[i][j][rg] + bv;
                if (RELU) vv = fmaxf(vv, 0.f);
                if (OUTF16)
                    ((_Float16*)Cout)[(size_t)(rbase + rg) * N + col] = (_Float16)vv;
                else
                    ((float*)Cout)[(size_t)(rbase + rg) * N + col] = vv;
            }
        }
    }
}

// ---------------------------------------------------------------------------
// GEMM (N=256 fixed) + bias + residual + LayerNorm fused.
// Out: X (f32, in-place residual target) and X16 (f16 copy).
// BM=64, BN=256, 256 threads (4 waves, 2x2), wave tile 32x128.
// ---------------------------------------------------------------------------
__global__ __launch_bounds__(256) void hgemm_ln_kernel(
    const _Float16* __restrict__ A, const _Float16* __restrict__ W,
    const float* __restrict__ bias, const float* __restrict__ gamma,
    const float* __restrict__ beta, float* __restrict__ X,
    _Float16* __restrict__ X16, int K)
{
    constexpr int BM = 64, BN = 256, MT = 2, NT = 8, RA = 1, RB = 4;
    __shared__ _Float16 As[BM * 32];
    __shared__ _Float16 Bs[BN * 32];
    __shared__ float redS[2][BM][2];

    const int tid = threadIdx.x;
    const int lane = tid & 63;
    const int lm = lane & 15, lq = lane >> 4;
    const int wrow = ((tid >> 6) & 1) * 32;
    const int wcol = (tid >> 7) * 128;
    const int half = tid >> 7;
    const int m0 = blockIdx.x * BM;
    const _Float16* Ab = A + (size_t)m0 * K;

    v4f acc[MT][NT];
#pragma unroll
    for (int i = 0; i < MT; ++i)
#pragma unroll
        for (int j = 0; j < NT; ++j) acc[i][j] = (v4f){0.f, 0.f, 0.f, 0.f};

    const int rowS = tid >> 2, qS = tid & 3;

    uint4 ra[RA], rb[RB];
#pragma unroll
    for (int r = 0; r < RA; ++r)
        ra[r] = *(const uint4*)(Ab + (size_t)(rowS + 64 * r) * K + qS * 8);
#pragma unroll
    for (int r = 0; r < RB; ++r)
        rb[r] = *(const uint4*)(W + (size_t)(rowS + 64 * r) * K + qS * 8);

    for (int k0 = 0; k0 < K; k0 += 32) {
        __syncthreads();
#pragma unroll
        for (int r = 0; r < RA; ++r)
            *(uint4*)(As + (size_t)(tid + 256 * r) * 8) = ra[r];
#pragma unroll
        for (int r = 0; r < RB; ++r)
            *(uint4*)(Bs + (size_t)(tid + 256 * r) * 8) = rb[r];
        __syncthreads();
        int kn = k0 + 32;
        if (kn < K) {
#pragma unroll
            for (int r = 0; r < RA; ++r)
                ra[r] = *(const uint4*)(Ab + (size_t)(rowS + 64 * r) * K + kn + qS * 8);
#pragma unroll
            for (int r = 0; r < RB; ++r)
                rb[r] = *(const uint4*)(W + (size_t)(rowS + 64 * r) * K + kn + qS * 8);
        }
        v8h af[MT], bf[NT];
#pragma unroll
        for (int i = 0; i < MT; ++i)
            af[i] = *(const v8h*)(As + (size_t)(wrow + i * 16 + lm) * 32 + lq * 8);
#pragma unroll
        for (int j = 0; j < NT; ++j)
            bf[j] = *(const v8h*)(Bs + (size_t)(wcol + j * 16 + lm) * 32 + lq * 8);
#pragma unroll
        for (int i = 0; i < MT; ++i)
#pragma unroll
            for (int j = 0; j < NT; ++j)
                acc[i][j] = __builtin_amdgcn_mfma_f32_16x16x32_f16(
                    af[i], bf[j], acc[i][j], 0, 0, 0);
    }

    // y = gemm + bias + residual; accumulate per-row sums
    float s[MT][4], s2[MT][4];
#pragma unroll
    for (int i = 0; i < MT; ++i)
#pragma unroll
        for (int rg = 0; rg < 4; ++rg) { s[i][rg] = 0.f; s2[i][rg] = 0.f; }
#pragma unroll
    for (int j = 0; j < NT; ++j) {
        int col = wcol + j * 16 + lm;
        float bv = bias[col];
#pragma unroll
        for (int i = 0; i < MT; ++i) {
            int rbase = m0 + wrow + i * 16 + lq * 4;
#pragma unroll
            for (int rg = 0; rg < 4; ++rg) {
                float y = acc[i][j][rg] + bv + X[(size_t)(rbase + rg) * 256 + col];
                acc[i][j][rg] = y;
                s[i][rg] += y;
                s2[i][rg] += y * y;
            }
        }
    }
    // reduce across the 16 lm lanes (same row), publish per-half partials
#pragma unroll
    for (int i = 0; i < MT; ++i)
#pragma unroll
        for (int rg = 0; rg < 4; ++rg) {
            float a = s[i][rg], b2 = s2[i][rg];
#pragma unroll
            for (int m = 1; m < 16; m <<= 1) {
                a += __shfl_xor(a, m);
                b2 += __shfl_xor(b2, m);
            }
            if (lm == 0) {
                int rloc = wrow + i * 16 + lq * 4 + rg;
                redS[half][rloc][0] = a;
                redS[half][rloc][1] = b2;
            }
        }
    __syncthreads();
#pragma unroll
    for (int i = 0; i < MT; ++i) {
#pragma unroll
        for (int rg = 0; rg < 4; ++rg) {
            int rloc = wrow + i * 16 + lq * 4 + rg;
            float st = redS[0][rloc][0] + redS[1][rloc][0];
            float s2t = redS[0][rloc][1] + redS[1][rloc][1];
            float mean = st * (1.f / 256.f);
            float var = s2t * (1.f / 256.f) - mean * mean;
            float inv = rsqrtf(var + 1e-5f);
            size_t rowb = (size_t)(m0 + rloc) * 256;
#pragma unroll
            for (int j = 0; j < NT; ++j) {
                int col = wcol + j * 16 + lm;
                float o = (acc[i][j][rg] - mean) * inv * gamma[col] + beta[col];
                X[rowb + col] = o;
                X16[rowb + col] = (_Float16)o;
            }
        }
    }
}

// ---------------------------------------------------------------------------
// Fused weight conversion (cvt_all + Whh MFMA-fragment blob + permuted bias).
// Wih dest rows are gate-interleaved: dest row j*4+g = src row g*256+j.
// Whh blob: B-fragments for mfma_f32_16x16x32_f16. Fragment (w,jt,kt):
//   word idx = (((w*8+jt)*8+kt)*64 + lane)*4 + wd
//   n = w*128 + jt*16 + (lane&15)   (logical gate index, = j*4+g)
//   k = kt*32 + (lane>>4)*8 + wd*2  (+0,+1 packed)
//   src row = (n&3)*256 + (n>>2)
// ---------------------------------------------------------------------------
__global__ __launch_bounds__(256) void cvt_fused_kernel(
    const float* __restrict__ s0, const float* __restrict__ s1,
    const float* __restrict__ s2, const float* __restrict__ s3,
    const float* __restrict__ s4, const float* __restrict__ s5,
    _Float16* __restrict__ dst,
    const float* __restrict__ Whh, unsigned int* __restrict__ WB,
    const float* __restrict__ bih, const float* __restrict__ bhh,
    float* __restrict__ PB)
{
    if (blockIdx.x < 7424) {
        int i = blockIdx.x * 256 + threadIdx.x;
        if (i >= 1900544) return;
        float val;
        if (i < 589824)       val = s0[i];
        else if (i < 786432)  val = s1[i - 589824];
        else if (i < 1179648) val = s2[i - 786432];
        else if (i < 1572864) val = s3[i - 1179648];
        else if (i < 1835008) {
            int idx = i - 1572864;
            int rp = idx >> 8, k = idx & 255;
            int j = rp >> 2, g = rp & 3;
            val = s4[(g * 256 + j) * 256 + k];
        }
        else                  val = s5[i - 1835008];
        dst[i] = (_Float16)val;
    } else {
        int idx = (blockIdx.x - 7424) * 256 + threadIdx.x;  // 0..131071
        if (idx < 1024) {
            int j = idx >> 2, g = idx & 3;
            PB[idx] = bih[g * 256 + j] + bhh[g * 256 + j];
        }
        int wd   = idx & 3;
        int lane = (idx >> 2) & 63;
        int kt   = (idx >> 8) & 7;
        int jt   = (idx >> 11) & 7;
        int w    = (idx >> 14) & 7;
        int n = w * 128 + jt * 16 + (lane & 15);
        int src_r = (n & 3) * 256 + (n >> 2);
        int k = kt * 32 + ((lane >> 4) << 3) + (wd << 1);
        _Float16 lo = (_Float16)Whh[src_r * 256 + k];
        _Float16 hi = (_Float16)Whh[src_r * 256 + k + 1];
        U32H2 x; x.h = h2t{lo, hi};
        WB[idx] = x.u;
    }
}

// ---------------------------------------------------------------------------
// Part encoder with bin-encoder fused (bb computed redundantly per block).
// ---------------------------------------------------------------------------
__global__ __launch_bounds__(128) void part_enc_kernel(
    const float* __restrict__ parts, const float* __restrict__ W1,
    const float* __restrict__ b1, const float* __restrict__ W2,
    const float* __restrict__ b2, const float* __restrict__ bin_info,
    const float* __restrict__ be_W1, const float* __restrict__ be_b1,
    const float* __restrict__ be_W2, const float* __restrict__ be_b2,
    const float* __restrict__ pos_emb, float* __restrict__ X,
    _Float16* __restrict__ X16)
{
    __shared__ float W2s[128][129];
    __shared__ float h1[128];
    __shared__ float pin[16];
    __shared__ float h1b[64];
    __shared__ float bb_s[64];
    int tid = threadIdx.x;
    int b = blockIdx.x >> 3, s0 = (blockIdx.x & 7) * 32;
    for (int l = 0; l < 128; ++l) W2s[l][tid] = W2[l * 128 + tid];
    // bin encoder (64-dim MLP, redundant per block, trivial)
    {
        float x0 = bin_info[b * 2], x1 = bin_info[b * 2 + 1];
        if (tid < 64)
            h1b[tid] = fmaxf(be_W1[tid * 2] * x0 + be_W1[tid * 2 + 1] * x1
                             + be_b1[tid], 0.f);
        __syncthreads();
        if (tid < 64) {
            float a = be_b2[tid];
#pragma unroll 4
            for (int e = 0; e < 64; ++e) a += be_W2[tid * 64 + e] * h1b[e];
            bb_s[tid] = a;
        }
        __syncthreads();
    }
    float w1r[16];
#pragma unroll
    for (int k = 0; k < 16; ++k) w1r[k] = W1[tid * 16 + k];
    float bias1v = b1[tid], bias2v = b2[tid];
    for (int si = 0; si < 32; ++si) {
        int s = s0 + si;
        size_t row = (size_t)b * 256 + s;
        if (tid < 16) pin[tid] = parts[row * 16 + tid];
        __syncthreads();
        float h = bias1v;
#pragma unroll
        for (int k = 0; k < 16; ++k) h += w1r[k] * pin[k];
        h1[tid] = fmaxf(h, 0.f);
        __syncthreads();
        float acc = bias2v;
#pragma unroll 4
        for (int e = 0; e < 128; ++e) acc += W2s[tid][e] * h1[e];
        X[row * 256 + tid] = acc;
        X16[row * 256 + tid] = (_Float16)acc;
        if (tid < 64) {
            float bbv = bb_s[tid];
            float pev = pos_emb[s * 64 + tid];
            X[row * 256 + 128 + tid] = bbv;
            X[row * 256 + 192 + tid] = pev;
            X16[row * 256 + 128 + tid] = (_Float16)bbv;
            X16[row * 256 + 192 + tid] = (_Float16)pev;
        }
        __syncthreads();
    }
}

// ---------------------------------------------------------------------------
// MFMA attention: one block per (b,h), 256 threads (4 waves).
// ---------------------------------------------------------------------------
__global__ __launch_bounds__(256) void attn_mfma_kernel(
    const _Float16* __restrict__ QKV, _Float16* __restrict__ O16)
{
    int bh = blockIdx.x;
    int b = bh >> 3, h = bh & 7;
    const int tid = threadIdx.x;
    const int w = tid >> 6;
    const int lane = tid & 63;
    const int lm = lane & 15, lq = lane >> 4;
    const float c_se = 0.17677669529663687f * 1.44269504f;

    __shared__ _Float16 Ks[4][256][8];
    __shared__ _Float16 Vt[32][264];
    __shared__ _Float16 Ps[4][16][264];

    const _Float16* qkvb = QKV + (size_t)(b * 256) * 768 + h * 32;
    {
        int s = tid;
        const _Float16* kr = qkvb + (size_t)s * 768 + 256;
#pragma unroll
        for (int c = 0; c < 4; ++c)
            *(uint4*)&Ks[c][s][0] = *(const uint4*)(kr + c * 8);
        const _Float16* vr = qkvb + (size_t)s * 768 + 512;
        _Float16 vtmp[32];
        *(uint4*)&vtmp[0]  = *(const uint4*)(vr);
        *(uint4*)&vtmp[8]  = *(const uint4*)(vr + 8);
        *(uint4*)&vtmp[16] = *(const uint4*)(vr + 16);
        *(uint4*)&vtmp[24] = *(const uint4*)(vr + 24);
#pragma unroll
        for (int d = 0; d < 32; ++d) Vt[d][s] = vtmp[d];
    }
    __syncthreads();

#pragma unroll 1
    for (int st = 0; st < 4; ++st) {
        int rt = w * 4 + st;
        v8h qf = *(const v8h*)(QKV + (size_t)(b * 256 + rt * 16 + lm) * 768
                               + h * 32 + lq * 8);
        v4f acc[16];
#pragma unroll
        for (int ct = 0; ct < 16; ++ct) {
            v8h kf = *(const v8h*)&Ks[lq][ct * 16 + lm][0];
            acc[ct] = __builtin_amdgcn_mfma_f32_16x16x32_f16(
                qf, kf, (v4f){0.f, 0.f, 0.f, 0.f}, 0, 0, 0);
        }
        float sminv[4];
#pragma unroll
        for (int r = 0; r < 4; ++r) {
            float m = acc[0][r];
#pragma unroll
            for (int ct = 1; ct < 16; ++ct) m = fmaxf(m, acc[ct][r]);
#pragma unroll
            for (int msk = 1; msk < 16; msk <<= 1)
                m = fmaxf(m, __shfl_xor(m, msk));
            float ssum = 0.f;
#pragma unroll
            for (int ct = 0; ct < 16; ++ct) {
                float e = fexp2((acc[ct][r] - m) * c_se);
                acc[ct][r] = e;
                ssum += e;
            }
#pragma unroll
            for (int msk = 1; msk < 16; msk <<= 1)
                ssum += __shfl_xor(ssum, msk);
            sminv[r] = frcp(ssum);
        }
#pragma unroll
        for (int ct = 0; ct < 16; ++ct)
#pragma unroll
            for (int r = 0; r < 4; ++r)
                Ps[w][lq * 4 + r][ct * 16 + lm] =
                    (_Float16)(acc[ct][r] * sminv[r]);
#pragma unroll
        for (int dt = 0; dt < 2; ++dt) {
            v4f o = (v4f){0.f, 0.f, 0.f, 0.f};
#pragma unroll
            for (int jc = 0; jc < 8; ++jc) {
                v8h pf = *(const v8h*)&Ps[w][lm][jc * 32 + lq * 8];
                v8h vf = *(const v8h*)&Vt[dt * 16 + lm][jc * 32 + lq * 8];
                o = __builtin_amdgcn_mfma_f32_16x16x32_f16(pf, vf, o, 0, 0, 0);
            }
#pragma unroll
            for (int r = 0; r < 4; ++r)
                O16[(size_t)(b * 256 + rt * 16 + lq * 4 + r) * 256
                    + h * 32 + dt * 16 + lm] = (_Float16)o[r];
        }
    }
}

// ---------------------------------------------------------------------------
__global__ __launch_bounds__(256) void gather_kernel(
    const float* __restrict__ X, const int* __restrict__ target,
    _Float16* __restrict__ Xg16)
{
    int row = blockIdx.x;
    int b = row >> 8, t = row & 255;
    int d = threadIdx.x;
    float val = 0.f;
    if (t > 0) {
        int src = target[b * 256 + t - 1];
        val = X[((size_t)b * 256 + src) * 256 + d];
    }
    Xg16[(size_t)row * 256 + d] = (_Float16)val;
}

// ---------------------------------------------------------------------------
// LSTM recurrence via MFMA: 1 block/batch, 512 threads (8 waves).
// Whole Whh register-resident as wave-stationary B-fragments: v8h wf[8][8]
// = 256 regs/thread in the unified VGPR+AGPR file (launch_bounds 2 waves/EU
// -> 512-reg budget). No address-punning anywhere near wf so SROA promotes
// it (the R3 uint4/&-cast version went to scratch: VGPR=128, +3.8MB scratch
// traffic/dispatch, 963us). A = h broadcast to 16 rows (row-redundant).
// ---------------------------------------------------------------------------
__global__ __launch_bounds__(512, 2) void lstm_kernel(
    const _Float16* __restrict__ g_in, const uint4* __restrict__ WB4,
    _Float16* __restrict__ HALL16)
{
    const int b = blockIdx.x;
    const int tid = threadIdx.x;
    const int w = tid >> 6;
    const int lane = tid & 63;
    const int lq = lane >> 4;

    __shared__ float gf[1024];         // 4 KB gate staging
    __shared__ uint4 h2v[32];          // 512 B packed h (f16 pairs)
    unsigned int* h2_s = (unsigned int*)h2v;

    // stationary B-fragments, loaded as v8h (no type-punned element address)
    const v8h* __restrict__ WBv = (const v8h*)WB4;
    v8h wf[8][8];
#pragma unroll
    for (int jt = 0; jt < 8; ++jt)
#pragma unroll
        for (int kt = 0; kt < 8; ++kt)
            wf[jt][kt] = WBv[((((w << 3) + jt) << 3) + kt) * 64 + lane];

    if (tid < 128) h2_s[tid] = 0u;

    const _Float16* ginb = g_in + (size_t)b * 256 * 1024;
    uint2 gi = make_uint2(0u, 0u);
    if (tid < 256) gi = *(const uint2*)(ginb + tid * 4);
    float c_state = 0.f;
    __syncthreads();

    for (int t = 0; t < 256; ++t) {
        // A-fragments: h[kt*32 + lq*8 .. +8], broadcast within 16-lane groups
        v8h av[8];
#pragma unroll
        for (int kt = 0; kt < 8; ++kt)
            av[kt] = *(const v8h*)&h2v[kt * 4 + lq];

        v4f acc[8];
#pragma unroll
        for (int jt = 0; jt < 8; ++jt) acc[jt] = (v4f){0.f, 0.f, 0.f, 0.f};
#pragma unroll
        for (int kt = 0; kt < 8; ++kt) {
#pragma unroll
            for (int jt = 0; jt < 8; ++jt)
                acc[jt] = __builtin_amdgcn_mfma_f32_16x16x32_f16(
                    av[kt], wf[jt][kt], acc[jt], 0, 0, 0);
        }
        // D: col = lane&15 (= n within tile), rows redundant -> lanes 0..15
        if (lane < 16) {
#pragma unroll
            for (int jt = 0; jt < 8; ++jt)
                gf[(w << 7) + (jt << 4) + lane] = acc[jt][0];
        }
        __syncthreads();

        if (tid < 256) {
            int j = tid;
            float4 gv = *(const float4*)&gf[j << 2];
            h2t p0 = u2h(gi.x), p1 = u2h(gi.y);
            float ig = (float)p0.x + gv.x;
            float fg = (float)p0.y + gv.y;
            float gg = (float)p1.x + gv.z;
            float og = (float)p1.y + gv.w;
            c_state = fsigm(fg) * c_state + fsigm(ig) * ftanh_(gg);
            float h = fsigm(og) * ftanh_(c_state);
            HALL16[((size_t)(b * 256 + t)) * 256 + j] = (_Float16)h;
            U32H2 hxp; hxp.h = h2t{(_Float16)h, (_Float16)0.f};
            unsigned int hu = hxp.u & 0xffffu;
            unsigned int other = (unsigned int)__shfl_xor((int)hu, 1);
            if ((j & 1) == 0) h2_s[j >> 1] = hu | (other << 16);
            int tn = (t < 255) ? (t + 1) : 255;
            gi = *(const uint2*)(ginb + (size_t)tn * 1024 + j * 4);
        }
        __syncthreads();
    }
}

// ---------------------------------------------------------------------------
// Pointer logits: out[b,t,i] = vsum - 2 * sum_d v_d / (1 + exp2(s_d)),
// s = 2.88539*(hp+ep) (scale folded into LDS staging).
// ---------------------------------------------------------------------------
__global__ __launch_bounds__(256) void pointer_kernel(
    const float* __restrict__ HP, const float* __restrict__ EP,
    const float* __restrict__ v, float* __restrict__ out)
{
    int b = blockIdx.z, tt = blockIdx.y, it = blockIdx.x;
    __shared__ float hp_s[16][260];
    __shared__ float ep_s[16][260];
    __shared__ float v_s[256];
    __shared__ float red[4];
    int tid = threadIdx.x;
    const float cs = 2.88539008f;
    const float* hpb = HP + ((size_t)b * 256 + tt * 16) * 256;
    const float* epb = EP + ((size_t)b * 256 + it * 16) * 256;
#pragma unroll
    for (int l = 0; l < 4; ++l) {
        int idx = tid + l * 256;
        int r = idx >> 6, c4 = idx & 63;
        float4 hv = *(const float4*)(hpb + r * 256 + c4 * 4);
        hv.x *= cs; hv.y *= cs; hv.z *= cs; hv.w *= cs;
        *(float4*)&hp_s[r][c4 * 4] = hv;
        float4 ev = *(const float4*)(epb + r * 256 + c4 * 4);
        ev.x *= cs; ev.y *= cs; ev.z *= cs; ev.w *= cs;
        *(float4*)&ep_s[r][c4 * 4] = ev;
    }
    float vv = v[tid];
    v_s[tid] = vv;
    float vp = vv;
#pragma unroll
    for (int m = 1; m < 64; m <<= 1) vp += __shfl_xor(vp, m);
    if ((tid & 63) == 0) red[tid >> 6] = vp;
    __syncthreads();
    float vsum = red[0] + red[1] + red[2] + red[3];
    int tl = tid >> 4, il = tid & 15;
    float acc = 0.f;
#pragma unroll 4
    for (int d = 0; d < 256; ++d) {
        float sval = hp_s[tl][d] + ep_s[il][d];
        float r = frcp(1.0f + fexp2(sval));
        acc = fmaf(v_s[d], r, acc);
    }
    out[((size_t)b * 256 + tt * 16 + tl) * 256 + it * 16 + il] =
        vsum - 2.0f * acc;
}

// ---------------------------------------------------------------------------
extern "C" void kernel_launch(void* const* d_in, const int* in_sizes, int n_in,
                              void* d_out, int out_size, void* d_ws, size_t ws_size,
                              hipStream_t stream)
{
    const float* parts    = (const float*)d_in[0];
    const float* bin_info = (const float*)d_in[1];
    const int*   target   = (const int*)d_in[2];
    const float* pe_W1 = (const float*)d_in[3];
    const float* pe_b1 = (const float*)d_in[4];
    const float* pe_W2 = (const float*)d_in[5];
    const float* pe_b2 = (const float*)d_in[6];
    const float* be_W1 = (const float*)d_in[7];
    const float* be_b1 = (const float*)d_in[8];
    const float* be_W2 = (const float*)d_in[9];
    const float* be_b2 = (const float*)d_in[10];
    const float* pos_emb = (const float*)d_in[11];
    const float* tr_Wqkv = (const float*)d_in[12];
    const float* tr_bqkv = (const float*)d_in[13];
    const float* tr_Wo   = (const float*)d_in[14];
    const float* tr_bo   = (const float*)d_in[15];
    const float* tr_ln1_g = (const float*)d_in[16];
    const float* tr_ln1_b = (const float*)d_in[17];
    const float* tr_ff_W1 = (const float*)d_in[18];
    const float* tr_ff_b1 = (const float*)d_in[19];
    const float* tr_ff_W2 = (const float*)d_in[20];
    const float* tr_ff_b2 = (const float*)d_in[21];
    const float* tr_ln2_g = (const float*)d_in[22];
    const float* tr_ln2_b = (const float*)d_in[23];
    const float* lstm_Wih = (const float*)d_in[24];
    const float* lstm_Whh = (const float*)d_in[25];
    const float* lstm_bih = (const float*)d_in[26];
    const float* lstm_bhh = (const float*)d_in[27];
    const float* ptr_W = (const float*)d_in[28];
    const float* ptr_b = (const float*)d_in[29];
    const float* ptr_v = (const float*)d_in[30];

    // ---- workspace layout (floats) ----
    float* ws = (float*)d_ws;
    float* X     = ws;                        // 2,097,152
    float* S1    = X + 2097152;               // 8,388,608 (qkv/ff1/g_in f16)
    float* CF32  = S1 + 8388608;              // 2,097,152
    float* EPROJ = CF32 + 2097152;            // 2,097,152
    float* X16f  = EPROJ + 2097152;           // 1,048,576
    float* S2f   = X16f + 1048576;            // 1,048,576
    float* W16f  = S2f + 1048576;             // 1,048,576
    float* WBf   = W16f + 1048576;            // 131,072
    float* BBuf  = WBf + 131072;              // 2,048 (unused)
    float* PB    = BBuf + 2048;               // 1,024

    _Float16* X16    = (_Float16*)X16f;
    _Float16* Xg16   = X16;
    _Float16* S2h    = (_Float16*)S2f;
    _Float16* HALL16 = S2h;
    _Float16* S1h    = (_Float16*)S1;
    _Float16* W16    = (_Float16*)W16f;
    _Float16* Wqkv16 = W16;                   // 589,824
    _Float16* Wo16   = Wqkv16 + 589824;       // 196,608
    _Float16* Wff116 = Wo16 + 196608;         // 393,216
    _Float16* Wff216 = Wff116 + 393216;       // 393,216
    _Float16* Wih16  = Wff216 + 393216;       // 262,144 (gate-interleaved rows)
    _Float16* WpW16  = Wih16 + 262144;        // 65,536

    // ---- one-time weight conversions (single fused launch) ----
    cvt_fused_kernel<<<7936, 256, 0, stream>>>(
        tr_Wqkv, tr_Wo, tr_ff_W1, tr_ff_W2, lstm_Wih, ptr_W, W16,
        lstm_Whh, (unsigned int*)WBf, lstm_bih, lstm_bhh, PB);

    // ---- encoders (bin fused into part) ----
    part_enc_kernel<<<256, 128, 0, stream>>>(parts, pe_W1, pe_b1, pe_W2, pe_b2,
                                             bin_info, be_W1, be_b1, be_W2, be_b2,
                                             pos_emb, X, X16);

    // ---- transformer layers ----
    for (int l = 0; l < 3; ++l) {
        hgemm_kernel<64, 128, false, true><<<dim3(128, 6), 256, 0, stream>>>(
            X16, Wqkv16 + (size_t)l * 196608, tr_bqkv + l * 768, nullptr,
            S1h, 8192, 768, 256);
        attn_mfma_kernel<<<256, 256, 0, stream>>>(S1h, S2h);
        hgemm_ln_kernel<<<128, 256, 0, stream>>>(
            S2h, Wo16 + (size_t)l * 65536, tr_bo + l * 256,
            tr_ln1_g + l * 256, tr_ln1_b + l * 256, X, X16, 256);
        hgemm_kernel<64, 128, true, true><<<dim3(128, 4), 256, 0, stream>>>(
            X16, Wff116 + (size_t)l * 131072, tr_ff_b1 + l * 512, nullptr,
            S1h, 8192, 512, 256);
        hgemm_ln_kernel<<<128, 256, 0, stream>>>(
            S1h, Wff216 + (size_t)l * 131072, tr_ff_b2 + l * 256,
            tr_ln2_g + l * 256, tr_ln2_b + l * 256, X, X16, 512);
    }

    // ---- pointer decode ----
    hgemm_kernel<64, 64, false, false><<<dim3(128, 4), 256, 0, stream>>>(
        X16, WpW16, ptr_b, nullptr, EPROJ, 8192, 256, 256);
    gather_kernel<<<8192, 256, 0, stream>>>(X, target, Xg16);
    hgemm_kernel<64, 128, false, true><<<dim3(128, 8), 256, 0, stream>>>(
        Xg16, Wih16, PB, nullptr, S1h, 8192, 1024, 256);
    lstm_kernel<<<32, 512, 0, stream>>>(S1h, (const uint4*)WBf, HALL16);
    hgemm_kernel<64, 64, false, false><<<dim3(128, 4), 256, 0, stream>>>(
        HALL16, WpW16, ptr_b, nullptr, CF32, 8192, 256, 256);
    pointer_kernel<<<dim3(16, 16, 32), 256, 0, stream>>>(CF32, EPROJ, ptr_v,
                                                         (float*)d_out);
}

// Round 5
// 1343.305 us; speedup vs baseline: 1.2874x; 1.2178x over previous
//
#include <hip/hip_runtime.h>
#include <cstddef>

#define DEV __device__ __forceinline__

DEV float fexp2(float x) { return __builtin_amdgcn_exp2f(x); }
DEV float frcp(float x)  { return __builtin_amdgcn_rcpf(x); }
DEV float fsigm(float x) { return frcp(1.0f + fexp2(-1.44269504f * x)); }
DEV float ftanh_(float x){ return 1.0f - 2.0f * frcp(1.0f + fexp2(2.88539008f * x)); }

typedef _Float16 h2t __attribute__((ext_vector_type(2)));
typedef _Float16 v8h __attribute__((ext_vector_type(8)));
typedef float v4f __attribute__((ext_vector_type(4)));
union U32H2 { unsigned int u; h2t h; };
DEV h2t u2h(unsigned int u) { U32H2 x; x.u = u; return x.h; }

// ---------------------------------------------------------------------------
// f16 MFMA GEMM: C[M,N] = A[M,K] @ W[N,K]^T + bias; A,W f16 row-major.
// BM in {64,128}, BK=32, 256 threads (4 waves, 2x2), wave tile (BM/2)x(BN/2).
// ---------------------------------------------------------------------------
template <int BM, int BN, bool RELU, bool OUTF16>
__global__ __launch_bounds__(256) void hgemm_kernel(
    const _Float16* __restrict__ A, const _Float16* __restrict__ W,
    const float* __restrict__ bias1, const float* __restrict__ bias2,
    void* __restrict__ Cout, int M, int N, int K)
{
    constexpr int MT = BM / 32;
    constexpr int NT = BN / 32;
    constexpr int RA = BM / 64;
    constexpr int RB = BN / 64;
    __shared__ _Float16 As[BM * 32];
    __shared__ _Float16 Bs[BN * 32];

    const int tid = threadIdx.x;
    const int lane = tid & 63;
    const int lm = lane & 15, lq = lane >> 4;
    const int wrow = ((tid >> 6) & 1) * (BM / 2);
    const int wcol = (tid >> 7) * (BN / 2);
    const int m0 = blockIdx.x * BM, n0 = blockIdx.y * BN;
    const _Float16* Ab = A + (size_t)m0 * K;
    const _Float16* Wb = W + (size_t)n0 * K;

    v4f acc[MT][NT];
#pragma unroll
    for (int i = 0; i < MT; ++i)
#pragma unroll
        for (int j = 0; j < NT; ++j) acc[i][j] = (v4f){0.f, 0.f, 0.f, 0.f};

    const int rowS = tid >> 2, qS = tid & 3;

    uint4 ra[RA], rb[RB];
#pragma unroll
    for (int r = 0; r < RA; ++r)
        ra[r] = *(const uint4*)(Ab + (size_t)(rowS + 64 * r) * K + qS * 8);
#pragma unroll
    for (int r = 0; r < RB; ++r)
        rb[r] = *(const uint4*)(Wb + (size_t)(rowS + 64 * r) * K + qS * 8);

    for (int k0 = 0; k0 < K; k0 += 32) {
        __syncthreads();
#pragma unroll
        for (int r = 0; r < RA; ++r)
            *(uint4*)(As + (size_t)(tid + 256 * r) * 8) = ra[r];
#pragma unroll
        for (int r = 0; r < RB; ++r)
            *(uint4*)(Bs + (size_t)(tid + 256 * r) * 8) = rb[r];
        __syncthreads();
        int kn = k0 + 32;
        if (kn < K) {
#pragma unroll
            for (int r = 0; r < RA; ++r)
                ra[r] = *(const uint4*)(Ab + (size_t)(rowS + 64 * r) * K + kn + qS * 8);
#pragma unroll
            for (int r = 0; r < RB; ++r)
                rb[r] = *(const uint4*)(Wb + (size_t)(rowS + 64 * r) * K + kn + qS * 8);
        }
        v8h af[MT], bf[NT];
#pragma unroll
        for (int i = 0; i < MT; ++i)
            af[i] = *(const v8h*)(As + (size_t)(wrow + i * 16 + lm) * 32 + lq * 8);
#pragma unroll
        for (int j = 0; j < NT; ++j)
            bf[j] = *(const v8h*)(Bs + (size_t)(wcol + j * 16 + lm) * 32 + lq * 8);
#pragma unroll
        for (int i = 0; i < MT; ++i)
#pragma unroll
            for (int j = 0; j < NT; ++j)
                acc[i][j] = __builtin_amdgcn_mfma_f32_16x16x32_f16(
                    af[i], bf[j], acc[i][j], 0, 0, 0);
    }

#pragma unroll
    for (int j = 0; j < NT; ++j) {
        int col = n0 + wcol + j * 16 + lm;
        float bv = bias1[col];
        if (bias2) bv += bias2[col];
#pragma unroll
        for (int i = 0; i < MT; ++i) {
            int rbase = m0 + wrow + i * 16 + lq * 4;
#pragma unroll
            for (int rg = 0; rg < 4; ++rg) {
                float vv = acc[i][j][rg] + bv;
                if (RELU) vv = fmaxf(vv, 0.f);
                if (OUTF16)
                    ((_Float16*)Cout)[(size_t)(rbase + rg) * N + col] = (_Float16)vv;
                else
                    ((float*)Cout)[(size_t)(rbase + rg) * N + col] = vv;
            }
        }
    }
}

// ---------------------------------------------------------------------------
// GEMM (N=256 fixed) + bias + residual + LayerNorm fused.
// Out: X (f32, in-place residual target) and X16 (f16 copy).
// BM=64, BN=256, 256 threads (4 waves, 2x2), wave tile 32x128.
// ---------------------------------------------------------------------------
__global__ __launch_bounds__(256) void hgemm_ln_kernel(
    const _Float16* __restrict__ A, const _Float16* __restrict__ W,
    const float* __restrict__ bias, const float* __restrict__ gamma,
    const float* __restrict__ beta, float* __restrict__ X,
    _Float16* __restrict__ X16, int K)
{
    constexpr int BM = 64, BN = 256, MT = 2, NT = 8, RA = 1, RB = 4;
    __shared__ _Float16 As[BM * 32];
    __shared__ _Float16 Bs[BN * 32];
    __shared__ float redS[2][BM][2];

    const int tid = threadIdx.x;
    const int lane = tid & 63;
    const int lm = lane & 15, lq = lane >> 4;
    const int wrow = ((tid >> 6) & 1) * 32;
    const int wcol = (tid >> 7) * 128;
    const int half = tid >> 7;
    const int m0 = blockIdx.x * BM;
    const _Float16* Ab = A + (size_t)m0 * K;

    v4f acc[MT][NT];
#pragma unroll
    for (int i = 0; i < MT; ++i)
#pragma unroll
        for (int j = 0; j < NT; ++j) acc[i][j] = (v4f){0.f, 0.f, 0.f, 0.f};

    const int rowS = tid >> 2, qS = tid & 3;

    uint4 ra[RA], rb[RB];
#pragma unroll
    for (int r = 0; r < RA; ++r)
        ra[r] = *(const uint4*)(Ab + (size_t)(rowS + 64 * r) * K + qS * 8);
#pragma unroll
    for (int r = 0; r < RB; ++r)
        rb[r] = *(const uint4*)(W + (size_t)(rowS + 64 * r) * K + qS * 8);

    for (int k0 = 0; k0 < K; k0 += 32) {
        __syncthreads();
#pragma unroll
        for (int r = 0; r < RA; ++r)
            *(uint4*)(As + (size_t)(tid + 256 * r) * 8) = ra[r];
#pragma unroll
        for (int r = 0; r < RB; ++r)
            *(uint4*)(Bs + (size_t)(tid + 256 * r) * 8) = rb[r];
        __syncthreads();
        int kn = k0 + 32;
        if (kn < K) {
#pragma unroll
            for (int r = 0; r < RA; ++r)
                ra[r] = *(const uint4*)(Ab + (size_t)(rowS + 64 * r) * K + kn + qS * 8);
#pragma unroll
            for (int r = 0; r < RB; ++r)
                rb[r] = *(const uint4*)(W + (size_t)(rowS + 64 * r) * K + kn + qS * 8);
        }
        v8h af[MT], bf[NT];
#pragma unroll
        for (int i = 0; i < MT; ++i)
            af[i] = *(const v8h*)(As + (size_t)(wrow + i * 16 + lm) * 32 + lq * 8);
#pragma unroll
        for (int j = 0; j < NT; ++j)
            bf[j] = *(const v8h*)(Bs + (size_t)(wcol + j * 16 + lm) * 32 + lq * 8);
#pragma unroll
        for (int i = 0; i < MT; ++i)
#pragma unroll
            for (int j = 0; j < NT; ++j)
                acc[i][j] = __builtin_amdgcn_mfma_f32_16x16x32_f16(
                    af[i], bf[j], acc[i][j], 0, 0, 0);
    }

    // y = gemm + bias + residual; accumulate per-row sums
    float s[MT][4], s2[MT][4];
#pragma unroll
    for (int i = 0; i < MT; ++i)
#pragma unroll
        for (int rg = 0; rg < 4; ++rg) { s[i][rg] = 0.f; s2[i][rg] = 0.f; }
#pragma unroll
    for (int j = 0; j < NT; ++j) {
        int col = wcol + j * 16 + lm;
        float bv = bias[col];
#pragma unroll
        for (int i = 0; i < MT; ++i) {
            int rbase = m0 + wrow + i * 16 + lq * 4;
#pragma unroll
            for (int rg = 0; rg < 4; ++rg) {
                float y = acc[i][j][rg] + bv + X[(size_t)(rbase + rg) * 256 + col];
                acc[i][j][rg] = y;
                s[i][rg] += y;
                s2[i][rg] += y * y;
            }
        }
    }
    // reduce across the 16 lm lanes (same row), publish per-half partials
#pragma unroll
    for (int i = 0; i < MT; ++i)
#pragma unroll
        for (int rg = 0; rg < 4; ++rg) {
            float a = s[i][rg], b2 = s2[i][rg];
#pragma unroll
            for (int m = 1; m < 16; m <<= 1) {
                a += __shfl_xor(a, m);
                b2 += __shfl_xor(b2, m);
            }
            if (lm == 0) {
                int rloc = wrow + i * 16 + lq * 4 + rg;
                redS[half][rloc][0] = a;
                redS[half][rloc][1] = b2;
            }
        }
    __syncthreads();
#pragma unroll
    for (int i = 0; i < MT; ++i) {
#pragma unroll
        for (int rg = 0; rg < 4; ++rg) {
            int rloc = wrow + i * 16 + lq * 4 + rg;
            float st = redS[0][rloc][0] + redS[1][rloc][0];
            float s2t = redS[0][rloc][1] + redS[1][rloc][1];
            float mean = st * (1.f / 256.f);
            float var = s2t * (1.f / 256.f) - mean * mean;
            float inv = rsqrtf(var + 1e-5f);
            size_t rowb = (size_t)(m0 + rloc) * 256;
#pragma unroll
            for (int j = 0; j < NT; ++j) {
                int col = wcol + j * 16 + lm;
                float o = (acc[i][j][rg] - mean) * inv * gamma[col] + beta[col];
                X[rowb + col] = o;
                X16[rowb + col] = (_Float16)o;
            }
        }
    }
}

// ---------------------------------------------------------------------------
// Fused weight conversion (cvt_all + Whh MFMA-fragment blob + permuted bias).
// Wih dest rows are gate-interleaved: dest row j*4+g = src row g*256+j.
// Whh blob: B-fragments for mfma_f32_16x16x32_f16. Fragment (w8,jt8,kt):
//   word idx = (((w8*8+jt8)*8+kt)*64 + lane)*4 + wd
//   n = w8*128 + jt8*16 + (lane&15)  (logical gate index, = j*4+g)
//   k = kt*32 + (lane>>4)*8 + wd*2   (+0,+1 packed)
//   src row = (n&3)*256 + (n>>2)
// ---------------------------------------------------------------------------
__global__ __launch_bounds__(256) void cvt_fused_kernel(
    const float* __restrict__ s0, const float* __restrict__ s1,
    const float* __restrict__ s2, const float* __restrict__ s3,
    const float* __restrict__ s4, const float* __restrict__ s5,
    _Float16* __restrict__ dst,
    const float* __restrict__ Whh, unsigned int* __restrict__ WB,
    const float* __restrict__ bih, const float* __restrict__ bhh,
    float* __restrict__ PB)
{
    if (blockIdx.x < 7424) {
        int i = blockIdx.x * 256 + threadIdx.x;
        if (i >= 1900544) return;
        float val;
        if (i < 589824)       val = s0[i];
        else if (i < 786432)  val = s1[i - 589824];
        else if (i < 1179648) val = s2[i - 786432];
        else if (i < 1572864) val = s3[i - 1179648];
        else if (i < 1835008) {
            int idx = i - 1572864;
            int rp = idx >> 8, k = idx & 255;
            int j = rp >> 2, g = rp & 3;
            val = s4[(g * 256 + j) * 256 + k];
        }
        else                  val = s5[i - 1835008];
        dst[i] = (_Float16)val;
    } else {
        int idx = (blockIdx.x - 7424) * 256 + threadIdx.x;  // 0..131071
        if (idx < 1024) {
            int j = idx >> 2, g = idx & 3;
            PB[idx] = bih[g * 256 + j] + bhh[g * 256 + j];
        }
        int wd   = idx & 3;
        int lane = (idx >> 2) & 63;
        int kt   = (idx >> 8) & 7;
        int jt   = (idx >> 11) & 7;
        int w    = (idx >> 14) & 7;
        int n = w * 128 + jt * 16 + (lane & 15);
        int src_r = (n & 3) * 256 + (n >> 2);
        int k = kt * 32 + ((lane >> 4) << 3) + (wd << 1);
        _Float16 lo = (_Float16)Whh[src_r * 256 + k];
        _Float16 hi = (_Float16)Whh[src_r * 256 + k + 1];
        U32H2 x; x.h = h2t{lo, hi};
        WB[idx] = x.u;
    }
}

// ---------------------------------------------------------------------------
// Part encoder with bin-encoder fused (bb computed redundantly per block).
// ---------------------------------------------------------------------------
__global__ __launch_bounds__(128) void part_enc_kernel(
    const float* __restrict__ parts, const float* __restrict__ W1,
    const float* __restrict__ b1, const float* __restrict__ W2,
    const float* __restrict__ b2, const float* __restrict__ bin_info,
    const float* __restrict__ be_W1, const float* __restrict__ be_b1,
    const float* __restrict__ be_W2, const float* __restrict__ be_b2,
    const float* __restrict__ pos_emb, float* __restrict__ X,
    _Float16* __restrict__ X16)
{
    __shared__ float W2s[128][129];
    __shared__ float h1[128];
    __shared__ float pin[16];
    __shared__ float h1b[64];
    __shared__ float bb_s[64];
    int tid = threadIdx.x;
    int b = blockIdx.x >> 3, s0 = (blockIdx.x & 7) * 32;
    for (int l = 0; l < 128; ++l) W2s[l][tid] = W2[l * 128 + tid];
    // bin encoder (64-dim MLP, redundant per block, trivial)
    {
        float x0 = bin_info[b * 2], x1 = bin_info[b * 2 + 1];
        if (tid < 64)
            h1b[tid] = fmaxf(be_W1[tid * 2] * x0 + be_W1[tid * 2 + 1] * x1
                             + be_b1[tid], 0.f);
        __syncthreads();
        if (tid < 64) {
            float a = be_b2[tid];
#pragma unroll 4
            for (int e = 0; e < 64; ++e) a += be_W2[tid * 64 + e] * h1b[e];
            bb_s[tid] = a;
        }
        __syncthreads();
    }
    float w1r[16];
#pragma unroll
    for (int k = 0; k < 16; ++k) w1r[k] = W1[tid * 16 + k];
    float bias1v = b1[tid], bias2v = b2[tid];
    for (int si = 0; si < 32; ++si) {
        int s = s0 + si;
        size_t row = (size_t)b * 256 + s;
        if (tid < 16) pin[tid] = parts[row * 16 + tid];
        __syncthreads();
        float h = bias1v;
#pragma unroll
        for (int k = 0; k < 16; ++k) h += w1r[k] * pin[k];
        h1[tid] = fmaxf(h, 0.f);
        __syncthreads();
        float acc = bias2v;
#pragma unroll 4
        for (int e = 0; e < 128; ++e) acc += W2s[tid][e] * h1[e];
        X[row * 256 + tid] = acc;
        X16[row * 256 + tid] = (_Float16)acc;
        if (tid < 64) {
            float bbv = bb_s[tid];
            float pev = pos_emb[s * 64 + tid];
            X[row * 256 + 128 + tid] = bbv;
            X[row * 256 + 192 + tid] = pev;
            X16[row * 256 + 128 + tid] = (_Float16)bbv;
            X16[row * 256 + 192 + tid] = (_Float16)pev;
        }
        __syncthreads();
    }
}

// ---------------------------------------------------------------------------
// MFMA attention: one block per (b,h), 256 threads (4 waves).
// ---------------------------------------------------------------------------
__global__ __launch_bounds__(256) void attn_mfma_kernel(
    const _Float16* __restrict__ QKV, _Float16* __restrict__ O16)
{
    int bh = blockIdx.x;
    int b = bh >> 3, h = bh & 7;
    const int tid = threadIdx.x;
    const int w = tid >> 6;
    const int lane = tid & 63;
    const int lm = lane & 15, lq = lane >> 4;
    const float c_se = 0.17677669529663687f * 1.44269504f;

    __shared__ _Float16 Ks[4][256][8];
    __shared__ _Float16 Vt[32][264];
    __shared__ _Float16 Ps[4][16][264];

    const _Float16* qkvb = QKV + (size_t)(b * 256) * 768 + h * 32;
    {
        int s = tid;
        const _Float16* kr = qkvb + (size_t)s * 768 + 256;
#pragma unroll
        for (int c = 0; c < 4; ++c)
            *(uint4*)&Ks[c][s][0] = *(const uint4*)(kr + c * 8);
        const _Float16* vr = qkvb + (size_t)s * 768 + 512;
        _Float16 vtmp[32];
        *(uint4*)&vtmp[0]  = *(const uint4*)(vr);
        *(uint4*)&vtmp[8]  = *(const uint4*)(vr + 8);
        *(uint4*)&vtmp[16] = *(const uint4*)(vr + 16);
        *(uint4*)&vtmp[24] = *(const uint4*)(vr + 24);
#pragma unroll
        for (int d = 0; d < 32; ++d) Vt[d][s] = vtmp[d];
    }
    __syncthreads();

#pragma unroll 1
    for (int st = 0; st < 4; ++st) {
        int rt = w * 4 + st;
        v8h qf = *(const v8h*)(QKV + (size_t)(b * 256 + rt * 16 + lm) * 768
                               + h * 32 + lq * 8);
        v4f acc[16];
#pragma unroll
        for (int ct = 0; ct < 16; ++ct) {
            v8h kf = *(const v8h*)&Ks[lq][ct * 16 + lm][0];
            acc[ct] = __builtin_amdgcn_mfma_f32_16x16x32_f16(
                qf, kf, (v4f){0.f, 0.f, 0.f, 0.f}, 0, 0, 0);
        }
        float sminv[4];
#pragma unroll
        for (int r = 0; r < 4; ++r) {
            float m = acc[0][r];
#pragma unroll
            for (int ct = 1; ct < 16; ++ct) m = fmaxf(m, acc[ct][r]);
#pragma unroll
            for (int msk = 1; msk < 16; msk <<= 1)
                m = fmaxf(m, __shfl_xor(m, msk));
            float ssum = 0.f;
#pragma unroll
            for (int ct = 0; ct < 16; ++ct) {
                float e = fexp2((acc[ct][r] - m) * c_se);
                acc[ct][r] = e;
                ssum += e;
            }
#pragma unroll
            for (int msk = 1; msk < 16; msk <<= 1)
                ssum += __shfl_xor(ssum, msk);
            sminv[r] = frcp(ssum);
        }
#pragma unroll
        for (int ct = 0; ct < 16; ++ct)
#pragma unroll
            for (int r = 0; r < 4; ++r)
                Ps[w][lq * 4 + r][ct * 16 + lm] =
                    (_Float16)(acc[ct][r] * sminv[r]);
#pragma unroll
        for (int dt = 0; dt < 2; ++dt) {
            v4f o = (v4f){0.f, 0.f, 0.f, 0.f};
#pragma unroll
            for (int jc = 0; jc < 8; ++jc) {
                v8h pf = *(const v8h*)&Ps[w][lm][jc * 32 + lq * 8];
                v8h vf = *(const v8h*)&Vt[dt * 16 + lm][jc * 32 + lq * 8];
                o = __builtin_amdgcn_mfma_f32_16x16x32_f16(pf, vf, o, 0, 0, 0);
            }
#pragma unroll
            for (int r = 0; r < 4; ++r)
                O16[(size_t)(b * 256 + rt * 16 + lq * 4 + r) * 256
                    + h * 32 + dt * 16 + lm] = (_Float16)o[r];
        }
    }
}

// ---------------------------------------------------------------------------
__global__ __launch_bounds__(256) void gather_kernel(
    const float* __restrict__ X, const int* __restrict__ target,
    _Float16* __restrict__ Xg16)
{
    int row = blockIdx.x;
    int b = row >> 8, t = row & 255;
    int d = threadIdx.x;
    float val = 0.f;
    if (t > 0) {
        int src = target[b * 256 + t - 1];
        val = X[((size_t)b * 256 + src) * 256 + d];
    }
    Xg16[(size_t)row * 256 + d] = (_Float16)val;
}

// ---------------------------------------------------------------------------
// LSTM recurrence via MFMA: 1 block/batch, 256 threads (4 waves, 1 wave/SIMD
// -> full 512-reg unified budget/wave; the 512-thread variants of R3/R4 were
// hard-capped at 256 regs/wave and forced to scratch, 959us). Wave w covers
// n in [w*256, w*256+256): jt 0..15, kt 0..7 -> 128 frags/wave. Split:
//   regs 90 frags (360 regs): kt0..4 all jt + kt5 jt0..9
//   LDS  38 frags (152 KB):   kt6, kt7, kt5 jt10..15
// acc halved (jt in 2 halves of 8) -> ~416 regs total, under the measured
// 450 no-spill line. A = h broadcast to 16 rows. Blob index for (w4,jt,kt):
// old8-wave frag (w8=2*w4+(jt>>3), jt8=jt&7).
// ---------------------------------------------------------------------------
__global__ __launch_bounds__(256, 1) void lstm_kernel(
    const _Float16* __restrict__ g_in, const uint4* __restrict__ WB4,
    _Float16* __restrict__ HALL16)
{
    const int b = blockIdx.x;
    const int tid = threadIdx.x;
    const int w = tid >> 6;
    const int lane = tid & 63;
    const int lq = lane >> 4;

    __shared__ v8h wlds[9728];         // 152 KB: 38 frags x 4 waves
    __shared__ float gf[1024];         // 4 KB gate staging
    __shared__ uint4 h2v[32];          // 512 B packed h (f16 pairs)
    unsigned int* h2_s = (unsigned int*)h2v;

    const v8h* __restrict__ WBv = (const v8h*)WB4;

#define FRAG_IDX(jt, kt) \
    ((((2 * w + ((jt) >> 3)) * 8 + ((jt) & 7)) * 8 + (kt)) * 64 + lane)

    // register-resident fragments
    v8h wf[90];
#pragma unroll
    for (int kt = 0; kt < 5; ++kt)
#pragma unroll
        for (int jt = 0; jt < 16; ++jt)
            wf[kt * 16 + jt] = WBv[FRAG_IDX(jt, kt)];
#pragma unroll
    for (int jt = 0; jt < 10; ++jt)
        wf[80 + jt] = WBv[FRAG_IDX(jt, 5)];

    // LDS-resident fragments: kt6 -> slot jt, kt7 -> 16+jt, kt5 jt>=10 -> 32+..
#pragma unroll
    for (int jt = 0; jt < 16; ++jt)
        wlds[(w * 38 + jt) * 64 + lane] = WBv[FRAG_IDX(jt, 6)];
#pragma unroll
    for (int jt = 0; jt < 16; ++jt)
        wlds[(w * 38 + 16 + jt) * 64 + lane] = WBv[FRAG_IDX(jt, 7)];
#pragma unroll
    for (int jt = 10; jt < 16; ++jt)
        wlds[(w * 38 + 32 + (jt - 10)) * 64 + lane] = WBv[FRAG_IDX(jt, 5)];
#undef FRAG_IDX

    if (tid < 128) h2_s[tid] = 0u;

    const _Float16* ginb = g_in + (size_t)b * 256 * 1024;
    uint2 gi = *(const uint2*)(ginb + tid * 4);
    float c_state = 0.f;
    __syncthreads();

#pragma unroll 1
    for (int t = 0; t < 256; ++t) {
#pragma unroll
        for (int half = 0; half < 2; ++half) {
            v4f acc[8];
#pragma unroll
            for (int j2 = 0; j2 < 8; ++j2) acc[j2] = (v4f){0.f, 0.f, 0.f, 0.f};
#pragma unroll
            for (int kt = 0; kt < 8; ++kt) {
                v8h av = *(const v8h*)&h2v[kt * 4 + lq];
#pragma unroll
                for (int j2 = 0; j2 < 8; ++j2) {
                    const int jt = half * 8 + j2;
                    v8h bb;
                    if (kt < 5)                       bb = wf[kt * 16 + jt];
                    else if (kt == 5 && jt < 10)      bb = wf[80 + jt];
                    else if (kt == 5)                 bb = wlds[(w * 38 + 32 + (jt - 10)) * 64 + lane];
                    else if (kt == 6)                 bb = wlds[(w * 38 + jt) * 64 + lane];
                    else                              bb = wlds[(w * 38 + 16 + jt) * 64 + lane];
                    acc[j2] = __builtin_amdgcn_mfma_f32_16x16x32_f16(
                        av, bb, acc[j2], 0, 0, 0);
                }
            }
            // D: col = lane&15 (= n within tile), rows redundant -> lanes 0..15
            if (lane < 16) {
#pragma unroll
                for (int j2 = 0; j2 < 8; ++j2)
                    gf[w * 256 + (half * 8 + j2) * 16 + lane] = acc[j2][0];
            }
        }
        __syncthreads();

        {
            int j = tid;
            float4 gv = *(const float4*)&gf[j << 2];
            h2t p0 = u2h(gi.x), p1 = u2h(gi.y);
            float ig = (float)p0.x + gv.x;
            float fg = (float)p0.y + gv.y;
            float gg = (float)p1.x + gv.z;
            float og = (float)p1.y + gv.w;
            c_state = fsigm(fg) * c_state + fsigm(ig) * ftanh_(gg);
            float h = fsigm(og) * ftanh_(c_state);
            HALL16[((size_t)(b * 256 + t)) * 256 + j] = (_Float16)h;
            U32H2 hxp; hxp.h = h2t{(_Float16)h, (_Float16)0.f};
            unsigned int hu = hxp.u & 0xffffu;
            unsigned int other = (unsigned int)__shfl_xor((int)hu, 1);
            if ((j & 1) == 0) h2_s[j >> 1] = hu | (other << 16);
            int tn = (t < 255) ? (t + 1) : 255;
            gi = *(const uint2*)(ginb + (size_t)tn * 1024 + j * 4);
        }
        __syncthreads();
    }
}

// ---------------------------------------------------------------------------
// Pointer logits: out[b,t,i] = vsum - 2 * sum_d v_d / (1 + exp2(s_d)),
// s = 2.88539*(hp+ep) (scale folded into LDS staging).
// ---------------------------------------------------------------------------
__global__ __launch_bounds__(256) void pointer_kernel(
    const float* __restrict__ HP, const float* __restrict__ EP,
    const float* __restrict__ v, float* __restrict__ out)
{
    int b = blockIdx.z, tt = blockIdx.y, it = blockIdx.x;
    __shared__ float hp_s[16][260];
    __shared__ float ep_s[16][260];
    __shared__ float v_s[256];
    __shared__ float red[4];
    int tid = threadIdx.x;
    const float cs = 2.88539008f;
    const float* hpb = HP + ((size_t)b * 256 + tt * 16) * 256;
    const float* epb = EP + ((size_t)b * 256 + it * 16) * 256;
#pragma unroll
    for (int l = 0; l < 4; ++l) {
        int idx = tid + l * 256;
        int r = idx >> 6, c4 = idx & 63;
        float4 hv = *(const float4*)(hpb + r * 256 + c4 * 4);
        hv.x *= cs; hv.y *= cs; hv.z *= cs; hv.w *= cs;
        *(float4*)&hp_s[r][c4 * 4] = hv;
        float4 ev = *(const float4*)(epb + r * 256 + c4 * 4);
        ev.x *= cs; ev.y *= cs; ev.z *= cs; ev.w *= cs;
        *(float4*)&ep_s[r][c4 * 4] = ev;
    }
    float vv = v[tid];
    v_s[tid] = vv;
    float vp = vv;
#pragma unroll
    for (int m = 1; m < 64; m <<= 1) vp += __shfl_xor(vp, m);
    if ((tid & 63) == 0) red[tid >> 6] = vp;
    __syncthreads();
    float vsum = red[0] + red[1] + red[2] + red[3];
    int tl = tid >> 4, il = tid & 15;
    float acc = 0.f;
#pragma unroll 4
    for (int d = 0; d < 256; ++d) {
        float sval = hp_s[tl][d] + ep_s[il][d];
        float r = frcp(1.0f + fexp2(sval));
        acc = fmaf(v_s[d], r, acc);
    }
    out[((size_t)b * 256 + tt * 16 + tl) * 256 + it * 16 + il] =
        vsum - 2.0f * acc;
}

// ---------------------------------------------------------------------------
extern "C" void kernel_launch(void* const* d_in, const int* in_sizes, int n_in,
                              void* d_out, int out_size, void* d_ws, size_t ws_size,
                              hipStream_t stream)
{
    const float* parts    = (const float*)d_in[0];
    const float* bin_info = (const float*)d_in[1];
    const int*   target   = (const int*)d_in[2];
    const float* pe_W1 = (const float*)d_in[3];
    const float* pe_b1 = (const float*)d_in[4];
    const float* pe_W2 = (const float*)d_in[5];
    const float* pe_b2 = (const float*)d_in[6];
    const float* be_W1 = (const float*)d_in[7];
    const float* be_b1 = (const float*)d_in[8];
    const float* be_W2 = (const float*)d_in[9];
    const float* be_b2 = (const float*)d_in[10];
    const float* pos_emb = (const float*)d_in[11];
    const float* tr_Wqkv = (const float*)d_in[12];
    const float* tr_bqkv = (const float*)d_in[13];
    const float* tr_Wo   = (const float*)d_in[14];
    const float* tr_bo   = (const float*)d_in[15];
    const float* tr_ln1_g = (const float*)d_in[16];
    const float* tr_ln1_b = (const float*)d_in[17];
    const float* tr_ff_W1 = (const float*)d_in[18];
    const float* tr_ff_b1 = (const float*)d_in[19];
    const float* tr_ff_W2 = (const float*)d_in[20];
    const float* tr_ff_b2 = (const float*)d_in[21];
    const float* tr_ln2_g = (const float*)d_in[22];
    const float* tr_ln2_b = (const float*)d_in[23];
    const float* lstm_Wih = (const float*)d_in[24];
    const float* lstm_Whh = (const float*)d_in[25];
    const float* lstm_bih = (const float*)d_in[26];
    const float* lstm_bhh = (const float*)d_in[27];
    const float* ptr_W = (const float*)d_in[28];
    const float* ptr_b = (const float*)d_in[29];
    const float* ptr_v = (const float*)d_in[30];

    // ---- workspace layout (floats) ----
    float* ws = (float*)d_ws;
    float* X     = ws;                        // 2,097,152
    float* S1    = X + 2097152;               // 8,388,608 (qkv/ff1/g_in f16)
    float* CF32  = S1 + 8388608;              // 2,097,152
    float* EPROJ = CF32 + 2097152;            // 2,097,152
    float* X16f  = EPROJ + 2097152;           // 1,048,576
    float* S2f   = X16f + 1048576;            // 1,048,576
    float* W16f  = S2f + 1048576;             // 1,048,576
    float* WBf   = W16f + 1048576;            // 131,072
    float* BBuf  = WBf + 131072;              // 2,048 (unused)
    float* PB    = BBuf + 2048;               // 1,024

    _Float16* X16    = (_Float16*)X16f;
    _Float16* Xg16   = X16;
    _Float16* S2h    = (_Float16*)S2f;
    _Float16* HALL16 = S2h;
    _Float16* S1h    = (_Float16*)S1;
    _Float16* W16    = (_Float16*)W16f;
    _Float16* Wqkv16 = W16;                   // 589,824
    _Float16* Wo16   = Wqkv16 + 589824;       // 196,608
    _Float16* Wff116 = Wo16 + 196608;         // 393,216
    _Float16* Wff216 = Wff116 + 393216;       // 393,216
    _Float16* Wih16  = Wff216 + 393216;       // 262,144 (gate-interleaved rows)
    _Float16* WpW16  = Wih16 + 262144;        // 65,536

    // ---- one-time weight conversions (single fused launch) ----
    cvt_fused_kernel<<<7936, 256, 0, stream>>>(
        tr_Wqkv, tr_Wo, tr_ff_W1, tr_ff_W2, lstm_Wih, ptr_W, W16,
        lstm_Whh, (unsigned int*)WBf, lstm_bih, lstm_bhh, PB);

    // ---- encoders (bin fused into part) ----
    part_enc_kernel<<<256, 128, 0, stream>>>(parts, pe_W1, pe_b1, pe_W2, pe_b2,
                                             bin_info, be_W1, be_b1, be_W2, be_b2,
                                             pos_emb, X, X16);

    // ---- transformer layers ----
    for (int l = 0; l < 3; ++l) {
        hgemm_kernel<64, 128, false, true><<<dim3(128, 6), 256, 0, stream>>>(
            X16, Wqkv16 + (size_t)l * 196608, tr_bqkv + l * 768, nullptr,
            S1h, 8192, 768, 256);
        attn_mfma_kernel<<<256, 256, 0, stream>>>(S1h, S2h);
        hgemm_ln_kernel<<<128, 256, 0, stream>>>(
            S2h, Wo16 + (size_t)l * 65536, tr_bo + l * 256,
            tr_ln1_g + l * 256, tr_ln1_b + l * 256, X, X16, 256);
        hgemm_kernel<64, 128, true, true><<<dim3(128, 4), 256, 0, stream>>>(
            X16, Wff116 + (size_t)l * 131072, tr_ff_b1 + l * 512, nullptr,
            S1h, 8192, 512, 256);
        hgemm_ln_kernel<<<128, 256, 0, stream>>>(
            S1h, Wff216 + (size_t)l * 131072, tr_ff_b2 + l * 256,
            tr_ln2_g + l * 256, tr_ln2_b + l * 256, X, X16, 512);
    }

    // ---- pointer decode ----
    hgemm_kernel<64, 64, false, false><<<dim3(128, 4), 256, 0, stream>>>(
        X16, WpW16, ptr_b, nullptr, EPROJ, 8192, 256, 256);
    gather_kernel<<<8192, 256, 0, stream>>>(X, target, Xg16);
    hgemm_kernel<64, 128, false, true><<<dim3(128, 8), 256, 0, stream>>>(
        Xg16, Wih16, PB, nullptr, S1h, 8192, 1024, 256);
    lstm_kernel<<<32, 256, 0, stream>>>(S1h, (const uint4*)WBf, HALL16);
    hgemm_kernel<64, 64, false, false><<<dim3(128, 4), 256, 0, stream>>>(
        HALL16, WpW16, ptr_b, nullptr, CF32, 8192, 256, 256);
    pointer_kernel<<<dim3(16, 16, 32), 256, 0, stream>>>(CF32, EPROJ, ptr_v,
                                                         (float*)d_out);
}

// Round 6
// 1120.439 us; speedup vs baseline: 1.5435x; 1.1989x over previous
//
#include <hip/hip_runtime.h>
#include <cstddef>

#define DEV __device__ __forceinline__

DEV float fexp2(float x) { return __builtin_amdgcn_exp2f(x); }
DEV float frcp(float x)  { return __builtin_amdgcn_rcpf(x); }
DEV float fsigm(float x) { return frcp(1.0f + fexp2(-1.44269504f * x)); }
DEV float ftanh_(float x){ return 1.0f - 2.0f * frcp(1.0f + fexp2(2.88539008f * x)); }

typedef _Float16 h2t __attribute__((ext_vector_type(2)));
typedef _Float16 v8h __attribute__((ext_vector_type(8)));
typedef float v4f __attribute__((ext_vector_type(4)));
union U32H2 { unsigned int u; h2t h; };
DEV h2t u2h(unsigned int u) { U32H2 x; x.u = u; return x.h; }

// ---------------------------------------------------------------------------
// f16 MFMA GEMM: C[M,N] = A[M,K] @ W[N,K]^T + bias; A,W f16 row-major.
// BM in {64,128}, BK=32, 256 threads (4 waves, 2x2), wave tile (BM/2)x(BN/2).
// ---------------------------------------------------------------------------
template <int BM, int BN, bool RELU, bool OUTF16>
__global__ __launch_bounds__(256) void hgemm_kernel(
    const _Float16* __restrict__ A, const _Float16* __restrict__ W,
    const float* __restrict__ bias1, const float* __restrict__ bias2,
    void* __restrict__ Cout, int M, int N, int K)
{
    constexpr int MT = BM / 32;
    constexpr int NT = BN / 32;
    constexpr int RA = BM / 64;
    constexpr int RB = BN / 64;
    __shared__ _Float16 As[BM * 32];
    __shared__ _Float16 Bs[BN * 32];

    const int tid = threadIdx.x;
    const int lane = tid & 63;
    const int lm = lane & 15, lq = lane >> 4;
    const int wrow = ((tid >> 6) & 1) * (BM / 2);
    const int wcol = (tid >> 7) * (BN / 2);
    const int m0 = blockIdx.x * BM, n0 = blockIdx.y * BN;
    const _Float16* Ab = A + (size_t)m0 * K;
    const _Float16* Wb = W + (size_t)n0 * K;

    v4f acc[MT][NT];
#pragma unroll
    for (int i = 0; i < MT; ++i)
#pragma unroll
        for (int j = 0; j < NT; ++j) acc[i][j] = (v4f){0.f, 0.f, 0.f, 0.f};

    const int rowS = tid >> 2, qS = tid & 3;

    uint4 ra[RA], rb[RB];
#pragma unroll
    for (int r = 0; r < RA; ++r)
        ra[r] = *(const uint4*)(Ab + (size_t)(rowS + 64 * r) * K + qS * 8);
#pragma unroll
    for (int r = 0; r < RB; ++r)
        rb[r] = *(const uint4*)(Wb + (size_t)(rowS + 64 * r) * K + qS * 8);

    for (int k0 = 0; k0 < K; k0 += 32) {
        __syncthreads();
#pragma unroll
        for (int r = 0; r < RA; ++r)
            *(uint4*)(As + (size_t)(tid + 256 * r) * 8) = ra[r];
#pragma unroll
        for (int r = 0; r < RB; ++r)
            *(uint4*)(Bs + (size_t)(tid + 256 * r) * 8) = rb[r];
        __syncthreads();
        int kn = k0 + 32;
        if (kn < K) {
#pragma unroll
            for (int r = 0; r < RA; ++r)
                ra[r] = *(const uint4*)(Ab + (size_t)(rowS + 64 * r) * K + kn + qS * 8);
#pragma unroll
            for (int r = 0; r < RB; ++r)
                rb[r] = *(const uint4*)(Wb + (size_t)(rowS + 64 * r) * K + kn + qS * 8);
        }
        v8h af[MT], bf[NT];
#pragma unroll
        for (int i = 0; i < MT; ++i)
            af[i] = *(const v8h*)(As + (size_t)(wrow + i * 16 + lm) * 32 + lq * 8);
#pragma unroll
        for (int j = 0; j < NT; ++j)
            bf[j] = *(const v8h*)(Bs + (size_t)(wcol + j * 16 + lm) * 32 + lq * 8);
#pragma unroll
        for (int i = 0; i < MT; ++i)
#pragma unroll
            for (int j = 0; j < NT; ++j)
                acc[i][j] = __builtin_amdgcn_mfma_f32_16x16x32_f16(
                    af[i], bf[j], acc[i][j], 0, 0, 0);
    }

#pragma unroll
    for (int j = 0; j < NT; ++j) {
        int col = n0 + wcol + j * 16 + lm;
        float bv = bias1[col];
        if (bias2) bv += bias2[col];
#pragma unroll
        for (int i = 0; i < MT; ++i) {
            int rbase = m0 + wrow + i * 16 + lq * 4;
#pragma unroll
            for (int rg = 0; rg < 4; ++rg) {
                float vv = acc[i][j][rg] + bv;
                if (RELU) vv = fmaxf(vv, 0.f);
                if (OUTF16)
                    ((_Float16*)Cout)[(size_t)(rbase + rg) * N + col] = (_Float16)vv;
                else
                    ((float*)Cout)[(size_t)(rbase + rg) * N + col] = vv;
            }
        }
    }
}

// ---------------------------------------------------------------------------
// GEMM (N=256 fixed) + bias + residual + LayerNorm fused.
// Out: X (f32, in-place residual target) and X16 (f16 copy).
// BM=64, BN=256, 256 threads (4 waves, 2x2), wave tile 32x128.
// ---------------------------------------------------------------------------
__global__ __launch_bounds__(256) void hgemm_ln_kernel(
    const _Float16* __restrict__ A, const _Float16* __restrict__ W,
    const float* __restrict__ bias, const float* __restrict__ gamma,
    const float* __restrict__ beta, float* __restrict__ X,
    _Float16* __restrict__ X16, int K)
{
    constexpr int BM = 64, BN = 256, MT = 2, NT = 8, RA = 1, RB = 4;
    __shared__ _Float16 As[BM * 32];
    __shared__ _Float16 Bs[BN * 32];
    __shared__ float redS[2][BM][2];

    const int tid = threadIdx.x;
    const int lane = tid & 63;
    const int lm = lane & 15, lq = lane >> 4;
    const int wrow = ((tid >> 6) & 1) * 32;
    const int wcol = (tid >> 7) * 128;
    const int half = tid >> 7;
    const int m0 = blockIdx.x * BM;
    const _Float16* Ab = A + (size_t)m0 * K;

    v4f acc[MT][NT];
#pragma unroll
    for (int i = 0; i < MT; ++i)
#pragma unroll
        for (int j = 0; j < NT; ++j) acc[i][j] = (v4f){0.f, 0.f, 0.f, 0.f};

    const int rowS = tid >> 2, qS = tid & 3;

    uint4 ra[RA], rb[RB];
#pragma unroll
    for (int r = 0; r < RA; ++r)
        ra[r] = *(const uint4*)(Ab + (size_t)(rowS + 64 * r) * K + qS * 8);
#pragma unroll
    for (int r = 0; r < RB; ++r)
        rb[r] = *(const uint4*)(W + (size_t)(rowS + 64 * r) * K + qS * 8);

    for (int k0 = 0; k0 < K; k0 += 32) {
        __syncthreads();
#pragma unroll
        for (int r = 0; r < RA; ++r)
            *(uint4*)(As + (size_t)(tid + 256 * r) * 8) = ra[r];
#pragma unroll
        for (int r = 0; r < RB; ++r)
            *(uint4*)(Bs + (size_t)(tid + 256 * r) * 8) = rb[r];
        __syncthreads();
        int kn = k0 + 32;
        if (kn < K) {
#pragma unroll
            for (int r = 0; r < RA; ++r)
                ra[r] = *(const uint4*)(Ab + (size_t)(rowS + 64 * r) * K + kn + qS * 8);
#pragma unroll
            for (int r = 0; r < RB; ++r)
                rb[r] = *(const uint4*)(W + (size_t)(rowS + 64 * r) * K + kn + qS * 8);
        }
        v8h af[MT], bf[NT];
#pragma unroll
        for (int i = 0; i < MT; ++i)
            af[i] = *(const v8h*)(As + (size_t)(wrow + i * 16 + lm) * 32 + lq * 8);
#pragma unroll
        for (int j = 0; j < NT; ++j)
            bf[j] = *(const v8h*)(Bs + (size_t)(wcol + j * 16 + lm) * 32 + lq * 8);
#pragma unroll
        for (int i = 0; i < MT; ++i)
#pragma unroll
            for (int j = 0; j < NT; ++j)
                acc[i][j] = __builtin_amdgcn_mfma_f32_16x16x32_f16(
                    af[i], bf[j], acc[i][j], 0, 0, 0);
    }

    // y = gemm + bias + residual; accumulate per-row sums
    float s[MT][4], s2[MT][4];
#pragma unroll
    for (int i = 0; i < MT; ++i)
#pragma unroll
        for (int rg = 0; rg < 4; ++rg) { s[i][rg] = 0.f; s2[i][rg] = 0.f; }
#pragma unroll
    for (int j = 0; j < NT; ++j) {
        int col = wcol + j * 16 + lm;
        float bv = bias[col];
#pragma unroll
        for (int i = 0; i < MT; ++i) {
            int rbase = m0 + wrow + i * 16 + lq * 4;
#pragma unroll
            for (int rg = 0; rg < 4; ++rg) {
                float y = acc[i][j][rg] + bv + X[(size_t)(rbase + rg) * 256 + col];
                acc[i][j][rg] = y;
                s[i][rg] += y;
                s2[i][rg] += y * y;
            }
        }
    }
    // reduce across the 16 lm lanes (same row), publish per-half partials
#pragma unroll
    for (int i = 0; i < MT; ++i)
#pragma unroll
        for (int rg = 0; rg < 4; ++rg) {
            float a = s[i][rg], b2 = s2[i][rg];
#pragma unroll
            for (int m = 1; m < 16; m <<= 1) {
                a += __shfl_xor(a, m);
                b2 += __shfl_xor(b2, m);
            }
            if (lm == 0) {
                int rloc = wrow + i * 16 + lq * 4 + rg;
                redS[half][rloc][0] = a;
                redS[half][rloc][1] = b2;
            }
        }
    __syncthreads();
#pragma unroll
    for (int i = 0; i < MT; ++i) {
#pragma unroll
        for (int rg = 0; rg < 4; ++rg) {
            int rloc = wrow + i * 16 + lq * 4 + rg;
            float st = redS[0][rloc][0] + redS[1][rloc][0];
            float s2t = redS[0][rloc][1] + redS[1][rloc][1];
            float mean = st * (1.f / 256.f);
            float var = s2t * (1.f / 256.f) - mean * mean;
            float inv = rsqrtf(var + 1e-5f);
            size_t rowb = (size_t)(m0 + rloc) * 256;
#pragma unroll
            for (int j = 0; j < NT; ++j) {
                int col = wcol + j * 16 + lm;
                float o = (acc[i][j][rg] - mean) * inv * gamma[col] + beta[col];
                X[rowb + col] = o;
                X16[rowb + col] = (_Float16)o;
            }
        }
    }
}

// ---------------------------------------------------------------------------
// Fused weight conversion (cvt_all + Whh blob + permuted bias in one launch).
// Wih dest rows are gate-interleaved: dest row j*4+g = src row g*256+j.
// Whh blob chunk map (q=0..63 -> (i,c)): LDS 8 (c<2 all i), regs 44
// (2<=c<13 all i), stream 12 (13<=c<16 all i).  [R0 layout, measured-best]
// ---------------------------------------------------------------------------
__global__ __launch_bounds__(256) void cvt_fused_kernel(
    const float* __restrict__ s0, const float* __restrict__ s1,
    const float* __restrict__ s2, const float* __restrict__ s3,
    const float* __restrict__ s4, const float* __restrict__ s5,
    _Float16* __restrict__ dst,
    const float* __restrict__ Whh, unsigned int* __restrict__ WB,
    const float* __restrict__ bih, const float* __restrict__ bhh,
    float* __restrict__ PB)
{
    if (blockIdx.x < 7424) {
        int i = blockIdx.x * 256 + threadIdx.x;
        if (i >= 1900544) return;
        float val;
        if (i < 589824)       val = s0[i];
        else if (i < 786432)  val = s1[i - 589824];
        else if (i < 1179648) val = s2[i - 786432];
        else if (i < 1572864) val = s3[i - 1179648];
        else if (i < 1835008) {
            int idx = i - 1572864;
            int rp = idx >> 8, k = idx & 255;
            int j = rp >> 2, g = rp & 3;
            val = s4[(g * 256 + j) * 256 + k];
        }
        else                  val = s5[i - 1835008];
        dst[i] = (_Float16)val;
    } else {
        int idx = (blockIdx.x - 7424) * 256 + threadIdx.x;  // 0..131071
        if (idx < 1024) {
            int j = idx >> 2, g = idx & 3;
            PB[idx] = bih[g * 256 + j] + bhh[g * 256 + j];
        }
        int l = idx & 3;
        int gt = idx >> 2;
        int tid = gt & 511;
        int q = gt >> 9;                            // 0..63
        int i, c;
        if (q < 8)       { i = q >> 1; c = q & 1; }
        else if (q < 52) { int qq = q - 8; i = qq / 11; c = 2 + qq % 11; }
        else             { int qq = q - 52; c = 13 + (qq >> 2); i = qq & 3; }
        int r = ((tid & 255) << 2) + i;
        int k = ((tid >> 8) << 7) + (c << 3) + (l << 1);
        _Float16 lo = (_Float16)Whh[r * 256 + k];
        _Float16 hi = (_Float16)Whh[r * 256 + k + 1];
        U32H2 x; x.h = h2t{lo, hi};
        WB[idx] = x.u;
    }
}

// ---------------------------------------------------------------------------
// Part encoder with bin-encoder fused (bb computed redundantly per block).
// ---------------------------------------------------------------------------
__global__ __launch_bounds__(128) void part_enc_kernel(
    const float* __restrict__ parts, const float* __restrict__ W1,
    const float* __restrict__ b1, const float* __restrict__ W2,
    const float* __restrict__ b2, const float* __restrict__ bin_info,
    const float* __restrict__ be_W1, const float* __restrict__ be_b1,
    const float* __restrict__ be_W2, const float* __restrict__ be_b2,
    const float* __restrict__ pos_emb, float* __restrict__ X,
    _Float16* __restrict__ X16)
{
    __shared__ float W2s[128][129];
    __shared__ float h1[128];
    __shared__ float pin[16];
    __shared__ float h1b[64];
    __shared__ float bb_s[64];
    int tid = threadIdx.x;
    int b = blockIdx.x >> 3, s0 = (blockIdx.x & 7) * 32;
    for (int l = 0; l < 128; ++l) W2s[l][tid] = W2[l * 128 + tid];
    // bin encoder (64-dim MLP, redundant per block, trivial)
    {
        float x0 = bin_info[b * 2], x1 = bin_info[b * 2 + 1];
        if (tid < 64)
            h1b[tid] = fmaxf(be_W1[tid * 2] * x0 + be_W1[tid * 2 + 1] * x1
                             + be_b1[tid], 0.f);
        __syncthreads();
        if (tid < 64) {
            float a = be_b2[tid];
#pragma unroll 4
            for (int e = 0; e < 64; ++e) a += be_W2[tid * 64 + e] * h1b[e];
            bb_s[tid] = a;
        }
        __syncthreads();
    }
    float w1r[16];
#pragma unroll
    for (int k = 0; k < 16; ++k) w1r[k] = W1[tid * 16 + k];
    float bias1v = b1[tid], bias2v = b2[tid];
    for (int si = 0; si < 32; ++si) {
        int s = s0 + si;
        size_t row = (size_t)b * 256 + s;
        if (tid < 16) pin[tid] = parts[row * 16 + tid];
        __syncthreads();
        float h = bias1v;
#pragma unroll
        for (int k = 0; k < 16; ++k) h += w1r[k] * pin[k];
        h1[tid] = fmaxf(h, 0.f);
        __syncthreads();
        float acc = bias2v;
#pragma unroll 4
        for (int e = 0; e < 128; ++e) acc += W2s[tid][e] * h1[e];
        X[row * 256 + tid] = acc;
        X16[row * 256 + tid] = (_Float16)acc;
        if (tid < 64) {
            float bbv = bb_s[tid];
            float pev = pos_emb[s * 64 + tid];
            X[row * 256 + 128 + tid] = bbv;
            X[row * 256 + 192 + tid] = pev;
            X16[row * 256 + 128 + tid] = (_Float16)bbv;
            X16[row * 256 + 192 + tid] = (_Float16)pev;
        }
        __syncthreads();
    }
}

// ---------------------------------------------------------------------------
// MFMA attention: one block per (b,h), 256 threads (4 waves).
// ---------------------------------------------------------------------------
__global__ __launch_bounds__(256) void attn_mfma_kernel(
    const _Float16* __restrict__ QKV, _Float16* __restrict__ O16)
{
    int bh = blockIdx.x;
    int b = bh >> 3, h = bh & 7;
    const int tid = threadIdx.x;
    const int w = tid >> 6;
    const int lane = tid & 63;
    const int lm = lane & 15, lq = lane >> 4;
    const float c_se = 0.17677669529663687f * 1.44269504f;

    __shared__ _Float16 Ks[4][256][8];
    __shared__ _Float16 Vt[32][264];
    __shared__ _Float16 Ps[4][16][264];

    const _Float16* qkvb = QKV + (size_t)(b * 256) * 768 + h * 32;
    {
        int s = tid;
        const _Float16* kr = qkvb + (size_t)s * 768 + 256;
#pragma unroll
        for (int c = 0; c < 4; ++c)
            *(uint4*)&Ks[c][s][0] = *(const uint4*)(kr + c * 8);
        const _Float16* vr = qkvb + (size_t)s * 768 + 512;
        _Float16 vtmp[32];
        *(uint4*)&vtmp[0]  = *(const uint4*)(vr);
        *(uint4*)&vtmp[8]  = *(const uint4*)(vr + 8);
        *(uint4*)&vtmp[16] = *(const uint4*)(vr + 16);
        *(uint4*)&vtmp[24] = *(const uint4*)(vr + 24);
#pragma unroll
        for (int d = 0; d < 32; ++d) Vt[d][s] = vtmp[d];
    }
    __syncthreads();

#pragma unroll 1
    for (int st = 0; st < 4; ++st) {
        int rt = w * 4 + st;
        v8h qf = *(const v8h*)(QKV + (size_t)(b * 256 + rt * 16 + lm) * 768
                               + h * 32 + lq * 8);
        v4f acc[16];
#pragma unroll
        for (int ct = 0; ct < 16; ++ct) {
            v8h kf = *(const v8h*)&Ks[lq][ct * 16 + lm][0];
            acc[ct] = __builtin_amdgcn_mfma_f32_16x16x32_f16(
                qf, kf, (v4f){0.f, 0.f, 0.f, 0.f}, 0, 0, 0);
        }
        float sminv[4];
#pragma unroll
        for (int r = 0; r < 4; ++r) {
            float m = acc[0][r];
#pragma unroll
            for (int ct = 1; ct < 16; ++ct) m = fmaxf(m, acc[ct][r]);
#pragma unroll
            for (int msk = 1; msk < 16; msk <<= 1)
                m = fmaxf(m, __shfl_xor(m, msk));
            float ssum = 0.f;
#pragma unroll
            for (int ct = 0; ct < 16; ++ct) {
                float e = fexp2((acc[ct][r] - m) * c_se);
                acc[ct][r] = e;
                ssum += e;
            }
#pragma unroll
            for (int msk = 1; msk < 16; msk <<= 1)
                ssum += __shfl_xor(ssum, msk);
            sminv[r] = frcp(ssum);
        }
#pragma unroll
        for (int ct = 0; ct < 16; ++ct)
#pragma unroll
            for (int r = 0; r < 4; ++r)
                Ps[w][lq * 4 + r][ct * 16 + lm] =
                    (_Float16)(acc[ct][r] * sminv[r]);
#pragma unroll
        for (int dt = 0; dt < 2; ++dt) {
            v4f o = (v4f){0.f, 0.f, 0.f, 0.f};
#pragma unroll
            for (int jc = 0; jc < 8; ++jc) {
                v8h pf = *(const v8h*)&Ps[w][lm][jc * 32 + lq * 8];
                v8h vf = *(const v8h*)&Vt[dt * 16 + lm][jc * 32 + lq * 8];
                o = __builtin_amdgcn_mfma_f32_16x16x32_f16(pf, vf, o, 0, 0, 0);
            }
#pragma unroll
            for (int r = 0; r < 4; ++r)
                O16[(size_t)(b * 256 + rt * 16 + lq * 4 + r) * 256
                    + h * 32 + dt * 16 + lm] = (_Float16)o[r];
        }
    }
}

// ---------------------------------------------------------------------------
__global__ __launch_bounds__(256) void gather_kernel(
    const float* __restrict__ X, const int* __restrict__ target,
    _Float16* __restrict__ Xg16)
{
    int row = blockIdx.x;
    int b = row >> 8, t = row & 255;
    int d = threadIdx.x;
    float val = 0.f;
    if (t > 0) {
        int src = target[b * 256 + t - 1];
        val = X[((size_t)b * 256 + src) * 256 + d];
    }
    Xg16[(size_t)row * 256 + d] = (_Float16)val;
}

// ---------------------------------------------------------------------------
// LSTM recurrence: 1 block/batch, 512 threads. Weights: 64 KB LDS +
// 176 VGPR slab + 96 KB/step L2 stream. g_in f16 gate-interleaved [t][j*4+g].
// R0 design, measured 363us — best of all 5 weight-placement probes
// (R1 LDS-heavy 449, R2 readlane 408, R3/R4 MFMA-scratch 963/959,
// R5 MFMA reg/LDS 588). VALU+DS co-critical; do not re-balance placement.
// ---------------------------------------------------------------------------
__global__ __launch_bounds__(512) void lstm_kernel(
    const _Float16* __restrict__ g_in, const uint4* __restrict__ WB4,
    _Float16* __restrict__ HALL16)
{
    const int b = blockIdx.x;
    const int tid = threadIdx.x;
    const int kh = tid >> 8, j4 = tid & 255;

    __shared__ uint4 WL4[4096];        // 64 KB
    __shared__ float gpart[2][1024];   // 8 KB
    __shared__ uint4 h2v[32];          // 512 B
    unsigned int* h2_s = (unsigned int*)h2v;

#pragma unroll
    for (int g = 0; g < 8; ++g) WL4[g * 512 + tid] = WB4[g * 512 + tid];
    uint4 wr[44];
#pragma unroll
    for (int q = 0; q < 44; ++q) wr[q] = WB4[(8 + q) * 512 + tid];
    if (tid < 128) h2_s[tid] = 0u;

    const _Float16* ginb = g_in + (size_t)b * 256 * 1024;
    uint2 gi = make_uint2(0u, 0u);
    if (tid < 256) gi = *(const uint2*)(ginb + tid * 4);
    float c_state = 0.f;
    const uint4* SW4 = WB4 + 52 * 512;
    __syncthreads();

    for (int t = 0; t < 256; ++t) {
        uint4 sw[12];
#pragma unroll
        for (int q = 0; q < 4; ++q) sw[q] = SW4[q * 512 + tid];

        float acc[4] = {0.f, 0.f, 0.f, 0.f};
#pragma unroll
        for (int c = 0; c < 16; ++c) {
            if (c == 2) {
#pragma unroll
                for (int q = 4; q < 8; ++q) sw[q] = SW4[q * 512 + tid];
            }
            if (c == 6) {
#pragma unroll
                for (int q = 8; q < 12; ++q) sw[q] = SW4[q * 512 + tid];
            }
            uint4 h4 = h2v[(kh << 4) + c];
            h2t hx = u2h(h4.x), hy = u2h(h4.y), hz = u2h(h4.z), hw = u2h(h4.w);
#pragma unroll
            for (int i = 0; i < 4; ++i) {
                uint4 w = (c < 2)  ? WL4[((i << 1) + c) * 512 + tid]
                        : (c < 13) ? wr[i * 11 + (c - 2)]
                                   : sw[((c - 13) << 2) + i];
                acc[i] = __builtin_amdgcn_fdot2(u2h(w.x), hx, acc[i], false);
                acc[i] = __builtin_amdgcn_fdot2(u2h(w.y), hy, acc[i], false);
                acc[i] = __builtin_amdgcn_fdot2(u2h(w.z), hz, acc[i], false);
                acc[i] = __builtin_amdgcn_fdot2(u2h(w.w), hw, acc[i], false);
            }
        }
        *(float4*)&gpart[kh][j4 << 2] = make_float4(acc[0], acc[1], acc[2], acc[3]);
        __syncthreads();

        if (tid < 256) {
            int j = tid;
            h2t p0 = u2h(gi.x), p1 = u2h(gi.y);
            float ig = (float)p0.x + gpart[0][j]       + gpart[1][j];
            float fg = (float)p0.y + gpart[0][j + 256] + gpart[1][j + 256];
            float gg = (float)p1.x + gpart[0][j + 512] + gpart[1][j + 512];
            float og = (float)p1.y + gpart[0][j + 768] + gpart[1][j + 768];
            c_state = fsigm(fg) * c_state + fsigm(ig) * ftanh_(gg);
            float h = fsigm(og) * ftanh_(c_state);
            HALL16[((size_t)(b * 256 + t)) * 256 + j] = (_Float16)h;
            U32H2 hxp; hxp.h = h2t{(_Float16)h, (_Float16)0.f};
            unsigned int hu = hxp.u & 0xffffu;
            unsigned int other = (unsigned int)__shfl_xor((int)hu, 1);
            if ((j & 1) == 0) h2_s[j >> 1] = hu | (other << 16);
            int tn = (t < 255) ? (t + 1) : 255;
            gi = *(const uint2*)(ginb + (size_t)tn * 1024 + j * 4);
        }
        __syncthreads();
    }
}

// ---------------------------------------------------------------------------
// Pointer logits: out[b,t,i] = vsum - 2 * sum_d v_d / (1 + exp2(s_d)),
// s = 2.88539*(hp+ep) (scale folded into LDS staging).
// ---------------------------------------------------------------------------
__global__ __launch_bounds__(256) void pointer_kernel(
    const float* __restrict__ HP, const float* __restrict__ EP,
    const float* __restrict__ v, float* __restrict__ out)
{
    int b = blockIdx.z, tt = blockIdx.y, it = blockIdx.x;
    __shared__ float hp_s[16][260];
    __shared__ float ep_s[16][260];
    __shared__ float v_s[256];
    __shared__ float red[4];
    int tid = threadIdx.x;
    const float cs = 2.88539008f;
    const float* hpb = HP + ((size_t)b * 256 + tt * 16) * 256;
    const float* epb = EP + ((size_t)b * 256 + it * 16) * 256;
#pragma unroll
    for (int l = 0; l < 4; ++l) {
        int idx = tid + l * 256;
        int r = idx >> 6, c4 = idx & 63;
        float4 hv = *(const float4*)(hpb + r * 256 + c4 * 4);
        hv.x *= cs; hv.y *= cs; hv.z *= cs; hv.w *= cs;
        *(float4*)&hp_s[r][c4 * 4] = hv;
        float4 ev = *(const float4*)(epb + r * 256 + c4 * 4);
        ev.x *= cs; ev.y *= cs; ev.z *= cs; ev.w *= cs;
        *(float4*)&ep_s[r][c4 * 4] = ev;
    }
    float vv = v[tid];
    v_s[tid] = vv;
    float vp = vv;
#pragma unroll
    for (int m = 1; m < 64; m <<= 1) vp += __shfl_xor(vp, m);
    if ((tid & 63) == 0) red[tid >> 6] = vp;
    __syncthreads();
    float vsum = red[0] + red[1] + red[2] + red[3];
    int tl = tid >> 4, il = tid & 15;
    float acc = 0.f;
#pragma unroll 4
    for (int d = 0; d < 256; ++d) {
        float sval = hp_s[tl][d] + ep_s[il][d];
        float r = frcp(1.0f + fexp2(sval));
        acc = fmaf(v_s[d], r, acc);
    }
    out[((size_t)b * 256 + tt * 16 + tl) * 256 + it * 16 + il] =
        vsum - 2.0f * acc;
}

// ---------------------------------------------------------------------------
extern "C" void kernel_launch(void* const* d_in, const int* in_sizes, int n_in,
                              void* d_out, int out_size, void* d_ws, size_t ws_size,
                              hipStream_t stream)
{
    const float* parts    = (const float*)d_in[0];
    const float* bin_info = (const float*)d_in[1];
    const int*   target   = (const int*)d_in[2];
    const float* pe_W1 = (const float*)d_in[3];
    const float* pe_b1 = (const float*)d_in[4];
    const float* pe_W2 = (const float*)d_in[5];
    const float* pe_b2 = (const float*)d_in[6];
    const float* be_W1 = (const float*)d_in[7];
    const float* be_b1 = (const float*)d_in[8];
    const float* be_W2 = (const float*)d_in[9];
    const float* be_b2 = (const float*)d_in[10];
    const float* pos_emb = (const float*)d_in[11];
    const float* tr_Wqkv = (const float*)d_in[12];
    const float* tr_bqkv = (const float*)d_in[13];
    const float* tr_Wo   = (const float*)d_in[14];
    const float* tr_bo   = (const float*)d_in[15];
    const float* tr_ln1_g = (const float*)d_in[16];
    const float* tr_ln1_b = (const float*)d_in[17];
    const float* tr_ff_W1 = (const float*)d_in[18];
    const float* tr_ff_b1 = (const float*)d_in[19];
    const float* tr_ff_W2 = (const float*)d_in[20];
    const float* tr_ff_b2 = (const float*)d_in[21];
    const float* tr_ln2_g = (const float*)d_in[22];
    const float* tr_ln2_b = (const float*)d_in[23];
    const float* lstm_Wih = (const float*)d_in[24];
    const float* lstm_Whh = (const float*)d_in[25];
    const float* lstm_bih = (const float*)d_in[26];
    const float* lstm_bhh = (const float*)d_in[27];
    const float* ptr_W = (const float*)d_in[28];
    const float* ptr_b = (const float*)d_in[29];
    const float* ptr_v = (const float*)d_in[30];

    // ---- workspace layout (floats) ----
    float* ws = (float*)d_ws;
    float* X     = ws;                        // 2,097,152
    float* S1    = X + 2097152;               // 8,388,608 (qkv/ff1/g_in f16)
    float* CF32  = S1 + 8388608;              // 2,097,152
    float* EPROJ = CF32 + 2097152;            // 2,097,152
    float* X16f  = EPROJ + 2097152;           // 1,048,576
    float* S2f   = X16f + 1048576;            // 1,048,576
    float* W16f  = S2f + 1048576;             // 1,048,576
    float* WBf   = W16f + 1048576;            // 131,072
    float* BBuf  = WBf + 131072;              // 2,048 (unused)
    float* PB    = BBuf + 2048;               // 1,024

    _Float16* X16    = (_Float16*)X16f;
    _Float16* Xg16   = X16;
    _Float16* S2h    = (_Float16*)S2f;
    _Float16* HALL16 = S2h;
    _Float16* S1h    = (_Float16*)S1;
    _Float16* W16    = (_Float16*)W16f;
    _Float16* Wqkv16 = W16;                   // 589,824
    _Float16* Wo16   = Wqkv16 + 589824;       // 196,608
    _Float16* Wff116 = Wo16 + 196608;         // 393,216
    _Float16* Wff216 = Wff116 + 393216;       // 393,216
    _Float16* Wih16  = Wff216 + 393216;       // 262,144 (gate-interleaved rows)
    _Float16* WpW16  = Wih16 + 262144;        // 65,536

    // ---- one-time weight conversions (single fused launch) ----
    cvt_fused_kernel<<<7936, 256, 0, stream>>>(
        tr_Wqkv, tr_Wo, tr_ff_W1, tr_ff_W2, lstm_Wih, ptr_W, W16,
        lstm_Whh, (unsigned int*)WBf, lstm_bih, lstm_bhh, PB);

    // ---- encoders (bin fused into part) ----
    part_enc_kernel<<<256, 128, 0, stream>>>(parts, pe_W1, pe_b1, pe_W2, pe_b2,
                                             bin_info, be_W1, be_b1, be_W2, be_b2,
                                             pos_emb, X, X16);

    // ---- transformer layers ----
    for (int l = 0; l < 3; ++l) {
        hgemm_kernel<64, 128, false, true><<<dim3(128, 6), 256, 0, stream>>>(
            X16, Wqkv16 + (size_t)l * 196608, tr_bqkv + l * 768, nullptr,
            S1h, 8192, 768, 256);
        attn_mfma_kernel<<<256, 256, 0, stream>>>(S1h, S2h);
        hgemm_ln_kernel<<<128, 256, 0, stream>>>(
            S2h, Wo16 + (size_t)l * 65536, tr_bo + l * 256,
            tr_ln1_g + l * 256, tr_ln1_b + l * 256, X, X16, 256);
        hgemm_kernel<64, 128, true, true><<<dim3(128, 4), 256, 0, stream>>>(
            X16, Wff116 + (size_t)l * 131072, tr_ff_b1 + l * 512, nullptr,
            S1h, 8192, 512, 256);
        hgemm_ln_kernel<<<128, 256, 0, stream>>>(
            S1h, Wff216 + (size_t)l * 131072, tr_ff_b2 + l * 256,
            tr_ln2_g + l * 256, tr_ln2_b + l * 256, X, X16, 512);
    }

    // ---- pointer decode ----
    hgemm_kernel<64, 64, false, false><<<dim3(128, 4), 256, 0, stream>>>(
        X16, WpW16, ptr_b, nullptr, EPROJ, 8192, 256, 256);
    gather_kernel<<<8192, 256, 0, stream>>>(X, target, Xg16);
    hgemm_kernel<64, 128, false, true><<<dim3(128, 8), 256, 0, stream>>>(
        Xg16, Wih16, PB, nullptr, S1h, 8192, 1024, 256);
    lstm_kernel<<<32, 512, 0, stream>>>(S1h, (const uint4*)WBf, HALL16);
    hgemm_kernel<64, 64, false, false><<<dim3(128, 4), 256, 0, stream>>>(
        HALL16, WpW16, ptr_b, nullptr, CF32, 8192, 256, 256);
    pointer_kernel<<<dim3(16, 16, 32), 256, 0, stream>>>(CF32, EPROJ, ptr_v,
                                                         (float*)d_out);
}

// Round 7
// 1114.534 us; speedup vs baseline: 1.5516x; 1.0053x over previous
//
#include <hip/hip_runtime.h>
#include <cstddef>

#define DEV __device__ __forceinline__

DEV float fexp2(float x) { return __builtin_amdgcn_exp2f(x); }
DEV float frcp(float x)  { return __builtin_amdgcn_rcpf(x); }
DEV float fsigm(float x) { return frcp(1.0f + fexp2(-1.44269504f * x)); }
DEV float ftanh_(float x){ return 1.0f - 2.0f * frcp(1.0f + fexp2(2.88539008f * x)); }

typedef _Float16 h2t __attribute__((ext_vector_type(2)));
typedef _Float16 v8h __attribute__((ext_vector_type(8)));
typedef float v4f __attribute__((ext_vector_type(4)));
union U32H2 { unsigned int u; h2t h; };
DEV h2t u2h(unsigned int u) { U32H2 x; x.u = u; return x.h; }

// ---------------------------------------------------------------------------
// f16 MFMA GEMM: C[M,N] = A[M,K] @ W[N,K]^T + bias; A,W f16 row-major.
// BM in {64,128}, BK=32, 256 threads (4 waves, 2x2), wave tile (BM/2)x(BN/2).
// ---------------------------------------------------------------------------
template <int BM, int BN, bool RELU, bool OUTF16>
__global__ __launch_bounds__(256) void hgemm_kernel(
    const _Float16* __restrict__ A, const _Float16* __restrict__ W,
    const float* __restrict__ bias1, const float* __restrict__ bias2,
    void* __restrict__ Cout, int M, int N, int K)
{
    constexpr int MT = BM / 32;
    constexpr int NT = BN / 32;
    constexpr int RA = BM / 64;
    constexpr int RB = BN / 64;
    __shared__ _Float16 As[BM * 32];
    __shared__ _Float16 Bs[BN * 32];

    const int tid = threadIdx.x;
    const int lane = tid & 63;
    const int lm = lane & 15, lq = lane >> 4;
    const int wrow = ((tid >> 6) & 1) * (BM / 2);
    const int wcol = (tid >> 7) * (BN / 2);
    const int m0 = blockIdx.x * BM, n0 = blockIdx.y * BN;
    const _Float16* Ab = A + (size_t)m0 * K;
    const _Float16* Wb = W + (size_t)n0 * K;

    v4f acc[MT][NT];
#pragma unroll
    for (int i = 0; i < MT; ++i)
#pragma unroll
        for (int j = 0; j < NT; ++j) acc[i][j] = (v4f){0.f, 0.f, 0.f, 0.f};

    const int rowS = tid >> 2, qS = tid & 3;

    uint4 ra[RA], rb[RB];
#pragma unroll
    for (int r = 0; r < RA; ++r)
        ra[r] = *(const uint4*)(Ab + (size_t)(rowS + 64 * r) * K + qS * 8);
#pragma unroll
    for (int r = 0; r < RB; ++r)
        rb[r] = *(const uint4*)(Wb + (size_t)(rowS + 64 * r) * K + qS * 8);

    for (int k0 = 0; k0 < K; k0 += 32) {
        __syncthreads();
#pragma unroll
        for (int r = 0; r < RA; ++r)
            *(uint4*)(As + (size_t)(tid + 256 * r) * 8) = ra[r];
#pragma unroll
        for (int r = 0; r < RB; ++r)
            *(uint4*)(Bs + (size_t)(tid + 256 * r) * 8) = rb[r];
        __syncthreads();
        int kn = k0 + 32;
        if (kn < K) {
#pragma unroll
            for (int r = 0; r < RA; ++r)
                ra[r] = *(const uint4*)(Ab + (size_t)(rowS + 64 * r) * K + kn + qS * 8);
#pragma unroll
            for (int r = 0; r < RB; ++r)
                rb[r] = *(const uint4*)(Wb + (size_t)(rowS + 64 * r) * K + kn + qS * 8);
        }
        v8h af[MT], bf[NT];
#pragma unroll
        for (int i = 0; i < MT; ++i)
            af[i] = *(const v8h*)(As + (size_t)(wrow + i * 16 + lm) * 32 + lq * 8);
#pragma unroll
        for (int j = 0; j < NT; ++j)
            bf[j] = *(const v8h*)(Bs + (size_t)(wcol + j * 16 + lm) * 32 + lq * 8);
#pragma unroll
        for (int i = 0; i < MT; ++i)
#pragma unroll
            for (int j = 0; j < NT; ++j)
                acc[i][j] = __builtin_amdgcn_mfma_f32_16x16x32_f16(
                    af[i], bf[j], acc[i][j], 0, 0, 0);
    }

#pragma unroll
    for (int j = 0; j < NT; ++j) {
        int col = n0 + wcol + j * 16 + lm;
        float bv = bias1[col];
        if (bias2) bv += bias2[col];
#pragma unroll
        for (int i = 0; i < MT; ++i) {
            int rbase = m0 + wrow + i * 16 + lq * 4;
#pragma unroll
            for (int rg = 0; rg < 4; ++rg) {
                float vv = acc[i][j][rg] + bv;
                if (RELU) vv = fmaxf(vv, 0.f);
                if (OUTF16)
                    ((_Float16*)Cout)[(size_t)(rbase + rg) * N + col] = (_Float16)vv;
                else
                    ((float*)Cout)[(size_t)(rbase + rg) * N + col] = vv;
            }
        }
    }
}

// ---------------------------------------------------------------------------
// Wih GEMM with fused teacher-forcing gather: A row m (= b*256+t) is
// X16[b*256 + target[b*256+t-1]] (zeros for t==0). BM=64, BN=128, K=256.
// Replaces the separate 8192-block gather dispatch; numerically identical
// (gather wrote (f16)X[src], X16[src] = (f16)X[src]).
// ---------------------------------------------------------------------------
__global__ __launch_bounds__(256) void hgemm_gather_kernel(
    const _Float16* __restrict__ X16, const int* __restrict__ target,
    const _Float16* __restrict__ W, const float* __restrict__ bias1,
    _Float16* __restrict__ Cout, int N, int K)
{
    constexpr int BM = 64, BN = 128, MT = 2, NT = 4, RB = 2;
    __shared__ _Float16 As[BM * 32];
    __shared__ _Float16 Bs[BN * 32];

    const int tid = threadIdx.x;
    const int lane = tid & 63;
    const int lm = lane & 15, lq = lane >> 4;
    const int wrow = ((tid >> 6) & 1) * (BM / 2);
    const int wcol = (tid >> 7) * (BN / 2);
    const int m0 = blockIdx.x * BM, n0 = blockIdx.y * BN;
    const _Float16* Wb = W + (size_t)n0 * K;

    v4f acc[MT][NT];
#pragma unroll
    for (int i = 0; i < MT; ++i)
#pragma unroll
        for (int j = 0; j < NT; ++j) acc[i][j] = (v4f){0.f, 0.f, 0.f, 0.f};

    const int rowS = tid >> 2, qS = tid & 3;

    // per-row indirection (hoisted: row -> source pointer, zero-mask)
    const int m = m0 + rowS;
    const int bb = m >> 8, tt = m & 255;
    const bool valid = (tt > 0);
    const _Float16* arow = X16;
    if (valid) {
        int src = target[bb * 256 + tt - 1];
        arow = X16 + ((size_t)(bb * 256 + src)) * 256;
    }

    uint4 ra, rb[RB];
    ra = valid ? *(const uint4*)(arow + qS * 8) : (uint4){0u, 0u, 0u, 0u};
#pragma unroll
    for (int r = 0; r < RB; ++r)
        rb[r] = *(const uint4*)(Wb + (size_t)(rowS + 64 * r) * K + qS * 8);

    for (int k0 = 0; k0 < K; k0 += 32) {
        __syncthreads();
        *(uint4*)(As + (size_t)tid * 8) = ra;
#pragma unroll
        for (int r = 0; r < RB; ++r)
            *(uint4*)(Bs + (size_t)(tid + 256 * r) * 8) = rb[r];
        __syncthreads();
        int kn = k0 + 32;
        if (kn < K) {
            ra = valid ? *(const uint4*)(arow + kn + qS * 8)
                       : (uint4){0u, 0u, 0u, 0u};
#pragma unroll
            for (int r = 0; r < RB; ++r)
                rb[r] = *(const uint4*)(Wb + (size_t)(rowS + 64 * r) * K + kn + qS * 8);
        }
        v8h af[MT], bf[NT];
#pragma unroll
        for (int i = 0; i < MT; ++i)
            af[i] = *(const v8h*)(As + (size_t)(wrow + i * 16 + lm) * 32 + lq * 8);
#pragma unroll
        for (int j = 0; j < NT; ++j)
            bf[j] = *(const v8h*)(Bs + (size_t)(wcol + j * 16 + lm) * 32 + lq * 8);
#pragma unroll
        for (int i = 0; i < MT; ++i)
#pragma unroll
            for (int j = 0; j < NT; ++j)
                acc[i][j] = __builtin_amdgcn_mfma_f32_16x16x32_f16(
                    af[i], bf[j], acc[i][j], 0, 0, 0);
    }

#pragma unroll
    for (int j = 0; j < NT; ++j) {
        int col = n0 + wcol + j * 16 + lm;
        float bv = bias1[col];
#pragma unroll
        for (int i = 0; i < MT; ++i) {
            int rbase = m0 + wrow + i * 16 + lq * 4;
#pragma unroll
            for (int rg = 0; rg < 4; ++rg)
                Cout[(size_t)(rbase + rg) * N + col] =
                    (_Float16)(acc[i][j][rg] + bv);
        }
    }
}

// ---------------------------------------------------------------------------
// GEMM (N=256 fixed) + bias + residual + LayerNorm fused.
// Out: X (f32, in-place residual target) and X16 (f16 copy).
// BM=64, BN=256, 256 threads (4 waves, 2x2), wave tile 32x128.
// ---------------------------------------------------------------------------
__global__ __launch_bounds__(256) void hgemm_ln_kernel(
    const _Float16* __restrict__ A, const _Float16* __restrict__ W,
    const float* __restrict__ bias, const float* __restrict__ gamma,
    const float* __restrict__ beta, float* __restrict__ X,
    _Float16* __restrict__ X16, int K)
{
    constexpr int BM = 64, BN = 256, MT = 2, NT = 8, RA = 1, RB = 4;
    __shared__ _Float16 As[BM * 32];
    __shared__ _Float16 Bs[BN * 32];
    __shared__ float redS[2][BM][2];

    const int tid = threadIdx.x;
    const int lane = tid & 63;
    const int lm = lane & 15, lq = lane >> 4;
    const int wrow = ((tid >> 6) & 1) * 32;
    const int wcol = (tid >> 7) * 128;
    const int half = tid >> 7;
    const int m0 = blockIdx.x * BM;
    const _Float16* Ab = A + (size_t)m0 * K;

    v4f acc[MT][NT];
#pragma unroll
    for (int i = 0; i < MT; ++i)
#pragma unroll
        for (int j = 0; j < NT; ++j) acc[i][j] = (v4f){0.f, 0.f, 0.f, 0.f};

    const int rowS = tid >> 2, qS = tid & 3;

    uint4 ra[RA], rb[RB];
#pragma unroll
    for (int r = 0; r < RA; ++r)
        ra[r] = *(const uint4*)(Ab + (size_t)(rowS + 64 * r) * K + qS * 8);
#pragma unroll
    for (int r = 0; r < RB; ++r)
        rb[r] = *(const uint4*)(W + (size_t)(rowS + 64 * r) * K + qS * 8);

    for (int k0 = 0; k0 < K; k0 += 32) {
        __syncthreads();
#pragma unroll
        for (int r = 0; r < RA; ++r)
            *(uint4*)(As + (size_t)(tid + 256 * r) * 8) = ra[r];
#pragma unroll
        for (int r = 0; r < RB; ++r)
            *(uint4*)(Bs + (size_t)(tid + 256 * r) * 8) = rb[r];
        __syncthreads();
        int kn = k0 + 32;
        if (kn < K) {
#pragma unroll
            for (int r = 0; r < RA; ++r)
                ra[r] = *(const uint4*)(Ab + (size_t)(rowS + 64 * r) * K + kn + qS * 8);
#pragma unroll
            for (int r = 0; r < RB; ++r)
                rb[r] = *(const uint4*)(W + (size_t)(rowS + 64 * r) * K + kn + qS * 8);
        }
        v8h af[MT], bf[NT];
#pragma unroll
        for (int i = 0; i < MT; ++i)
            af[i] = *(const v8h*)(As + (size_t)(wrow + i * 16 + lm) * 32 + lq * 8);
#pragma unroll
        for (int j = 0; j < NT; ++j)
            bf[j] = *(const v8h*)(Bs + (size_t)(wcol + j * 16 + lm) * 32 + lq * 8);
#pragma unroll
        for (int i = 0; i < MT; ++i)
#pragma unroll
            for (int j = 0; j < NT; ++j)
                acc[i][j] = __builtin_amdgcn_mfma_f32_16x16x32_f16(
                    af[i], bf[j], acc[i][j], 0, 0, 0);
    }

    // y = gemm + bias + residual; accumulate per-row sums
    float s[MT][4], s2[MT][4];
#pragma unroll
    for (int i = 0; i < MT; ++i)
#pragma unroll
        for (int rg = 0; rg < 4; ++rg) { s[i][rg] = 0.f; s2[i][rg] = 0.f; }
#pragma unroll
    for (int j = 0; j < NT; ++j) {
        int col = wcol + j * 16 + lm;
        float bv = bias[col];
#pragma unroll
        for (int i = 0; i < MT; ++i) {
            int rbase = m0 + wrow + i * 16 + lq * 4;
#pragma unroll
            for (int rg = 0; rg < 4; ++rg) {
                float y = acc[i][j][rg] + bv + X[(size_t)(rbase + rg) * 256 + col];
                acc[i][j][rg] = y;
                s[i][rg] += y;
                s2[i][rg] += y * y;
            }
        }
    }
    // reduce across the 16 lm lanes (same row), publish per-half partials
#pragma unroll
    for (int i = 0; i < MT; ++i)
#pragma unroll
        for (int rg = 0; rg < 4; ++rg) {
            float a = s[i][rg], b2 = s2[i][rg];
#pragma unroll
            for (int m = 1; m < 16; m <<= 1) {
                a += __shfl_xor(a, m);
                b2 += __shfl_xor(b2, m);
            }
            if (lm == 0) {
                int rloc = wrow + i * 16 + lq * 4 + rg;
                redS[half][rloc][0] = a;
                redS[half][rloc][1] = b2;
            }
        }
    __syncthreads();
#pragma unroll
    for (int i = 0; i < MT; ++i) {
#pragma unroll
        for (int rg = 0; rg < 4; ++rg) {
            int rloc = wrow + i * 16 + lq * 4 + rg;
            float st = redS[0][rloc][0] + redS[1][rloc][0];
            float s2t = redS[0][rloc][1] + redS[1][rloc][1];
            float mean = st * (1.f / 256.f);
            float var = s2t * (1.f / 256.f) - mean * mean;
            float inv = rsqrtf(var + 1e-5f);
            size_t rowb = (size_t)(m0 + rloc) * 256;
#pragma unroll
            for (int j = 0; j < NT; ++j) {
                int col = wcol + j * 16 + lm;
                float o = (acc[i][j][rg] - mean) * inv * gamma[col] + beta[col];
                X[rowb + col] = o;
                X16[rowb + col] = (_Float16)o;
            }
        }
    }
}

// ---------------------------------------------------------------------------
// Fused weight conversion (cvt_all + Whh blob + permuted bias in one launch).
// Wih dest rows are gate-interleaved: dest row j*4+g = src row g*256+j.
// Whh blob chunk map (q=0..63 -> (i,c)): LDS 8 (c<2 all i), regs 44
// (2<=c<13 all i), stream 12 (13<=c<16 all i).  [R0 layout, measured-best]
// ---------------------------------------------------------------------------
__global__ __launch_bounds__(256) void cvt_fused_kernel(
    const float* __restrict__ s0, const float* __restrict__ s1,
    const float* __restrict__ s2, const float* __restrict__ s3,
    const float* __restrict__ s4, const float* __restrict__ s5,
    _Float16* __restrict__ dst,
    const float* __restrict__ Whh, unsigned int* __restrict__ WB,
    const float* __restrict__ bih, const float* __restrict__ bhh,
    float* __restrict__ PB)
{
    if (blockIdx.x < 7424) {
        int i = blockIdx.x * 256 + threadIdx.x;
        if (i >= 1900544) return;
        float val;
        if (i < 589824)       val = s0[i];
        else if (i < 786432)  val = s1[i - 589824];
        else if (i < 1179648) val = s2[i - 786432];
        else if (i < 1572864) val = s3[i - 1179648];
        else if (i < 1835008) {
            int idx = i - 1572864;
            int rp = idx >> 8, k = idx & 255;
            int j = rp >> 2, g = rp & 3;
            val = s4[(g * 256 + j) * 256 + k];
        }
        else                  val = s5[i - 1835008];
        dst[i] = (_Float16)val;
    } else {
        int idx = (blockIdx.x - 7424) * 256 + threadIdx.x;  // 0..131071
        if (idx < 1024) {
            int j = idx >> 2, g = idx & 3;
            PB[idx] = bih[g * 256 + j] + bhh[g * 256 + j];
        }
        int l = idx & 3;
        int gt = idx >> 2;
        int tid = gt & 511;
        int q = gt >> 9;                            // 0..63
        int i, c;
        if (q < 8)       { i = q >> 1; c = q & 1; }
        else if (q < 52) { int qq = q - 8; i = qq / 11; c = 2 + qq % 11; }
        else             { int qq = q - 52; c = 13 + (qq >> 2); i = qq & 3; }
        int r = ((tid & 255) << 2) + i;
        int k = ((tid >> 8) << 7) + (c << 3) + (l << 1);
        _Float16 lo = (_Float16)Whh[r * 256 + k];
        _Float16 hi = (_Float16)Whh[r * 256 + k + 1];
        U32H2 x; x.h = h2t{lo, hi};
        WB[idx] = x.u;
    }
}

// ---------------------------------------------------------------------------
// Part encoder with bin-encoder fused (bb computed redundantly per block).
// ---------------------------------------------------------------------------
__global__ __launch_bounds__(128) void part_enc_kernel(
    const float* __restrict__ parts, const float* __restrict__ W1,
    const float* __restrict__ b1, const float* __restrict__ W2,
    const float* __restrict__ b2, const float* __restrict__ bin_info,
    const float* __restrict__ be_W1, const float* __restrict__ be_b1,
    const float* __restrict__ be_W2, const float* __restrict__ be_b2,
    const float* __restrict__ pos_emb, float* __restrict__ X,
    _Float16* __restrict__ X16)
{
    __shared__ float W2s[128][129];
    __shared__ float h1[128];
    __shared__ float pin[16];
    __shared__ float h1b[64];
    __shared__ float bb_s[64];
    int tid = threadIdx.x;
    int b = blockIdx.x >> 3, s0 = (blockIdx.x & 7) * 32;
    for (int l = 0; l < 128; ++l) W2s[l][tid] = W2[l * 128 + tid];
    // bin encoder (64-dim MLP, redundant per block, trivial)
    {
        float x0 = bin_info[b * 2], x1 = bin_info[b * 2 + 1];
        if (tid < 64)
            h1b[tid] = fmaxf(be_W1[tid * 2] * x0 + be_W1[tid * 2 + 1] * x1
                             + be_b1[tid], 0.f);
        __syncthreads();
        if (tid < 64) {
            float a = be_b2[tid];
#pragma unroll 4
            for (int e = 0; e < 64; ++e) a += be_W2[tid * 64 + e] * h1b[e];
            bb_s[tid] = a;
        }
        __syncthreads();
    }
    float w1r[16];
#pragma unroll
    for (int k = 0; k < 16; ++k) w1r[k] = W1[tid * 16 + k];
    float bias1v = b1[tid], bias2v = b2[tid];
    for (int si = 0; si < 32; ++si) {
        int s = s0 + si;
        size_t row = (size_t)b * 256 + s;
        if (tid < 16) pin[tid] = parts[row * 16 + tid];
        __syncthreads();
        float h = bias1v;
#pragma unroll
        for (int k = 0; k < 16; ++k) h += w1r[k] * pin[k];
        h1[tid] = fmaxf(h, 0.f);
        __syncthreads();
        float acc = bias2v;
#pragma unroll 4
        for (int e = 0; e < 128; ++e) acc += W2s[tid][e] * h1[e];
        X[row * 256 + tid] = acc;
        X16[row * 256 + tid] = (_Float16)acc;
        if (tid < 64) {
            float bbv = bb_s[tid];
            float pev = pos_emb[s * 64 + tid];
            X[row * 256 + 128 + tid] = bbv;
            X[row * 256 + 192 + tid] = pev;
            X16[row * 256 + 128 + tid] = (_Float16)bbv;
            X16[row * 256 + 192 + tid] = (_Float16)pev;
        }
        __syncthreads();
    }
}

// ---------------------------------------------------------------------------
// MFMA attention: one block per (b,h), 256 threads (4 waves).
// ---------------------------------------------------------------------------
__global__ __launch_bounds__(256) void attn_mfma_kernel(
    const _Float16* __restrict__ QKV, _Float16* __restrict__ O16)
{
    int bh = blockIdx.x;
    int b = bh >> 3, h = bh & 7;
    const int tid = threadIdx.x;
    const int w = tid >> 6;
    const int lane = tid & 63;
    const int lm = lane & 15, lq = lane >> 4;
    const float c_se = 0.17677669529663687f * 1.44269504f;

    __shared__ _Float16 Ks[4][256][8];
    __shared__ _Float16 Vt[32][264];
    __shared__ _Float16 Ps[4][16][264];

    const _Float16* qkvb = QKV + (size_t)(b * 256) * 768 + h * 32;
    {
        int s = tid;
        const _Float16* kr = qkvb + (size_t)s * 768 + 256;
#pragma unroll
        for (int c = 0; c < 4; ++c)
            *(uint4*)&Ks[c][s][0] = *(const uint4*)(kr + c * 8);
        const _Float16* vr = qkvb + (size_t)s * 768 + 512;
        _Float16 vtmp[32];
        *(uint4*)&vtmp[0]  = *(const uint4*)(vr);
        *(uint4*)&vtmp[8]  = *(const uint4*)(vr + 8);
        *(uint4*)&vtmp[16] = *(const uint4*)(vr + 16);
        *(uint4*)&vtmp[24] = *(const uint4*)(vr + 24);
#pragma unroll
        for (int d = 0; d < 32; ++d) Vt[d][s] = vtmp[d];
    }
    __syncthreads();

#pragma unroll 1
    for (int st = 0; st < 4; ++st) {
        int rt = w * 4 + st;
        v8h qf = *(const v8h*)(QKV + (size_t)(b * 256 + rt * 16 + lm) * 768
                               + h * 32 + lq * 8);
        v4f acc[16];
#pragma unroll
        for (int ct = 0; ct < 16; ++ct) {
            v8h kf = *(const v8h*)&Ks[lq][ct * 16 + lm][0];
            acc[ct] = __builtin_amdgcn_mfma_f32_16x16x32_f16(
                qf, kf, (v4f){0.f, 0.f, 0.f, 0.f}, 0, 0, 0);
        }
        float sminv[4];
#pragma unroll
        for (int r = 0; r < 4; ++r) {
            float m = acc[0][r];
#pragma unroll
            for (int ct = 1; ct < 16; ++ct) m = fmaxf(m, acc[ct][r]);
#pragma unroll
            for (int msk = 1; msk < 16; msk <<= 1)
                m = fmaxf(m, __shfl_xor(m, msk));
            float ssum = 0.f;
#pragma unroll
            for (int ct = 0; ct < 16; ++ct) {
                float e = fexp2((acc[ct][r] - m) * c_se);
                acc[ct][r] = e;
                ssum += e;
            }
#pragma unroll
            for (int msk = 1; msk < 16; msk <<= 1)
                ssum += __shfl_xor(ssum, msk);
            sminv[r] = frcp(ssum);
        }
#pragma unroll
        for (int ct = 0; ct < 16; ++ct)
#pragma unroll
            for (int r = 0; r < 4; ++r)
                Ps[w][lq * 4 + r][ct * 16 + lm] =
                    (_Float16)(acc[ct][r] * sminv[r]);
#pragma unroll
        for (int dt = 0; dt < 2; ++dt) {
            v4f o = (v4f){0.f, 0.f, 0.f, 0.f};
#pragma unroll
            for (int jc = 0; jc < 8; ++jc) {
                v8h pf = *(const v8h*)&Ps[w][lm][jc * 32 + lq * 8];
                v8h vf = *(const v8h*)&Vt[dt * 16 + lm][jc * 32 + lq * 8];
                o = __builtin_amdgcn_mfma_f32_16x16x32_f16(pf, vf, o, 0, 0, 0);
            }
#pragma unroll
            for (int r = 0; r < 4; ++r)
                O16[(size_t)(b * 256 + rt * 16 + lq * 4 + r) * 256
                    + h * 32 + dt * 16 + lm] = (_Float16)o[r];
        }
    }
}

// ---------------------------------------------------------------------------
// LSTM recurrence: 1 block/batch, 512 threads. Weights: 64 KB LDS +
// 176 VGPR slab + 96 KB/step L2 stream. g_in f16 gate-interleaved [t][j*4+g].
// R0 design, measured 362-363us — best of all 5 weight-placement probes
// (R1 LDS-heavy 449, R2 readlane 408, R3/R4 MFMA-scratch 963/959,
// R5 MFMA reg/LDS 588). VALU+DS co-critical; do not re-balance placement.
// ---------------------------------------------------------------------------
__global__ __launch_bounds__(512) void lstm_kernel(
    const _Float16* __restrict__ g_in, const uint4* __restrict__ WB4,
    _Float16* __restrict__ HALL16)
{
    const int b = blockIdx.x;
    const int tid = threadIdx.x;
    const int kh = tid >> 8, j4 = tid & 255;

    __shared__ uint4 WL4[4096];        // 64 KB
    __shared__ float gpart[2][1024];   // 8 KB
    __shared__ uint4 h2v[32];          // 512 B
    unsigned int* h2_s = (unsigned int*)h2v;

#pragma unroll
    for (int g = 0; g < 8; ++g) WL4[g * 512 + tid] = WB4[g * 512 + tid];
    uint4 wr[44];
#pragma unroll
    for (int q = 0; q < 44; ++q) wr[q] = WB4[(8 + q) * 512 + tid];
    if (tid < 128) h2_s[tid] = 0u;

    const _Float16* ginb = g_in + (size_t)b * 256 * 1024;
    uint2 gi = make_uint2(0u, 0u);
    if (tid < 256) gi = *(const uint2*)(ginb + tid * 4);
    float c_state = 0.f;
    const uint4* SW4 = WB4 + 52 * 512;
    __syncthreads();

    for (int t = 0; t < 256; ++t) {
        uint4 sw[12];
#pragma unroll
        for (int q = 0; q < 4; ++q) sw[q] = SW4[q * 512 + tid];

        float acc[4] = {0.f, 0.f, 0.f, 0.f};
#pragma unroll
        for (int c = 0; c < 16; ++c) {
            if (c == 2) {
#pragma unroll
                for (int q = 4; q < 8; ++q) sw[q] = SW4[q * 512 + tid];
            }
            if (c == 6) {
#pragma unroll
                for (int q = 8; q < 12; ++q) sw[q] = SW4[q * 512 + tid];
            }
            uint4 h4 = h2v[(kh << 4) + c];
            h2t hx = u2h(h4.x), hy = u2h(h4.y), hz = u2h(h4.z), hw = u2h(h4.w);
#pragma unroll
            for (int i = 0; i < 4; ++i) {
                uint4 w = (c < 2)  ? WL4[((i << 1) + c) * 512 + tid]
                        : (c < 13) ? wr[i * 11 + (c - 2)]
                                   : sw[((c - 13) << 2) + i];
                acc[i] = __builtin_amdgcn_fdot2(u2h(w.x), hx, acc[i], false);
                acc[i] = __builtin_amdgcn_fdot2(u2h(w.y), hy, acc[i], false);
                acc[i] = __builtin_amdgcn_fdot2(u2h(w.z), hz, acc[i], false);
                acc[i] = __builtin_amdgcn_fdot2(u2h(w.w), hw, acc[i], false);
            }
        }
        *(float4*)&gpart[kh][j4 << 2] = make_float4(acc[0], acc[1], acc[2], acc[3]);
        __syncthreads();

        if (tid < 256) {
            int j = tid;
            h2t p0 = u2h(gi.x), p1 = u2h(gi.y);
            float ig = (float)p0.x + gpart[0][j]       + gpart[1][j];
            float fg = (float)p0.y + gpart[0][j + 256] + gpart[1][j + 256];
            float gg = (float)p1.x + gpart[0][j + 512] + gpart[1][j + 512];
            float og = (float)p1.y + gpart[0][j + 768] + gpart[1][j + 768];
            c_state = fsigm(fg) * c_state + fsigm(ig) * ftanh_(gg);
            float h = fsigm(og) * ftanh_(c_state);
            HALL16[((size_t)(b * 256 + t)) * 256 + j] = (_Float16)h;
            U32H2 hxp; hxp.h = h2t{(_Float16)h, (_Float16)0.f};
            unsigned int hu = hxp.u & 0xffffu;
            unsigned int other = (unsigned int)__shfl_xor((int)hu, 1);
            if ((j & 1) == 0) h2_s[j >> 1] = hu | (other << 16);
            int tn = (t < 255) ? (t + 1) : 255;
            gi = *(const uint2*)(ginb + (size_t)tn * 1024 + j * 4);
        }
        __syncthreads();
    }
}

// ---------------------------------------------------------------------------
// Pointer logits: out[b,t,i] = vsum - 2 * sum_d v_d / (1 + exp2(s_d)),
// s = 2.88539*(hp+ep) (scale folded into LDS staging).
// ---------------------------------------------------------------------------
__global__ __launch_bounds__(256) void pointer_kernel(
    const float* __restrict__ HP, const float* __restrict__ EP,
    const float* __restrict__ v, float* __restrict__ out)
{
    int b = blockIdx.z, tt = blockIdx.y, it = blockIdx.x;
    __shared__ float hp_s[16][260];
    __shared__ float ep_s[16][260];
    __shared__ float v_s[256];
    __shared__ float red[4];
    int tid = threadIdx.x;
    const float cs = 2.88539008f;
    const float* hpb = HP + ((size_t)b * 256 + tt * 16) * 256;
    const float* epb = EP + ((size_t)b * 256 + it * 16) * 256;
#pragma unroll
    for (int l = 0; l < 4; ++l) {
        int idx = tid + l * 256;
        int r = idx >> 6, c4 = idx & 63;
        float4 hv = *(const float4*)(hpb + r * 256 + c4 * 4);
        hv.x *= cs; hv.y *= cs; hv.z *= cs; hv.w *= cs;
        *(float4*)&hp_s[r][c4 * 4] = hv;
        float4 ev = *(const float4*)(epb + r * 256 + c4 * 4);
        ev.x *= cs; ev.y *= cs; ev.z *= cs; ev.w *= cs;
        *(float4*)&ep_s[r][c4 * 4] = ev;
    }
    float vv = v[tid];
    v_s[tid] = vv;
    float vp = vv;
#pragma unroll
    for (int m = 1; m < 64; m <<= 1) vp += __shfl_xor(vp, m);
    if ((tid & 63) == 0) red[tid >> 6] = vp;
    __syncthreads();
    float vsum = red[0] + red[1] + red[2] + red[3];
    int tl = tid >> 4, il = tid & 15;
    float acc = 0.f;
#pragma unroll 4
    for (int d = 0; d < 256; ++d) {
        float sval = hp_s[tl][d] + ep_s[il][d];
        float r = frcp(1.0f + fexp2(sval));
        acc = fmaf(v_s[d], r, acc);
    }
    out[((size_t)b * 256 + tt * 16 + tl) * 256 + it * 16 + il] =
        vsum - 2.0f * acc;
}

// ---------------------------------------------------------------------------
extern "C" void kernel_launch(void* const* d_in, const int* in_sizes, int n_in,
                              void* d_out, int out_size, void* d_ws, size_t ws_size,
                              hipStream_t stream)
{
    const float* parts    = (const float*)d_in[0];
    const float* bin_info = (const float*)d_in[1];
    const int*   target   = (const int*)d_in[2];
    const float* pe_W1 = (const float*)d_in[3];
    const float* pe_b1 = (const float*)d_in[4];
    const float* pe_W2 = (const float*)d_in[5];
    const float* pe_b2 = (const float*)d_in[6];
    const float* be_W1 = (const float*)d_in[7];
    const float* be_b1 = (const float*)d_in[8];
    const float* be_W2 = (const float*)d_in[9];
    const float* be_b2 = (const float*)d_in[10];
    const float* pos_emb = (const float*)d_in[11];
    const float* tr_Wqkv = (const float*)d_in[12];
    const float* tr_bqkv = (const float*)d_in[13];
    const float* tr_Wo   = (const float*)d_in[14];
    const float* tr_bo   = (const float*)d_in[15];
    const float* tr_ln1_g = (const float*)d_in[16];
    const float* tr_ln1_b = (const float*)d_in[17];
    const float* tr_ff_W1 = (const float*)d_in[18];
    const float* tr_ff_b1 = (const float*)d_in[19];
    const float* tr_ff_W2 = (const float*)d_in[20];
    const float* tr_ff_b2 = (const float*)d_in[21];
    const float* tr_ln2_g = (const float*)d_in[22];
    const float* tr_ln2_b = (const float*)d_in[23];
    const float* lstm_Wih = (const float*)d_in[24];
    const float* lstm_Whh = (const float*)d_in[25];
    const float* lstm_bih = (const float*)d_in[26];
    const float* lstm_bhh = (const float*)d_in[27];
    const float* ptr_W = (const float*)d_in[28];
    const float* ptr_b = (const float*)d_in[29];
    const float* ptr_v = (const float*)d_in[30];

    // ---- workspace layout (floats) ----
    float* ws = (float*)d_ws;
    float* X     = ws;                        // 2,097,152
    float* S1    = X + 2097152;               // 8,388,608 (qkv/ff1/g_in f16)
    float* CF32  = S1 + 8388608;              // 2,097,152
    float* EPROJ = CF32 + 2097152;            // 2,097,152
    float* X16f  = EPROJ + 2097152;           // 1,048,576
    float* S2f   = X16f + 1048576;            // 1,048,576
    float* W16f  = S2f + 1048576;             // 1,048,576
    float* WBf   = W16f + 1048576;            // 131,072
    float* BBuf  = WBf + 131072;              // 2,048 (unused)
    float* PB    = BBuf + 2048;               // 1,024

    _Float16* X16    = (_Float16*)X16f;
    _Float16* S2h    = (_Float16*)S2f;
    _Float16* HALL16 = S2h;
    _Float16* S1h    = (_Float16*)S1;
    _Float16* W16    = (_Float16*)W16f;
    _Float16* Wqkv16 = W16;                   // 589,824
    _Float16* Wo16   = Wqkv16 + 589824;       // 196,608
    _Float16* Wff116 = Wo16 + 196608;         // 393,216
    _Float16* Wff216 = Wff116 + 393216;       // 393,216
    _Float16* Wih16  = Wff216 + 393216;       // 262,144 (gate-interleaved rows)
    _Float16* WpW16  = Wih16 + 262144;        // 65,536

    // ---- one-time weight conversions (single fused launch) ----
    cvt_fused_kernel<<<7936, 256, 0, stream>>>(
        tr_Wqkv, tr_Wo, tr_ff_W1, tr_ff_W2, lstm_Wih, ptr_W, W16,
        lstm_Whh, (unsigned int*)WBf, lstm_bih, lstm_bhh, PB);

    // ---- encoders (bin fused into part) ----
    part_enc_kernel<<<256, 128, 0, stream>>>(parts, pe_W1, pe_b1, pe_W2, pe_b2,
                                             bin_info, be_W1, be_b1, be_W2, be_b2,
                                             pos_emb, X, X16);

    // ---- transformer layers ----
    for (int l = 0; l < 3; ++l) {
        hgemm_kernel<64, 128, false, true><<<dim3(128, 6), 256, 0, stream>>>(
            X16, Wqkv16 + (size_t)l * 196608, tr_bqkv + l * 768, nullptr,
            S1h, 8192, 768, 256);
        attn_mfma_kernel<<<256, 256, 0, stream>>>(S1h, S2h);
        hgemm_ln_kernel<<<128, 256, 0, stream>>>(
            S2h, Wo16 + (size_t)l * 65536, tr_bo + l * 256,
            tr_ln1_g + l * 256, tr_ln1_b + l * 256, X, X16, 256);
        hgemm_kernel<64, 128, true, true><<<dim3(128, 4), 256, 0, stream>>>(
            X16, Wff116 + (size_t)l * 131072, tr_ff_b1 + l * 512, nullptr,
            S1h, 8192, 512, 256);
        hgemm_ln_kernel<<<128, 256, 0, stream>>>(
            S1h, Wff216 + (size_t)l * 131072, tr_ff_b2 + l * 256,
            tr_ln2_g + l * 256, tr_ln2_b + l * 256, X, X16, 512);
    }

    // ---- pointer decode ----
    hgemm_kernel<64, 64, false, false><<<dim3(128, 4), 256, 0, stream>>>(
        X16, WpW16, ptr_b, nullptr, EPROJ, 8192, 256, 256);
    hgemm_gather_kernel<<<dim3(128, 8), 256, 0, stream>>>(
        X16, target, Wih16, PB, S1h, 1024, 256);
    lstm_kernel<<<32, 512, 0, stream>>>(S1h, (const uint4*)WBf, HALL16);
    hgemm_kernel<64, 64, false, false><<<dim3(128, 4), 256, 0, stream>>>(
        HALL16, WpW16, ptr_b, nullptr, CF32, 8192, 256, 256);
    pointer_kernel<<<dim3(16, 16, 32), 256, 0, stream>>>(CF32, EPROJ, ptr_v,
                                                         (float*)d_out);
}

// Round 8
// 1051.831 us; speedup vs baseline: 1.6441x; 1.0596x over previous
//
#include <hip/hip_runtime.h>
#include <cstddef>

#define DEV __device__ __forceinline__

DEV float fexp2(float x) { return __builtin_amdgcn_exp2f(x); }
DEV float frcp(float x)  { return __builtin_amdgcn_rcpf(x); }
DEV float fsigm(float x) { return frcp(1.0f + fexp2(-1.44269504f * x)); }
DEV float ftanh_(float x){ return 1.0f - 2.0f * frcp(1.0f + fexp2(2.88539008f * x)); }

typedef _Float16 h2t __attribute__((ext_vector_type(2)));
typedef _Float16 v8h __attribute__((ext_vector_type(8)));
typedef float v4f __attribute__((ext_vector_type(4)));
union U32H2 { unsigned int u; h2t h; };
DEV h2t u2h(unsigned int u) { U32H2 x; x.u = u; return x.h; }

// ---------------------------------------------------------------------------
// f16 MFMA GEMM: C[M,N] = A[M,K] @ W[N,K]^T + bias; A,W f16 row-major.
// BM in {64,128}, BK=32, 256 threads (4 waves, 2x2), wave tile (BM/2)x(BN/2).
// ---------------------------------------------------------------------------
template <int BM, int BN, bool RELU, bool OUTF16>
__global__ __launch_bounds__(256) void hgemm_kernel(
    const _Float16* __restrict__ A, const _Float16* __restrict__ W,
    const float* __restrict__ bias1, const float* __restrict__ bias2,
    void* __restrict__ Cout, int M, int N, int K)
{
    constexpr int MT = BM / 32;
    constexpr int NT = BN / 32;
    constexpr int RA = BM / 64;
    constexpr int RB = BN / 64;
    __shared__ _Float16 As[BM * 32];
    __shared__ _Float16 Bs[BN * 32];

    const int tid = threadIdx.x;
    const int lane = tid & 63;
    const int lm = lane & 15, lq = lane >> 4;
    const int wrow = ((tid >> 6) & 1) * (BM / 2);
    const int wcol = (tid >> 7) * (BN / 2);
    const int m0 = blockIdx.x * BM, n0 = blockIdx.y * BN;
    const _Float16* Ab = A + (size_t)m0 * K;
    const _Float16* Wb = W + (size_t)n0 * K;

    v4f acc[MT][NT];
#pragma unroll
    for (int i = 0; i < MT; ++i)
#pragma unroll
        for (int j = 0; j < NT; ++j) acc[i][j] = (v4f){0.f, 0.f, 0.f, 0.f};

    const int rowS = tid >> 2, qS = tid & 3;

    uint4 ra[RA], rb[RB];
#pragma unroll
    for (int r = 0; r < RA; ++r)
        ra[r] = *(const uint4*)(Ab + (size_t)(rowS + 64 * r) * K + qS * 8);
#pragma unroll
    for (int r = 0; r < RB; ++r)
        rb[r] = *(const uint4*)(Wb + (size_t)(rowS + 64 * r) * K + qS * 8);

    for (int k0 = 0; k0 < K; k0 += 32) {
        __syncthreads();
#pragma unroll
        for (int r = 0; r < RA; ++r)
            *(uint4*)(As + (size_t)(tid + 256 * r) * 8) = ra[r];
#pragma unroll
        for (int r = 0; r < RB; ++r)
            *(uint4*)(Bs + (size_t)(tid + 256 * r) * 8) = rb[r];
        __syncthreads();
        int kn = k0 + 32;
        if (kn < K) {
#pragma unroll
            for (int r = 0; r < RA; ++r)
                ra[r] = *(const uint4*)(Ab + (size_t)(rowS + 64 * r) * K + kn + qS * 8);
#pragma unroll
            for (int r = 0; r < RB; ++r)
                rb[r] = *(const uint4*)(Wb + (size_t)(rowS + 64 * r) * K + kn + qS * 8);
        }
        v8h af[MT], bf[NT];
#pragma unroll
        for (int i = 0; i < MT; ++i)
            af[i] = *(const v8h*)(As + (size_t)(wrow + i * 16 + lm) * 32 + lq * 8);
#pragma unroll
        for (int j = 0; j < NT; ++j)
            bf[j] = *(const v8h*)(Bs + (size_t)(wcol + j * 16 + lm) * 32 + lq * 8);
#pragma unroll
        for (int i = 0; i < MT; ++i)
#pragma unroll
            for (int j = 0; j < NT; ++j)
                acc[i][j] = __builtin_amdgcn_mfma_f32_16x16x32_f16(
                    af[i], bf[j], acc[i][j], 0, 0, 0);
    }

#pragma unroll
    for (int j = 0; j < NT; ++j) {
        int col = n0 + wcol + j * 16 + lm;
        float bv = bias1[col];
        if (bias2) bv += bias2[col];
#pragma unroll
        for (int i = 0; i < MT; ++i) {
            int rbase = m0 + wrow + i * 16 + lq * 4;
#pragma unroll
            for (int rg = 0; rg < 4; ++rg) {
                float vv = acc[i][j][rg] + bv;
                if (RELU) vv = fmaxf(vv, 0.f);
                if (OUTF16)
                    ((_Float16*)Cout)[(size_t)(rbase + rg) * N + col] = (_Float16)vv;
                else
                    ((float*)Cout)[(size_t)(rbase + rg) * N + col] = vv;
            }
        }
    }
}

// ---------------------------------------------------------------------------
// Wih GEMM with fused teacher-forcing gather: A row m (= b*256+t) is
// X16[b*256 + target[b*256+t-1]] (zeros for t==0). BM=64, BN=128, K=256.
// ---------------------------------------------------------------------------
__global__ __launch_bounds__(256) void hgemm_gather_kernel(
    const _Float16* __restrict__ X16, const int* __restrict__ target,
    const _Float16* __restrict__ W, const float* __restrict__ bias1,
    _Float16* __restrict__ Cout, int N, int K)
{
    constexpr int BM = 64, BN = 128, MT = 2, NT = 4, RB = 2;
    __shared__ _Float16 As[BM * 32];
    __shared__ _Float16 Bs[BN * 32];

    const int tid = threadIdx.x;
    const int lane = tid & 63;
    const int lm = lane & 15, lq = lane >> 4;
    const int wrow = ((tid >> 6) & 1) * (BM / 2);
    const int wcol = (tid >> 7) * (BN / 2);
    const int m0 = blockIdx.x * BM, n0 = blockIdx.y * BN;
    const _Float16* Wb = W + (size_t)n0 * K;

    v4f acc[MT][NT];
#pragma unroll
    for (int i = 0; i < MT; ++i)
#pragma unroll
        for (int j = 0; j < NT; ++j) acc[i][j] = (v4f){0.f, 0.f, 0.f, 0.f};

    const int rowS = tid >> 2, qS = tid & 3;

    const int m = m0 + rowS;
    const int bb = m >> 8, tt = m & 255;
    const bool valid = (tt > 0);
    const _Float16* arow = X16;
    if (valid) {
        int src = target[bb * 256 + tt - 1];
        arow = X16 + ((size_t)(bb * 256 + src)) * 256;
    }

    uint4 ra, rb[RB];
    ra = valid ? *(const uint4*)(arow + qS * 8) : (uint4){0u, 0u, 0u, 0u};
#pragma unroll
    for (int r = 0; r < RB; ++r)
        rb[r] = *(const uint4*)(Wb + (size_t)(rowS + 64 * r) * K + qS * 8);

    for (int k0 = 0; k0 < K; k0 += 32) {
        __syncthreads();
        *(uint4*)(As + (size_t)tid * 8) = ra;
#pragma unroll
        for (int r = 0; r < RB; ++r)
            *(uint4*)(Bs + (size_t)(tid + 256 * r) * 8) = rb[r];
        __syncthreads();
        int kn = k0 + 32;
        if (kn < K) {
            ra = valid ? *(const uint4*)(arow + kn + qS * 8)
                       : (uint4){0u, 0u, 0u, 0u};
#pragma unroll
            for (int r = 0; r < RB; ++r)
                rb[r] = *(const uint4*)(Wb + (size_t)(rowS + 64 * r) * K + kn + qS * 8);
        }
        v8h af[MT], bf[NT];
#pragma unroll
        for (int i = 0; i < MT; ++i)
            af[i] = *(const v8h*)(As + (size_t)(wrow + i * 16 + lm) * 32 + lq * 8);
#pragma unroll
        for (int j = 0; j < NT; ++j)
            bf[j] = *(const v8h*)(Bs + (size_t)(wcol + j * 16 + lm) * 32 + lq * 8);
#pragma unroll
        for (int i = 0; i < MT; ++i)
#pragma unroll
            for (int j = 0; j < NT; ++j)
                acc[i][j] = __builtin_amdgcn_mfma_f32_16x16x32_f16(
                    af[i], bf[j], acc[i][j], 0, 0, 0);
    }

#pragma unroll
    for (int j = 0; j < NT; ++j) {
        int col = n0 + wcol + j * 16 + lm;
        float bv = bias1[col];
#pragma unroll
        for (int i = 0; i < MT; ++i) {
            int rbase = m0 + wrow + i * 16 + lq * 4;
#pragma unroll
            for (int rg = 0; rg < 4; ++rg)
                Cout[(size_t)(rbase + rg) * N + col] =
                    (_Float16)(acc[i][j][rg] + bv);
        }
    }
}

// ---------------------------------------------------------------------------
// GEMM (N=256 fixed) + bias + residual + LayerNorm fused.
// Out: X (f32, in-place residual target) and X16 (f16 copy).
// BM=64, BN=256, 256 threads (4 waves, 2x2), wave tile 32x128.
// ---------------------------------------------------------------------------
__global__ __launch_bounds__(256) void hgemm_ln_kernel(
    const _Float16* __restrict__ A, const _Float16* __restrict__ W,
    const float* __restrict__ bias, const float* __restrict__ gamma,
    const float* __restrict__ beta, float* __restrict__ X,
    _Float16* __restrict__ X16, int K)
{
    constexpr int BM = 64, BN = 256, MT = 2, NT = 8, RA = 1, RB = 4;
    __shared__ _Float16 As[BM * 32];
    __shared__ _Float16 Bs[BN * 32];
    __shared__ float redS[2][BM][2];

    const int tid = threadIdx.x;
    const int lane = tid & 63;
    const int lm = lane & 15, lq = lane >> 4;
    const int wrow = ((tid >> 6) & 1) * 32;
    const int wcol = (tid >> 7) * 128;
    const int half = tid >> 7;
    const int m0 = blockIdx.x * BM;
    const _Float16* Ab = A + (size_t)m0 * K;

    v4f acc[MT][NT];
#pragma unroll
    for (int i = 0; i < MT; ++i)
#pragma unroll
        for (int j = 0; j < NT; ++j) acc[i][j] = (v4f){0.f, 0.f, 0.f, 0.f};

    const int rowS = tid >> 2, qS = tid & 3;

    uint4 ra[RA], rb[RB];
#pragma unroll
    for (int r = 0; r < RA; ++r)
        ra[r] = *(const uint4*)(Ab + (size_t)(rowS + 64 * r) * K + qS * 8);
#pragma unroll
    for (int r = 0; r < RB; ++r)
        rb[r] = *(const uint4*)(W + (size_t)(rowS + 64 * r) * K + qS * 8);

    for (int k0 = 0; k0 < K; k0 += 32) {
        __syncthreads();
#pragma unroll
        for (int r = 0; r < RA; ++r)
            *(uint4*)(As + (size_t)(tid + 256 * r) * 8) = ra[r];
#pragma unroll
        for (int r = 0; r < RB; ++r)
            *(uint4*)(Bs + (size_t)(tid + 256 * r) * 8) = rb[r];
        __syncthreads();
        int kn = k0 + 32;
        if (kn < K) {
#pragma unroll
            for (int r = 0; r < RA; ++r)
                ra[r] = *(const uint4*)(Ab + (size_t)(rowS + 64 * r) * K + kn + qS * 8);
#pragma unroll
            for (int r = 0; r < RB; ++r)
                rb[r] = *(const uint4*)(W + (size_t)(rowS + 64 * r) * K + kn + qS * 8);
        }
        v8h af[MT], bf[NT];
#pragma unroll
        for (int i = 0; i < MT; ++i)
            af[i] = *(const v8h*)(As + (size_t)(wrow + i * 16 + lm) * 32 + lq * 8);
#pragma unroll
        for (int j = 0; j < NT; ++j)
            bf[j] = *(const v8h*)(Bs + (size_t)(wcol + j * 16 + lm) * 32 + lq * 8);
#pragma unroll
        for (int i = 0; i < MT; ++i)
#pragma unroll
            for (int j = 0; j < NT; ++j)
                acc[i][j] = __builtin_amdgcn_mfma_f32_16x16x32_f16(
                    af[i], bf[j], acc[i][j], 0, 0, 0);
    }

    // y = gemm + bias + residual; accumulate per-row sums
    float s[MT][4], s2[MT][4];
#pragma unroll
    for (int i = 0; i < MT; ++i)
#pragma unroll
        for (int rg = 0; rg < 4; ++rg) { s[i][rg] = 0.f; s2[i][rg] = 0.f; }
#pragma unroll
    for (int j = 0; j < NT; ++j) {
        int col = wcol + j * 16 + lm;
        float bv = bias[col];
#pragma unroll
        for (int i = 0; i < MT; ++i) {
            int rbase = m0 + wrow + i * 16 + lq * 4;
#pragma unroll
            for (int rg = 0; rg < 4; ++rg) {
                float y = acc[i][j][rg] + bv + X[(size_t)(rbase + rg) * 256 + col];
                acc[i][j][rg] = y;
                s[i][rg] += y;
                s2[i][rg] += y * y;
            }
        }
    }
    // reduce across the 16 lm lanes (same row), publish per-half partials
#pragma unroll
    for (int i = 0; i < MT; ++i)
#pragma unroll
        for (int rg = 0; rg < 4; ++rg) {
            float a = s[i][rg], b2 = s2[i][rg];
#pragma unroll
            for (int m = 1; m < 16; m <<= 1) {
                a += __shfl_xor(a, m);
                b2 += __shfl_xor(b2, m);
            }
            if (lm == 0) {
                int rloc = wrow + i * 16 + lq * 4 + rg;
                redS[half][rloc][0] = a;
                redS[half][rloc][1] = b2;
            }
        }
    __syncthreads();
#pragma unroll
    for (int i = 0; i < MT; ++i) {
#pragma unroll
        for (int rg = 0; rg < 4; ++rg) {
            int rloc = wrow + i * 16 + lq * 4 + rg;
            float st = redS[0][rloc][0] + redS[1][rloc][0];
            float s2t = redS[0][rloc][1] + redS[1][rloc][1];
            float mean = st * (1.f / 256.f);
            float var = s2t * (1.f / 256.f) - mean * mean;
            float inv = rsqrtf(var + 1e-5f);
            size_t rowb = (size_t)(m0 + rloc) * 256;
#pragma unroll
            for (int j = 0; j < NT; ++j) {
                int col = wcol + j * 16 + lm;
                float o = (acc[i][j][rg] - mean) * inv * gamma[col] + beta[col];
                X[rowb + col] = o;
                X16[rowb + col] = (_Float16)o;
            }
        }
    }
}

// ---------------------------------------------------------------------------
// Fused weight conversion (cvt_all + Whh blob + permuted bias in one launch).
// Wih dest rows are gate-interleaved: dest row j*4+g = src row g*256+j.
// Whh blob chunk map (q=0..63 -> (i,c)): LDS 8 (c<2 all i), regs 44
// (2<=c<13 all i), stream 12 (13<=c<16 all i).  [R0 layout, measured-best]
// ---------------------------------------------------------------------------
__global__ __launch_bounds__(256) void cvt_fused_kernel(
    const float* __restrict__ s0, const float* __restrict__ s1,
    const float* __restrict__ s2, const float* __restrict__ s3,
    const float* __restrict__ s4, const float* __restrict__ s5,
    _Float16* __restrict__ dst,
    const float* __restrict__ Whh, unsigned int* __restrict__ WB,
    const float* __restrict__ bih, const float* __restrict__ bhh,
    float* __restrict__ PB)
{
    if (blockIdx.x < 7424) {
        int i = blockIdx.x * 256 + threadIdx.x;
        if (i >= 1900544) return;
        float val;
        if (i < 589824)       val = s0[i];
        else if (i < 786432)  val = s1[i - 589824];
        else if (i < 1179648) val = s2[i - 786432];
        else if (i < 1572864) val = s3[i - 1179648];
        else if (i < 1835008) {
            int idx = i - 1572864;
            int rp = idx >> 8, k = idx & 255;
            int j = rp >> 2, g = rp & 3;
            val = s4[(g * 256 + j) * 256 + k];
        }
        else                  val = s5[i - 1835008];
        dst[i] = (_Float16)val;
    } else {
        int idx = (blockIdx.x - 7424) * 256 + threadIdx.x;  // 0..131071
        if (idx < 1024) {
            int j = idx >> 2, g = idx & 3;
            PB[idx] = bih[g * 256 + j] + bhh[g * 256 + j];
        }
        int l = idx & 3;
        int gt = idx >> 2;
        int tid = gt & 511;
        int q = gt >> 9;                            // 0..63
        int i, c;
        if (q < 8)       { i = q >> 1; c = q & 1; }
        else if (q < 52) { int qq = q - 8; i = qq / 11; c = 2 + qq % 11; }
        else             { int qq = q - 52; c = 13 + (qq >> 2); i = qq & 3; }
        int r = ((tid & 255) << 2) + i;
        int k = ((tid >> 8) << 7) + (c << 3) + (l << 1);
        _Float16 lo = (_Float16)Whh[r * 256 + k];
        _Float16 hi = (_Float16)Whh[r * 256 + k + 1];
        U32H2 x; x.h = h2t{lo, hi};
        WB[idx] = x.u;
    }
}

// ---------------------------------------------------------------------------
// Part encoder with bin-encoder fused (bb computed redundantly per block).
// ---------------------------------------------------------------------------
__global__ __launch_bounds__(128) void part_enc_kernel(
    const float* __restrict__ parts, const float* __restrict__ W1,
    const float* __restrict__ b1, const float* __restrict__ W2,
    const float* __restrict__ b2, const float* __restrict__ bin_info,
    const float* __restrict__ be_W1, const float* __restrict__ be_b1,
    const float* __restrict__ be_W2, const float* __restrict__ be_b2,
    const float* __restrict__ pos_emb, float* __restrict__ X,
    _Float16* __restrict__ X16)
{
    __shared__ float W2s[128][129];
    __shared__ float h1[128];
    __shared__ float pin[16];
    __shared__ float h1b[64];
    __shared__ float bb_s[64];
    int tid = threadIdx.x;
    int b = blockIdx.x >> 3, s0 = (blockIdx.x & 7) * 32;
    for (int l = 0; l < 128; ++l) W2s[l][tid] = W2[l * 128 + tid];
    // bin encoder (64-dim MLP, redundant per block, trivial)
    {
        float x0 = bin_info[b * 2], x1 = bin_info[b * 2 + 1];
        if (tid < 64)
            h1b[tid] = fmaxf(be_W1[tid * 2] * x0 + be_W1[tid * 2 + 1] * x1
                             + be_b1[tid], 0.f);
        __syncthreads();
        if (tid < 64) {
            float a = be_b2[tid];
#pragma unroll 4
            for (int e = 0; e < 64; ++e) a += be_W2[tid * 64 + e] * h1b[e];
            bb_s[tid] = a;
        }
        __syncthreads();
    }
    float w1r[16];
#pragma unroll
    for (int k = 0; k < 16; ++k) w1r[k] = W1[tid * 16 + k];
    float bias1v = b1[tid], bias2v = b2[tid];
    for (int si = 0; si < 32; ++si) {
        int s = s0 + si;
        size_t row = (size_t)b * 256 + s;
        if (tid < 16) pin[tid] = parts[row * 16 + tid];
        __syncthreads();
        float h = bias1v;
#pragma unroll
        for (int k = 0; k < 16; ++k) h += w1r[k] * pin[k];
        h1[tid] = fmaxf(h, 0.f);
        __syncthreads();
        float acc = bias2v;
#pragma unroll 4
        for (int e = 0; e < 128; ++e) acc += W2s[tid][e] * h1[e];
        X[row * 256 + tid] = acc;
        X16[row * 256 + tid] = (_Float16)acc;
        if (tid < 64) {
            float bbv = bb_s[tid];
            float pev = pos_emb[s * 64 + tid];
            X[row * 256 + 128 + tid] = bbv;
            X[row * 256 + 192 + tid] = pev;
            X16[row * 256 + 128 + tid] = (_Float16)bbv;
            X16[row * 256 + 192 + tid] = (_Float16)pev;
        }
        __syncthreads();
    }
}

// ---------------------------------------------------------------------------
// MFMA attention: one block per (b,h), 256 threads (4 waves).
// ---------------------------------------------------------------------------
__global__ __launch_bounds__(256) void attn_mfma_kernel(
    const _Float16* __restrict__ QKV, _Float16* __restrict__ O16)
{
    int bh = blockIdx.x;
    int b = bh >> 3, h = bh & 7;
    const int tid = threadIdx.x;
    const int w = tid >> 6;
    const int lane = tid & 63;
    const int lm = lane & 15, lq = lane >> 4;
    const float c_se = 0.17677669529663687f * 1.44269504f;

    __shared__ _Float16 Ks[4][256][8];
    __shared__ _Float16 Vt[32][264];
    __shared__ _Float16 Ps[4][16][264];

    const _Float16* qkvb = QKV + (size_t)(b * 256) * 768 + h * 32;
    {
        int s = tid;
        const _Float16* kr = qkvb + (size_t)s * 768 + 256;
#pragma unroll
        for (int c = 0; c < 4; ++c)
            *(uint4*)&Ks[c][s][0] = *(const uint4*)(kr + c * 8);
        const _Float16* vr = qkvb + (size_t)s * 768 + 512;
        _Float16 vtmp[32];
        *(uint4*)&vtmp[0]  = *(const uint4*)(vr);
        *(uint4*)&vtmp[8]  = *(const uint4*)(vr + 8);
        *(uint4*)&vtmp[16] = *(const uint4*)(vr + 16);
        *(uint4*)&vtmp[24] = *(const uint4*)(vr + 24);
#pragma unroll
        for (int d = 0; d < 32; ++d) Vt[d][s] = vtmp[d];
    }
    __syncthreads();

#pragma unroll 1
    for (int st = 0; st < 4; ++st) {
        int rt = w * 4 + st;
        v8h qf = *(const v8h*)(QKV + (size_t)(b * 256 + rt * 16 + lm) * 768
                               + h * 32 + lq * 8);
        v4f acc[16];
#pragma unroll
        for (int ct = 0; ct < 16; ++ct) {
            v8h kf = *(const v8h*)&Ks[lq][ct * 16 + lm][0];
            acc[ct] = __builtin_amdgcn_mfma_f32_16x16x32_f16(
                qf, kf, (v4f){0.f, 0.f, 0.f, 0.f}, 0, 0, 0);
        }
        float sminv[4];
#pragma unroll
        for (int r = 0; r < 4; ++r) {
            float m = acc[0][r];
#pragma unroll
            for (int ct = 1; ct < 16; ++ct) m = fmaxf(m, acc[ct][r]);
#pragma unroll
            for (int msk = 1; msk < 16; msk <<= 1)
                m = fmaxf(m, __shfl_xor(m, msk));
            float ssum = 0.f;
#pragma unroll
            for (int ct = 0; ct < 16; ++ct) {
                float e = fexp2((acc[ct][r] - m) * c_se);
                acc[ct][r] = e;
                ssum += e;
            }
#pragma unroll
            for (int msk = 1; msk < 16; msk <<= 1)
                ssum += __shfl_xor(ssum, msk);
            sminv[r] = frcp(ssum);
        }
#pragma unroll
        for (int ct = 0; ct < 16; ++ct)
#pragma unroll
            for (int r = 0; r < 4; ++r)
                Ps[w][lq * 4 + r][ct * 16 + lm] =
                    (_Float16)(acc[ct][r] * sminv[r]);
#pragma unroll
        for (int dt = 0; dt < 2; ++dt) {
            v4f o = (v4f){0.f, 0.f, 0.f, 0.f};
#pragma unroll
            for (int jc = 0; jc < 8; ++jc) {
                v8h pf = *(const v8h*)&Ps[w][lm][jc * 32 + lq * 8];
                v8h vf = *(const v8h*)&Vt[dt * 16 + lm][jc * 32 + lq * 8];
                o = __builtin_amdgcn_mfma_f32_16x16x32_f16(pf, vf, o, 0, 0, 0);
            }
#pragma unroll
            for (int r = 0; r < 4; ++r)
                O16[(size_t)(b * 256 + rt * 16 + lq * 4 + r) * 256
                    + h * 32 + dt * 16 + lm] = (_Float16)o[r];
        }
    }
}

// ---------------------------------------------------------------------------
// Fat kernel: blocks 0..31 = LSTM recurrence (R0 design, 362us floor);
// blocks 32..287 = EPROJ GEMM (X16 @ WpW^T + ptr_b -> f32), BM=128 BN=64,
// all 512 threads active (8 waves 4x2, wave tile 32x32). The GEMM fills the
// 224 CUs that idle during the 32-block LSTM. LDS padded to 84KB so only
// 1 block/CU -> eproj blocks never co-reside with (and slow) an lstm block.
// ---------------------------------------------------------------------------
__global__ __launch_bounds__(512) void lstm_eproj_kernel(
    const _Float16* __restrict__ g_in, const uint4* __restrict__ WB4,
    _Float16* __restrict__ HALL16,
    const _Float16* __restrict__ X16, const _Float16* __restrict__ WpW,
    const float* __restrict__ ptr_b, float* __restrict__ EPROJ)
{
    __shared__ __align__(16) unsigned char smem[86016];
    const int tid = threadIdx.x;

    if (blockIdx.x >= 32) {
        // ---- EPROJ GEMM path ----
        _Float16* As = (_Float16*)smem;            // 128*32*2 = 8 KB
        _Float16* Bs = (_Float16*)(smem + 8192);   // 64*32*2  = 4 KB
        const int gb = (int)blockIdx.x - 32;       // 0..255
        const int m0 = (gb & 63) * 128, n0 = (gb >> 6) * 64;
        const int lane = tid & 63;
        const int lm = lane & 15, lq = lane >> 4;
        const int wr = (tid >> 6) & 3, wc = tid >> 8;
        const _Float16* Ab = X16 + (size_t)m0 * 256;
        const _Float16* Wb = WpW + (size_t)n0 * 256;

        v4f acc[2][2];
#pragma unroll
        for (int i = 0; i < 2; ++i)
#pragma unroll
            for (int j = 0; j < 2; ++j) acc[i][j] = (v4f){0.f, 0.f, 0.f, 0.f};

        const int rowSA = tid >> 2, qA = tid & 3;   // 128 rows x 4 uint4
        const int rowSB = tid >> 3, qB = tid & 7;   // 64 rows x 8 uint2
        uint4 ra = *(const uint4*)(Ab + (size_t)rowSA * 256 + qA * 8);
        uint2 rb = *(const uint2*)(Wb + (size_t)rowSB * 256 + qB * 4);

        for (int k0 = 0; k0 < 256; k0 += 32) {
            __syncthreads();
            *(uint4*)(As + (size_t)rowSA * 32 + qA * 8) = ra;
            *(uint2*)(Bs + (size_t)rowSB * 32 + qB * 4) = rb;
            __syncthreads();
            int kn = k0 + 32;
            if (kn < 256) {
                ra = *(const uint4*)(Ab + (size_t)rowSA * 256 + kn + qA * 8);
                rb = *(const uint2*)(Wb + (size_t)rowSB * 256 + kn + qB * 4);
            }
            v8h af[2], bf[2];
#pragma unroll
            for (int i = 0; i < 2; ++i)
                af[i] = *(const v8h*)(As + (size_t)(wr * 32 + i * 16 + lm) * 32 + lq * 8);
#pragma unroll
            for (int j = 0; j < 2; ++j)
                bf[j] = *(const v8h*)(Bs + (size_t)(wc * 32 + j * 16 + lm) * 32 + lq * 8);
#pragma unroll
            for (int i = 0; i < 2; ++i)
#pragma unroll
                for (int j = 0; j < 2; ++j)
                    acc[i][j] = __builtin_amdgcn_mfma_f32_16x16x32_f16(
                        af[i], bf[j], acc[i][j], 0, 0, 0);
        }
#pragma unroll
        for (int j = 0; j < 2; ++j) {
            int col = n0 + wc * 32 + j * 16 + lm;
            float bv = ptr_b[col];
#pragma unroll
            for (int i = 0; i < 2; ++i) {
                int rbase = m0 + wr * 32 + i * 16 + lq * 4;
#pragma unroll
                for (int rg = 0; rg < 4; ++rg)
                    EPROJ[(size_t)(rbase + rg) * 256 + col] = acc[i][j][rg] + bv;
            }
        }
        return;
    }

    // ---- LSTM path (R0 design verbatim, LDS carved from smem) ----
    uint4* WL4 = (uint4*)smem;                      // 64 KB
    float* gpart = (float*)(smem + 65536);          // 8 KB   [2][1024]
    uint4* h2v = (uint4*)(smem + 65536 + 8192);     // 512 B
    unsigned int* h2_s = (unsigned int*)h2v;

    const int b = blockIdx.x;
    const int kh = tid >> 8, j4 = tid & 255;

#pragma unroll
    for (int g = 0; g < 8; ++g) WL4[g * 512 + tid] = WB4[g * 512 + tid];
    uint4 wr[44];
#pragma unroll
    for (int q = 0; q < 44; ++q) wr[q] = WB4[(8 + q) * 512 + tid];
    if (tid < 128) h2_s[tid] = 0u;

    const _Float16* ginb = g_in + (size_t)b * 256 * 1024;
    uint2 gi = make_uint2(0u, 0u);
    if (tid < 256) gi = *(const uint2*)(ginb + tid * 4);
    float c_state = 0.f;
    const uint4* SW4 = WB4 + 52 * 512;
    __syncthreads();

    for (int t = 0; t < 256; ++t) {
        uint4 sw[12];
#pragma unroll
        for (int q = 0; q < 4; ++q) sw[q] = SW4[q * 512 + tid];

        float acc[4] = {0.f, 0.f, 0.f, 0.f};
#pragma unroll
        for (int c = 0; c < 16; ++c) {
            if (c == 2) {
#pragma unroll
                for (int q = 4; q < 8; ++q) sw[q] = SW4[q * 512 + tid];
            }
            if (c == 6) {
#pragma unroll
                for (int q = 8; q < 12; ++q) sw[q] = SW4[q * 512 + tid];
            }
            uint4 h4 = h2v[(kh << 4) + c];
            h2t hx = u2h(h4.x), hy = u2h(h4.y), hz = u2h(h4.z), hw = u2h(h4.w);
#pragma unroll
            for (int i = 0; i < 4; ++i) {
                uint4 w = (c < 2)  ? WL4[((i << 1) + c) * 512 + tid]
                        : (c < 13) ? wr[i * 11 + (c - 2)]
                                   : sw[((c - 13) << 2) + i];
                acc[i] = __builtin_amdgcn_fdot2(u2h(w.x), hx, acc[i], false);
                acc[i] = __builtin_amdgcn_fdot2(u2h(w.y), hy, acc[i], false);
                acc[i] = __builtin_amdgcn_fdot2(u2h(w.z), hz, acc[i], false);
                acc[i] = __builtin_amdgcn_fdot2(u2h(w.w), hw, acc[i], false);
            }
        }
        *(float4*)&gpart[kh * 1024 + (j4 << 2)] =
            make_float4(acc[0], acc[1], acc[2], acc[3]);
        __syncthreads();

        if (tid < 256) {
            int j = tid;
            h2t p0 = u2h(gi.x), p1 = u2h(gi.y);
            float ig = (float)p0.x + gpart[j]        + gpart[1024 + j];
            float fg = (float)p0.y + gpart[j + 256]  + gpart[1024 + j + 256];
            float gg = (float)p1.x + gpart[j + 512]  + gpart[1024 + j + 512];
            float og = (float)p1.y + gpart[j + 768]  + gpart[1024 + j + 768];
            c_state = fsigm(fg) * c_state + fsigm(ig) * ftanh_(gg);
            float h = fsigm(og) * ftanh_(c_state);
            HALL16[((size_t)(b * 256 + t)) * 256 + j] = (_Float16)h;
            U32H2 hxp; hxp.h = h2t{(_Float16)h, (_Float16)0.f};
            unsigned int hu = hxp.u & 0xffffu;
            unsigned int other = (unsigned int)__shfl_xor((int)hu, 1);
            if ((j & 1) == 0) h2_s[j >> 1] = hu | (other << 16);
            int tn = (t < 255) ? (t + 1) : 255;
            gi = *(const uint2*)(ginb + (size_t)tn * 1024 + j * 4);
        }
        __syncthreads();
    }
}

// ---------------------------------------------------------------------------
// Pointer logits: out[b,t,i] = vsum - 2 * sum_d v_d / (1 + exp2(s_d)),
// s = 2.88539*(hp+ep) (scale folded into LDS staging).
// ---------------------------------------------------------------------------
__global__ __launch_bounds__(256) void pointer_kernel(
    const float* __restrict__ HP, const float* __restrict__ EP,
    const float* __restrict__ v, float* __restrict__ out)
{
    int b = blockIdx.z, tt = blockIdx.y, it = blockIdx.x;
    __shared__ float hp_s[16][260];
    __shared__ float ep_s[16][260];
    __shared__ float v_s[256];
    __shared__ float red[4];
    int tid = threadIdx.x;
    const float cs = 2.88539008f;
    const float* hpb = HP + ((size_t)b * 256 + tt * 16) * 256;
    const float* epb = EP + ((size_t)b * 256 + it * 16) * 256;
#pragma unroll
    for (int l = 0; l < 4; ++l) {
        int idx = tid + l * 256;
        int r = idx >> 6, c4 = idx & 63;
        float4 hv = *(const float4*)(hpb + r * 256 + c4 * 4);
        hv.x *= cs; hv.y *= cs; hv.z *= cs; hv.w *= cs;
        *(float4*)&hp_s[r][c4 * 4] = hv;
        float4 ev = *(const float4*)(epb + r * 256 + c4 * 4);
        ev.x *= cs; ev.y *= cs; ev.z *= cs; ev.w *= cs;
        *(float4*)&ep_s[r][c4 * 4] = ev;
    }
    float vv = v[tid];
    v_s[tid] = vv;
    float vp = vv;
#pragma unroll
    for (int m = 1; m < 64; m <<= 1) vp += __shfl_xor(vp, m);
    if ((tid & 63) == 0) red[tid >> 6] = vp;
    __syncthreads();
    float vsum = red[0] + red[1] + red[2] + red[3];
    int tl = tid >> 4, il = tid & 15;
    float acc = 0.f;
#pragma unroll 4
    for (int d = 0; d < 256; ++d) {
        float sval = hp_s[tl][d] + ep_s[il][d];
        float r = frcp(1.0f + fexp2(sval));
        acc = fmaf(v_s[d], r, acc);
    }
    out[((size_t)b * 256 + tt * 16 + tl) * 256 + it * 16 + il] =
        vsum - 2.0f * acc;
}

// ---------------------------------------------------------------------------
extern "C" void kernel_launch(void* const* d_in, const int* in_sizes, int n_in,
                              void* d_out, int out_size, void* d_ws, size_t ws_size,
                              hipStream_t stream)
{
    const float* parts    = (const float*)d_in[0];
    const float* bin_info = (const float*)d_in[1];
    const int*   target   = (const int*)d_in[2];
    const float* pe_W1 = (const float*)d_in[3];
    const float* pe_b1 = (const float*)d_in[4];
    const float* pe_W2 = (const float*)d_in[5];
    const float* pe_b2 = (const float*)d_in[6];
    const float* be_W1 = (const float*)d_in[7];
    const float* be_b1 = (const float*)d_in[8];
    const float* be_W2 = (const float*)d_in[9];
    const float* be_b2 = (const float*)d_in[10];
    const float* pos_emb = (const float*)d_in[11];
    const float* tr_Wqkv = (const float*)d_in[12];
    const float* tr_bqkv = (const float*)d_in[13];
    const float* tr_Wo   = (const float*)d_in[14];
    const float* tr_bo   = (const float*)d_in[15];
    const float* tr_ln1_g = (const float*)d_in[16];
    const float* tr_ln1_b = (const float*)d_in[17];
    const float* tr_ff_W1 = (const float*)d_in[18];
    const float* tr_ff_b1 = (const float*)d_in[19];
    const float* tr_ff_W2 = (const float*)d_in[20];
    const float* tr_ff_b2 = (const float*)d_in[21];
    const float* tr_ln2_g = (const float*)d_in[22];
    const float* tr_ln2_b = (const float*)d_in[23];
    const float* lstm_Wih = (const float*)d_in[24];
    const float* lstm_Whh = (const float*)d_in[25];
    const float* lstm_bih = (const float*)d_in[26];
    const float* lstm_bhh = (const float*)d_in[27];
    const float* ptr_W = (const float*)d_in[28];
    const float* ptr_b = (const float*)d_in[29];
    const float* ptr_v = (const float*)d_in[30];

    // ---- workspace layout (floats) ----
    float* ws = (float*)d_ws;
    float* X     = ws;                        // 2,097,152
    float* S1    = X + 2097152;               // 8,388,608 (qkv/ff1/g_in f16)
    float* CF32  = S1 + 8388608;              // 2,097,152
    float* EPROJ = CF32 + 2097152;            // 2,097,152
    float* X16f  = EPROJ + 2097152;           // 1,048,576
    float* S2f   = X16f + 1048576;            // 1,048,576
    float* W16f  = S2f + 1048576;             // 1,048,576
    float* WBf   = W16f + 1048576;            // 131,072
    float* BBuf  = WBf + 131072;              // 2,048 (unused)
    float* PB    = BBuf + 2048;               // 1,024

    _Float16* X16    = (_Float16*)X16f;
    _Float16* S2h    = (_Float16*)S2f;
    _Float16* HALL16 = S2h;
    _Float16* S1h    = (_Float16*)S1;
    _Float16* W16    = (_Float16*)W16f;
    _Float16* Wqkv16 = W16;                   // 589,824
    _Float16* Wo16   = Wqkv16 + 589824;       // 196,608
    _Float16* Wff116 = Wo16 + 196608;         // 393,216
    _Float16* Wff216 = Wff116 + 393216;       // 393,216
    _Float16* Wih16  = Wff216 + 393216;       // 262,144 (gate-interleaved rows)
    _Float16* WpW16  = Wih16 + 262144;        // 65,536

    // ---- one-time weight conversions (single fused launch) ----
    cvt_fused_kernel<<<7936, 256, 0, stream>>>(
        tr_Wqkv, tr_Wo, tr_ff_W1, tr_ff_W2, lstm_Wih, ptr_W, W16,
        lstm_Whh, (unsigned int*)WBf, lstm_bih, lstm_bhh, PB);

    // ---- encoders (bin fused into part) ----
    part_enc_kernel<<<256, 128, 0, stream>>>(parts, pe_W1, pe_b1, pe_W2, pe_b2,
                                             bin_info, be_W1, be_b1, be_W2, be_b2,
                                             pos_emb, X, X16);

    // ---- transformer layers ----
    for (int l = 0; l < 3; ++l) {
        hgemm_kernel<64, 128, false, true><<<dim3(128, 6), 256, 0, stream>>>(
            X16, Wqkv16 + (size_t)l * 196608, tr_bqkv + l * 768, nullptr,
            S1h, 8192, 768, 256);
        attn_mfma_kernel<<<256, 256, 0, stream>>>(S1h, S2h);
        hgemm_ln_kernel<<<128, 256, 0, stream>>>(
            S2h, Wo16 + (size_t)l * 65536, tr_bo + l * 256,
            tr_ln1_g + l * 256, tr_ln1_b + l * 256, X, X16, 256);
        hgemm_kernel<64, 128, true, true><<<dim3(128, 4), 256, 0, stream>>>(
            X16, Wff116 + (size_t)l * 131072, tr_ff_b1 + l * 512, nullptr,
            S1h, 8192, 512, 256);
        hgemm_ln_kernel<<<128, 256, 0, stream>>>(
            S1h, Wff216 + (size_t)l * 131072, tr_ff_b2 + l * 256,
            tr_ln2_g + l * 256, tr_ln2_b + l * 256, X, X16, 512);
    }

    // ---- pointer decode ----
    hgemm_gather_kernel<<<dim3(128, 8), 256, 0, stream>>>(
        X16, target, Wih16, PB, S1h, 1024, 256);
    lstm_eproj_kernel<<<288, 512, 0, stream>>>(
        S1h, (const uint4*)WBf, HALL16, X16, WpW16, ptr_b, EPROJ);
    hgemm_kernel<64, 64, false, false><<<dim3(128, 4), 256, 0, stream>>>(
        HALL16, WpW16, ptr_b, nullptr, CF32, 8192, 256, 256);
    pointer_kernel<<<dim3(16, 16, 32), 256, 0, stream>>>(CF32, EPROJ, ptr_v,
                                                         (float*)d_out);
}